// Round 2
// baseline (622.812 us; speedup 1.0000x reference)
//
#include <hip/hip_runtime.h>
#include <stdint.h>

#define BB 6
#define NPTS 1024
#define DD 128
#define HH 320
#define WW 320
#define NC 500
#define HWsz (HH*WW)
#define CAP 4096
#define TILE 64
#define BKK 32

__device__ __forceinline__ int clampi(int v, int lo, int hi){ return v<lo?lo:(v>hi?hi:v); }
__device__ __forceinline__ int refl(int p, int L){ if(p<0)p=-p; if(p>=L)p=2*L-2-p; return p; }

// ---------------- projection (matches pairwise_project) ----------------
struct Proj { float u, v; int vis; };

__device__ Proj project_point(float ptx, float pty, int jsrc, int itgt,
                              const float* __restrict__ depths,
                              const float* __restrict__ poses,
                              const float* __restrict__ Km)
{
  // denorm_px
  float pxx = ((ptx + 1.0f)*(float)(WW-1))*0.5f;
  float pxy = ((pty + 1.0f)*(float)(HH-1))*0.5f;
  // depth lookup: clip(round(px),0,W-1)
  float rx = rintf(pxx), ry = rintf(pxy);
  rx = fminf(fmaxf(rx, 0.f), (float)(WW-1));
  ry = fminf(fmaxf(ry, 0.f), (float)(HH-1));
  int xi = (int)rx, yi = (int)ry;
  float d = depths[(size_t)jsrc*HWsz + yi*WW + xi];
  // Kinv (adjugate)
  float a00=Km[0],a01=Km[1],a02=Km[2],a10=Km[3],a11=Km[4],a12=Km[5],a20=Km[6],a21=Km[7],a22=Km[8];
  float det = a00*(a11*a22 - a12*a21) - a01*(a10*a22 - a12*a20) + a02*(a10*a21 - a11*a20);
  float id_ = 1.0f/det;
  float i00 = (a11*a22 - a12*a21)*id_;
  float i01 = (a02*a21 - a01*a22)*id_;
  float i02 = (a01*a12 - a02*a11)*id_;
  float i10 = (a12*a20 - a10*a22)*id_;
  float i11 = (a00*a22 - a02*a20)*id_;
  float i12 = (a02*a10 - a00*a12)*id_;
  float i20 = (a10*a21 - a11*a20)*id_;
  float i21 = (a01*a20 - a00*a21)*id_;
  float i22 = (a00*a11 - a01*a10)*id_;
  // cam = (hom @ Kinv.T) * d
  float c0 = (i00*pxx + i01*pxy + i02)*d;
  float c1 = (i10*pxx + i11*pxy + i12)*d;
  float c2 = (i20*pxx + i21*pxy + i22)*d;
  // world = R_j cam + t_j
  const float* Pj = poses + (size_t)jsrc*16;
  float w0 = Pj[0]*c0 + Pj[1]*c1 + Pj[2]*c2  + Pj[3];
  float w1 = Pj[4]*c0 + Pj[5]*c1 + Pj[6]*c2  + Pj[7];
  float w2 = Pj[8]*c0 + Pj[9]*c1 + Pj[10]*c2 + Pj[11];
  // diff = world - t_i ; cam2 = R_i^T diff
  const float* Pi = poses + (size_t)itgt*16;
  float dx = w0 - Pi[3], dy = w1 - Pi[7], dz = w2 - Pi[11];
  float e0 = Pi[0]*dx + Pi[4]*dy + Pi[8]*dz;
  float e1 = Pi[1]*dx + Pi[5]*dy + Pi[9]*dz;
  float e2 = Pi[2]*dx + Pi[6]*dy + Pi[10]*dz;
  // uvw = cam2 @ K.T
  float uu = a00*e0 + a01*e1 + a02*e2;
  float vv = a10*e0 + a11*e1 + a12*e2;
  float zz = a20*e0 + a21*e1 + a22*e2;
  float zs = (fabsf(zz) > 1e-6f) ? zz : 1e-6f;
  Proj r;
  r.u = uu/zs; r.v = vv/zs;
  r.vis = (zz > 0.1f) && (r.u >= 0.f) && (r.u <= (float)(WW-1)) && (r.v >= 0.f) && (r.v <= (float)(HH-1));
  return r;
}

// ---------------- K1: gray ----------------
__global__ void k_gray(const float* __restrict__ imgs, float* __restrict__ gray){
  int t = blockIdx.x*blockDim.x + threadIdx.x;
  if (t >= BB*HWsz) return;
  int b = t / HWsz, p = t - b*HWsz;
  const float* base = imgs + (size_t)b*3*HWsz;
  gray[t] = 0.299f*base[p] + 0.587f*base[HWsz+p] + 0.114f*base[2*HWsz+p];
}

// ---------------- K2: sobel (edge pad) + products ----------------
__global__ void k_sobel(const float* __restrict__ gray, float* __restrict__ gxx,
                        float* __restrict__ gyy, float* __restrict__ gxy){
  int t = blockIdx.x*blockDim.x + threadIdx.x;
  if (t >= BB*HWsz) return;
  int b = t / HWsz, p = t - b*HWsz;
  int y = p / WW, x = p - y*WW;
  const float* g = gray + (size_t)b*HWsz;
  int ym = clampi(y-1,0,HH-1), yp = clampi(y+1,0,HH-1);
  int xm = clampi(x-1,0,WW-1), xp = clampi(x+1,0,WW-1);
  float g00 = g[ym*WW+xm], g01 = g[ym*WW+x], g02 = g[ym*WW+xp];
  float g10 = g[y*WW+xm],                    g12 = g[y*WW+xp];
  float g20 = g[yp*WW+xm], g21 = g[yp*WW+x], g22 = g[yp*WW+xp];
  float gx = 0.125f*(g02-g00) + 0.25f*(g12-g10) + 0.125f*(g22-g20);
  float gy = 0.125f*(g20-g00) + 0.25f*(g21-g01) + 0.125f*(g22-g02);
  gxx[t] = gx*gx; gyy[t] = gy*gy; gxy[t] = gx*gy;
}

// ---------------- K3: gaussian 7x7 (reflect) + GFTT response ----------------
__global__ void k_gauss_resp(const float* __restrict__ gxx, const float* __restrict__ gyy,
                             const float* __restrict__ gxy, float* __restrict__ resp){
  int t = blockIdx.x*blockDim.x + threadIdx.x;
  if (t >= BB*HWsz) return;
  int b = t / HWsz, p = t - b*HWsz;
  int y = p / WW, x = p - y*WW;
  float w1[7]; float s = 0.f;
  #pragma unroll
  for (int i=0;i<7;++i){ float a=(float)i-3.f; w1[i]=expf(-0.5f*a*a); s+=w1[i]; }
  #pragma unroll
  for (int i=0;i<7;++i) w1[i] = w1[i]/s;
  const float* axx = gxx + (size_t)b*HWsz;
  const float* ayy = gyy + (size_t)b*HWsz;
  const float* axy = gxy + (size_t)b*HWsz;
  float sxx=0.f, syy=0.f, sxy=0.f;
  #pragma unroll
  for (int i=0;i<7;++i){
    int ry = refl(y+i-3, HH);
    const float* rxx = axx + (size_t)ry*WW;
    const float* ryy = ayy + (size_t)ry*WW;
    const float* rxy = axy + (size_t)ry*WW;
    float wr = w1[i];
    #pragma unroll
    for (int j=0;j<7;++j){
      int rx = refl(x+j-3, WW);
      float wc = wr*w1[j];
      sxx += wc*rxx[rx]; syy += wc*ryy[rx]; sxy += wc*rxy[rx];
    }
  }
  float tr = sxx+syy, df = sxx-syy;
  float disc = sqrtf(fmaxf(df*df + 4.f*sxy*sxy, 0.f));
  resp[t] = 0.5f*(tr - disc);
}

// ---------------- K4: 5x5 NMS (pad -inf) ----------------
__global__ void k_nms5(const float* __restrict__ resp, float* __restrict__ keep){
  int t = blockIdx.x*blockDim.x + threadIdx.x;
  if (t >= BB*HWsz) return;
  int b = t / HWsz, p = t - b*HWsz;
  int y = p / WW, x = p - y*WW;
  const float* rb = resp + (size_t)b*HWsz;
  float m = -1e30f;
  for (int dy=-2; dy<=2; ++dy){
    int yy = y+dy; if (yy<0||yy>=HH) continue;
    for (int dx=-2; dx<=2; ++dx){
      int xx2 = x+dx; if (xx2<0||xx2>=WW) continue;
      m = fmaxf(m, rb[yy*WW+xx2]);
    }
  }
  float r = rb[p];
  keep[t] = (r == m) ? r : 0.f;
}

// ---------------- K5: 8x8 block max + compact positive candidates ----------------
__global__ void k_blockmax_compact(const float* __restrict__ keep,
        unsigned long long* __restrict__ ckeys, unsigned int* __restrict__ ccnt){
  int t = blockIdx.x*blockDim.x + threadIdx.x;
  const int BLKS = (HH/8)*(WW/8);
  if (t >= BB*BLKS) return;
  int b = t / BLKS; int r = t - b*BLKS;
  int by = r / (WW/8), bx = r - by*(WW/8);
  const float* k0 = keep + (size_t)b*HWsz;
  float bm = -1e30f;
  for (int dy=0; dy<8; ++dy)
    for (int dx=0; dx<8; ++dx)
      bm = fmaxf(bm, k0[(by*8+dy)*WW + bx*8+dx]);
  if (!(bm > 0.f)) return;
  for (int dy=0; dy<8; ++dy)
    for (int dx=0; dx<8; ++dx){
      int yy = by*8+dy, xx2 = bx*8+dx;
      float v = k0[yy*WW+xx2];
      if (v == bm){
        unsigned int slot = atomicAdd(&ccnt[b], 1u);
        if (slot < CAP){
          unsigned int idx = (unsigned int)(yy*WW + xx2);
          ckeys[(size_t)b*CAP + slot] =
            ((unsigned long long)__float_as_uint(bm) << 32) |
            (unsigned long long)(0xFFFFFFFFu - idx);
        }
      }
    }
}

// ---------------- K6: bitonic top-500 per batch ----------------
__global__ __launch_bounds__(1024) void k_top500(const unsigned long long* __restrict__ ckeys,
        const unsigned int* __restrict__ ccnt, float* __restrict__ cpts, float* __restrict__ cvals){
  __shared__ unsigned long long sk[CAP];
  int b = blockIdx.x;
  int tid = threadIdx.x;
  unsigned int cnt = ccnt[b]; if (cnt > CAP) cnt = CAP;
  for (int i = tid; i < CAP; i += 1024)
    sk[i] = (i < (int)cnt) ? ckeys[(size_t)b*CAP + i] : 0ull;
  __syncthreads();
  for (int k = 2; k <= CAP; k <<= 1){
    for (int j = k >> 1; j > 0; j >>= 1){
      for (int i = tid; i < CAP; i += 1024){
        int l = i ^ j;
        if (l > i){
          unsigned long long A = sk[i], Bv = sk[l];
          bool up = ((i & k) == 0);
          if ((A > Bv) == up){ sk[i] = Bv; sk[l] = A; }
        }
      }
      __syncthreads();
    }
  }
  if (tid < NC){
    unsigned long long key = sk[CAP-1-tid];   // descending order
    float val = __uint_as_float((unsigned int)(key >> 32));
    size_t o = (size_t)b*NC + tid;
    if (val > 0.f){
      unsigned int idx = 0xFFFFFFFFu - (unsigned int)(key & 0xFFFFFFFFull);
      float fx = (float)(idx % WW), fy = (float)(idx / WW);
      cpts[o*2+0] = (fx*2.0f)/(float)(WW-1) - 1.0f;
      cpts[o*2+1] = (fy*2.0f)/(float)(HH-1) - 1.0f;
      cvals[o] = val;
    } else {
      cpts[o*2+0] = __int_as_float(0x7fc00000);
      cpts[o*2+1] = __int_as_float(0x7fc00000);
      cvals[o] = 0.f;
    }
  }
}

// ---------------- K7: corner projection + scatter-max ----------------
// flat f = j*(B*NC) + i*NC + n : scatter into batch j, pixel = proj[i,j,n], value = values[i,n]
__global__ void k_corner_scatter(const float* __restrict__ cpts, const float* __restrict__ cvals,
        const float* __restrict__ depths, const float* __restrict__ poses,
        const float* __restrict__ Km, unsigned int* __restrict__ target){
  int t = blockIdx.x*blockDim.x + threadIdx.x;
  if (t >= BB*BB*NC) return;
  int i = t / (BB*NC); int r = t - i*(BB*NC); int j = r / NC; int n = r - j*NC;
  float val = cvals[(size_t)i*NC + n];
  float ptx = cpts[((size_t)j*NC+n)*2+0];
  float pty = cpts[((size_t)j*NC+n)*2+1];
  if (!(val > 0.f) || ptx != ptx) return;
  Proj pr = project_point(ptx, pty, j, i, depths, poses, Km);
  if (!pr.vis) return;
  float nu = (pr.u*2.0f)/(float)(WW-1) - 1.0f;
  float nv = (pr.v*2.0f)/(float)(HH-1) - 1.0f;
  float px2 = ((nu+1.0f)*(float)(WW-1))*0.5f;
  float py2 = ((nv+1.0f)*(float)(HH-1))*0.5f;
  float rx = rintf(px2), ry = rintf(py2);
  if (!(rx >= 0.f && ry >= 0.f && rx <= (float)(WW-1) && ry <= (float)(HH-1))) return;
  int wf = (int)rx, hf = (int)ry;
  atomicMax(&target[(size_t)j*HWsz + hf*WW + wf], __float_as_uint(val));
}

// ---------------- K8: target NMS + BCE + laplacian reduce ----------------
__global__ void k_score_reduce(const float* __restrict__ target, const float* __restrict__ scores,
        double* __restrict__ acc){
  __shared__ float red[256];
  int t = blockIdx.x*blockDim.x + threadIdx.x;
  float bce = 0.f, extra = 0.f;
  if (t < BB*HWsz){
    int b = t / HWsz, p = t - b*HWsz;
    int y = p / WW, x = p - y*WW;
    const float* tg = target + (size_t)b*HWsz;
    float tv = tg[p];
    float m = -1e30f;
    for (int dy=-2; dy<=2; ++dy){
      int yy = y+dy; if (yy<0||yy>=HH) continue;
      for (int dx=-2; dx<=2; ++dx){
        int xx2 = x+dx; if (xx2<0||xx2>=WW) continue;
        m = fmaxf(m, tg[yy*WW+xx2]);
      }
    }
    float tb = (tv > 0.f && tv == m) ? 1.f : 0.f;
    float sc = scores[t];
    float pc = fminf(fmaxf(sc, 1e-12f), 1.0f - 1e-12f);
    bce = -(tb*logf(pc) + (1.f-tb)*logf(1.f-pc));
    const float* sb = scores + (size_t)b*HWsz;
    float S5 = 0.f;
    for (int dy=-2; dy<=2; ++dy){
      int yy = refl(y+dy, HH);
      for (int dx=-2; dx<=2; ++dx){
        int xx2 = refl(x+dx, WW);
        S5 += sb[yy*WW+xx2];
      }
    }
    float lap = (S5 - sc)*(1.0f/48.0f) - 0.5f*sc;
    extra = sc*expf(-lap);
  }
  red[threadIdx.x] = bce; __syncthreads();
  for (int s2=128; s2>0; s2>>=1){ if (threadIdx.x<s2) red[threadIdx.x]+=red[threadIdx.x+s2]; __syncthreads(); }
  if (threadIdx.x==0) atomicAdd(&acc[1], (double)red[0]);
  __syncthreads();
  red[threadIdx.x] = extra; __syncthreads();
  for (int s2=128; s2>0; s2>>=1){ if (threadIdx.x<s2) red[threadIdx.x]+=red[threadIdx.x+s2]; __syncthreads(); }
  if (threadIdx.x==0) atomicAdd(&acc[2], (double)red[0]);
}

// ---------------- K9a: row sum-of-squares ----------------
__global__ void k_rownorm(const float* __restrict__ desc, float* __restrict__ xx){
  int t = blockIdx.x*blockDim.x + threadIdx.x;
  if (t >= BB*NPTS) return;
  const float* dptr = desc + (size_t)t*DD;
  float s = 0.f;
  for (int d = 0; d < DD; d += 4){
    float4 v = *(const float4*)(dptr + d);
    s += v.x*v.x + v.y*v.y + v.z*v.z + v.w*v.w;
  }
  xx[t] = s;
}

// ---------------- K9b: project input points (raw proj + vis) ----------------
__global__ void k_proj_points(const float* __restrict__ points, const float* __restrict__ depths,
        const float* __restrict__ poses, const float* __restrict__ Km,
        float* __restrict__ mproj, unsigned char* __restrict__ mvis){
  int t = blockIdx.x*blockDim.x + threadIdx.x;
  if (t >= BB*BB*NPTS) return;
  int i = t / (BB*NPTS); int r = t - i*(BB*NPTS); int j = r / NPTS; int n = r - j*NPTS;
  float ptx = points[((size_t)j*NPTS+n)*2+0];
  float pty = points[((size_t)j*NPTS+n)*2+1];
  Proj pr = project_point(ptx, pty, j, i, depths, poses, Km);
  mproj[(size_t)t*2+0] = (pr.u*2.0f)/(float)(WW-1) - 1.0f;
  mproj[(size_t)t*2+1] = (pr.v*2.0f)/(float)(HH-1) - 1.0f;
  mvis[t] = pr.vis ? 1 : 0;
}

// ---------------- K10: distinction (intra cosine relu mean) ----------------
__global__ __launch_bounds__(256) void k_distinction(const float* __restrict__ desc,
        const float* __restrict__ xx, double* __restrict__ acc){
  __shared__ float As[TILE][BKK+1];
  __shared__ float Bs[TILE][BKK+1];
  __shared__ float red[256];
  int b = blockIdx.z;
  int mt = blockIdx.x, nt = blockIdx.y;
  int tid = threadIdx.x;
  int tx = tid & 15, ty = tid >> 4;
  float accv[4][4] = {};
  const float* da = desc + ((size_t)b*NPTS + mt*TILE)*DD;
  const float* db = desc + ((size_t)b*NPTS + nt*TILE)*DD;
  for (int k0 = 0; k0 < DD; k0 += BKK){
    for (int l = tid; l < TILE*(BKK/4); l += 256){
      int row = l / (BKK/4); int c4 = (l - row*(BKK/4))*4;
      float4 va = *(const float4*)(da + (size_t)row*DD + k0 + c4);
      As[row][c4+0]=va.x; As[row][c4+1]=va.y; As[row][c4+2]=va.z; As[row][c4+3]=va.w;
      float4 vb = *(const float4*)(db + (size_t)row*DD + k0 + c4);
      Bs[row][c4+0]=vb.x; Bs[row][c4+1]=vb.y; Bs[row][c4+2]=vb.z; Bs[row][c4+3]=vb.w;
    }
    __syncthreads();
    for (int kk = 0; kk < BKK; ++kk){
      float a0=As[ty*4+0][kk], a1=As[ty*4+1][kk], a2=As[ty*4+2][kk], a3=As[ty*4+3][kk];
      float b0=Bs[tx*4+0][kk], b1=Bs[tx*4+1][kk], b2=Bs[tx*4+2][kk], b3=Bs[tx*4+3][kk];
      accv[0][0]+=a0*b0; accv[0][1]+=a0*b1; accv[0][2]+=a0*b2; accv[0][3]+=a0*b3;
      accv[1][0]+=a1*b0; accv[1][1]+=a1*b1; accv[1][2]+=a1*b2; accv[1][3]+=a1*b3;
      accv[2][0]+=a2*b0; accv[2][1]+=a2*b1; accv[2][2]+=a2*b2; accv[2][3]+=a2*b3;
      accv[3][0]+=a3*b0; accv[3][1]+=a3*b1; accv[3][2]+=a3*b2; accv[3][3]+=a3*b3;
    }
    __syncthreads();
  }
  float local = 0.f;
  for (int mi=0; mi<4; ++mi){
    int m = mt*TILE + ty*4 + mi;
    float xm = xx[(size_t)b*NPTS + m];
    for (int ni=0; ni<4; ++ni){
      int n = nt*TILE + tx*4 + ni;
      float den = sqrtf(fmaxf(xm * xx[(size_t)b*NPTS + n], 1e-16f));
      local += fmaxf(accv[mi][ni]/den, 0.f);
    }
  }
  red[tid] = local; __syncthreads();
  for (int s2=128; s2>0; s2>>=1){ if (tid<s2) red[tid]+=red[tid+s2]; __syncthreads(); }
  if (tid==0) atomicAdd(&acc[0], (double)red[0]);
}

// ---------------- K11: match (inter cosine + dist masks) ----------------
__global__ __launch_bounds__(256) void k_match(const float* __restrict__ desc,
        const float* __restrict__ xx, const float* __restrict__ points,
        const float* __restrict__ mproj, const unsigned char* __restrict__ mvis,
        double* __restrict__ acc, unsigned long long* __restrict__ cnts){
  int ab = blockIdx.z; int a = ab / BB, b = ab - a*BB;
  int mt = blockIdx.x, nt = blockIdx.y;
  if (nt < mt) return;   // tri mask: need m < n
  __shared__ float As[TILE][BKK+1];
  __shared__ float Bs[TILE][BKK+1];
  __shared__ float sxa[TILE], sxb[TILE];
  __shared__ float ssrc[TILE][2], sdst[TILE][2];
  __shared__ unsigned char svis[TILE];
  __shared__ float red[256];
  __shared__ unsigned int ru[256];
  int tid = threadIdx.x;
  int tx = tid & 15, ty = tid >> 4;
  if (tid < TILE){
    int m = mt*TILE + tid;
    sxa[tid] = xx[(size_t)a*NPTS + m];
    float px = points[((size_t)b*NPTS+m)*2+0];
    float py = points[((size_t)b*NPTS+m)*2+1];
    ssrc[tid][0] = ((px+1.f)*(float)(WW-1))*0.5f;
    ssrc[tid][1] = ((py+1.f)*(float)(HH-1))*0.5f;
    svis[tid] = mvis[((size_t)a*BB+b)*NPTS + m];
    int n = nt*TILE + tid;
    sxb[tid] = xx[(size_t)b*NPTS + n];
    float qx = mproj[(((size_t)a*BB+b)*NPTS+n)*2+0];
    float qy = mproj[(((size_t)a*BB+b)*NPTS+n)*2+1];
    sdst[tid][0] = ((qx+1.f)*(float)(WW-1))*0.5f;
    sdst[tid][1] = ((qy+1.f)*(float)(HH-1))*0.5f;
  }
  float accv[4][4] = {};
  const float* da = desc + ((size_t)a*NPTS + mt*TILE)*DD;
  const float* db = desc + ((size_t)b*NPTS + nt*TILE)*DD;
  for (int k0 = 0; k0 < DD; k0 += BKK){
    for (int l = tid; l < TILE*(BKK/4); l += 256){
      int row = l / (BKK/4); int c4 = (l - row*(BKK/4))*4;
      float4 va = *(const float4*)(da + (size_t)row*DD + k0 + c4);
      As[row][c4+0]=va.x; As[row][c4+1]=va.y; As[row][c4+2]=va.z; As[row][c4+3]=va.w;
      float4 vb = *(const float4*)(db + (size_t)row*DD + k0 + c4);
      Bs[row][c4+0]=vb.x; Bs[row][c4+1]=vb.y; Bs[row][c4+2]=vb.z; Bs[row][c4+3]=vb.w;
    }
    __syncthreads();
    for (int kk = 0; kk < BKK; ++kk){
      float a0=As[ty*4+0][kk], a1=As[ty*4+1][kk], a2=As[ty*4+2][kk], a3=As[ty*4+3][kk];
      float b0=Bs[tx*4+0][kk], b1=Bs[tx*4+1][kk], b2=Bs[tx*4+2][kk], b3=Bs[tx*4+3][kk];
      accv[0][0]+=a0*b0; accv[0][1]+=a0*b1; accv[0][2]+=a0*b2; accv[0][3]+=a0*b3;
      accv[1][0]+=a1*b0; accv[1][1]+=a1*b1; accv[1][2]+=a1*b2; accv[1][3]+=a1*b3;
      accv[2][0]+=a2*b0; accv[2][1]+=a2*b1; accv[2][2]+=a2*b2; accv[2][3]+=a2*b3;
      accv[3][0]+=a3*b0; accv[3][1]+=a3*b1; accv[3][2]+=a3*b2; accv[3][3]+=a3*b3;
    }
    __syncthreads();
  }
  float pos = 0.f, neg = 0.f; unsigned int pc = 0, nc = 0;
  for (int mi=0; mi<4; ++mi){
    int ml = ty*4+mi; int m = mt*TILE + ml;
    if (!svis[ml]) continue;
    float sx_ = ssrc[ml][0], sy_ = ssrc[ml][1];
    float x2 = sx_*sx_ + sy_*sy_;
    float xm = sxa[ml];
    for (int ni=0; ni<4; ++ni){
      int nl = tx*4+ni; int n = nt*TILE + nl;
      if (m >= n) continue;
      float dxv = sdst[nl][0], dyv = sdst[nl][1];
      float y2 = dxv*dxv + dyv*dyv;
      float d2 = x2 + y2 - 2.f*(sx_*dxv + sy_*dyv);
      float dist = sqrtf(fmaxf(d2, 0.f));
      float den = sqrtf(fmaxf(xm * sxb[nl], 1e-16f));
      float p = accv[mi][ni]/den;
      if (dist <= 1.0f){ pos += p; pc++; } else { neg += p; nc++; }
    }
  }
  red[tid] = pos; __syncthreads();
  for (int s2=128; s2>0; s2>>=1){ if (tid<s2) red[tid]+=red[tid+s2]; __syncthreads(); }
  if (tid==0) atomicAdd(&acc[3], (double)red[0]);
  __syncthreads();
  red[tid] = neg; __syncthreads();
  for (int s2=128; s2>0; s2>>=1){ if (tid<s2) red[tid]+=red[tid+s2]; __syncthreads(); }
  if (tid==0) atomicAdd(&acc[4], (double)red[0]);
  ru[tid] = pc; __syncthreads();
  for (int s2=128; s2>0; s2>>=1){ if (tid<s2) ru[tid]+=ru[tid+s2]; __syncthreads(); }
  if (tid==0) atomicAdd(&cnts[0], (unsigned long long)ru[0]);
  __syncthreads();
  ru[tid] = nc; __syncthreads();
  for (int s2=128; s2>0; s2>>=1){ if (tid<s2) ru[tid]+=ru[tid+s2]; __syncthreads(); }
  if (tid==0) atomicAdd(&cnts[1], (unsigned long long)ru[0]);
}

// ---------------- K12: finalize ----------------
__global__ void k_final(const double* __restrict__ acc, const unsigned long long* __restrict__ cnts,
                        float* __restrict__ out){
  double distinction = acc[0] / (double)((long long)BB*NPTS*NPTS);
  double bce = acc[1] / (double)((long long)BB*HWsz);
  double extra = acc[2] / (double)((long long)BB*HWsz);
  double cornerness = bce + 10.0*extra;
  unsigned long long pc = cnts[0], nc = cnts[1];
  double pos_mean = acc[3] / (double)(pc ? pc : 1ull);
  double neg_mean = acc[4] / (double)(nc ? nc : 1ull);
  double match = 1.0 - pos_mean + neg_mean;
  out[0] = (float)(distinction + 0.5*cornerness + match);
}

extern "C" void kernel_launch(void* const* d_in, const int* in_sizes, int n_in,
                              void* d_out, int out_size, void* d_ws, size_t ws_size,
                              hipStream_t stream) {
  (void)in_sizes; (void)n_in; (void)out_size; (void)ws_size;
  const float* desc   = (const float*)d_in[0];
  const float* points = (const float*)d_in[1];
  const float* scores = (const float*)d_in[2];
  const float* depths = (const float*)d_in[3];
  const float* poses  = (const float*)d_in[4];
  const float* Km     = (const float*)d_in[5];
  const float* imgs   = (const float*)d_in[6];
  float* out = (float*)d_out;

  const size_t S = (size_t)BB*HWsz;
  float* gray = (float*)d_ws;          // S  (later: resp)
  float* bx   = gray + S;              // S  gxx -> keep1
  float* by   = bx + S;                // S  gyy -> target
  float* bxy  = by + S;                // S  gxy
  float* resp = gray;                  // reuse
  float* keep = bx;                    // reuse
  unsigned long long* ckeys = (unsigned long long*)(bxy + S);      // BB*CAP
  unsigned int* ccnt = (unsigned int*)(ckeys + (size_t)BB*CAP);    // BB
  double* acc = (double*)(ccnt + 6);                               // 5 doubles (24B offset keeps 8-align)
  unsigned long long* cnts = (unsigned long long*)(acc + 5);       // 2
  float* cpts  = (float*)(cnts + 2);                               // BB*NC*2
  float* cvals = cpts + (size_t)BB*NC*2;                           // BB*NC
  float* xx    = cvals + (size_t)BB*NC;                            // BB*NPTS
  float* mproj = xx + (size_t)BB*NPTS;                             // BB*BB*NPTS*2
  unsigned char* mvis = (unsigned char*)(mproj + (size_t)BB*BB*NPTS*2);

  const int npx = BB*HWsz;
  dim3 blk(256);
  dim3 gpx((npx + 255)/256);

  k_gray<<<gpx, blk, 0, stream>>>(imgs, gray);
  k_sobel<<<gpx, blk, 0, stream>>>(gray, bx, by, bxy);
  k_gauss_resp<<<gpx, blk, 0, stream>>>(bx, by, bxy, resp);

  // zero target (reuses gyy buffer: must be AFTER k_gauss_resp), counters, accumulators
  hipMemsetAsync(by, 0, S*sizeof(float), stream);
  hipMemsetAsync(ccnt, 0, 6*sizeof(unsigned int), stream);
  hipMemsetAsync(acc, 0, 5*sizeof(double) + 2*sizeof(unsigned long long), stream);

  k_nms5<<<gpx, blk, 0, stream>>>(resp, keep);
  {
    int n = BB*(HH/8)*(WW/8);
    k_blockmax_compact<<<dim3((n+255)/256), blk, 0, stream>>>(keep, ckeys, ccnt);
  }
  k_top500<<<dim3(BB), dim3(1024), 0, stream>>>(ckeys, ccnt, cpts, cvals);
  {
    int n = BB*BB*NC;
    k_corner_scatter<<<dim3((n+255)/256), blk, 0, stream>>>(cpts, cvals, depths, poses, Km,
                                                            (unsigned int*)by);
  }
  k_score_reduce<<<gpx, blk, 0, stream>>>(by, scores, acc);
  {
    int n = BB*NPTS;
    k_rownorm<<<dim3((n+255)/256), blk, 0, stream>>>(desc, xx);
  }
  {
    int n = BB*BB*NPTS;
    k_proj_points<<<dim3((n+255)/256), blk, 0, stream>>>(points, depths, poses, Km, mproj, mvis);
  }
  k_distinction<<<dim3(NPTS/TILE, NPTS/TILE, BB), blk, 0, stream>>>(desc, xx, acc);
  k_match<<<dim3(NPTS/TILE, NPTS/TILE, BB*BB), blk, 0, stream>>>(desc, xx, points, mproj, mvis,
                                                                 acc, cnts);
  k_final<<<dim3(1), dim3(1), 0, stream>>>(acc, cnts, out);
}

// Round 4
// 543.344 us; speedup vs baseline: 1.1463x; 1.1463x over previous
//
#include <hip/hip_runtime.h>
#include <stdint.h>

#define BB 6
#define NPTS 1024
#define DD 128
#define HH 320
#define WW 320
#define NC 500
#define HWsz (HH*WW)
#define CAP 4096

typedef __attribute__((ext_vector_type(8))) short bf16x8;
typedef __attribute__((ext_vector_type(4))) float f32x4;

__device__ __forceinline__ int clampi(int v, int lo, int hi){ return v<lo?lo:(v>hi?hi:v); }
__device__ __forceinline__ int refl(int p, int L){ if(p<0)p=-p; if(p>=L)p=2*L-2-p; return p; }

// ---------------- projection (matches pairwise_project) ----------------
struct Proj { float u, v; int vis; };

__device__ Proj project_point(float ptx, float pty, int jsrc, int itgt,
                              const float* __restrict__ depths,
                              const float* __restrict__ poses,
                              const float* __restrict__ Km)
{
  float pxx = ((ptx + 1.0f)*(float)(WW-1))*0.5f;
  float pxy = ((pty + 1.0f)*(float)(HH-1))*0.5f;
  float rx = rintf(pxx), ry = rintf(pxy);
  rx = fminf(fmaxf(rx, 0.f), (float)(WW-1));
  ry = fminf(fmaxf(ry, 0.f), (float)(HH-1));
  int xi = (int)rx, yi = (int)ry;
  float d = depths[(size_t)jsrc*HWsz + yi*WW + xi];
  float a00=Km[0],a01=Km[1],a02=Km[2],a10=Km[3],a11=Km[4],a12=Km[5],a20=Km[6],a21=Km[7],a22=Km[8];
  float det = a00*(a11*a22 - a12*a21) - a01*(a10*a22 - a12*a20) + a02*(a10*a21 - a11*a20);
  float id_ = 1.0f/det;
  float i00 = (a11*a22 - a12*a21)*id_;
  float i01 = (a02*a21 - a01*a22)*id_;
  float i02 = (a01*a12 - a02*a11)*id_;
  float i10 = (a12*a20 - a10*a22)*id_;
  float i11 = (a00*a22 - a02*a20)*id_;
  float i12 = (a02*a10 - a00*a12)*id_;
  float i20 = (a10*a21 - a11*a20)*id_;
  float i21 = (a01*a20 - a00*a21)*id_;
  float i22 = (a00*a11 - a01*a10)*id_;
  float c0 = (i00*pxx + i01*pxy + i02)*d;
  float c1 = (i10*pxx + i11*pxy + i12)*d;
  float c2 = (i20*pxx + i21*pxy + i22)*d;
  const float* Pj = poses + (size_t)jsrc*16;
  float w0 = Pj[0]*c0 + Pj[1]*c1 + Pj[2]*c2  + Pj[3];
  float w1 = Pj[4]*c0 + Pj[5]*c1 + Pj[6]*c2  + Pj[7];
  float w2 = Pj[8]*c0 + Pj[9]*c1 + Pj[10]*c2 + Pj[11];
  const float* Pi = poses + (size_t)itgt*16;
  float dx = w0 - Pi[3], dy = w1 - Pi[7], dz = w2 - Pi[11];
  float e0 = Pi[0]*dx + Pi[4]*dy + Pi[8]*dz;
  float e1 = Pi[1]*dx + Pi[5]*dy + Pi[9]*dz;
  float e2 = Pi[2]*dx + Pi[6]*dy + Pi[10]*dz;
  float uu = a00*e0 + a01*e1 + a02*e2;
  float vv = a10*e0 + a11*e1 + a12*e2;
  float zz = a20*e0 + a21*e1 + a22*e2;
  float zs = (fabsf(zz) > 1e-6f) ? zz : 1e-6f;
  Proj r;
  r.u = uu/zs; r.v = vv/zs;
  r.vis = (zz > 0.1f) && (r.u >= 0.f) && (r.u <= (float)(WW-1)) && (r.v >= 0.f) && (r.v <= (float)(HH-1));
  return r;
}

// ---------------- K1: gray ----------------
__global__ void k_gray(const float* __restrict__ imgs, float* __restrict__ gray){
  int t = blockIdx.x*blockDim.x + threadIdx.x;
  if (t >= BB*HWsz) return;
  int b = t / HWsz, p = t - b*HWsz;
  const float* base = imgs + (size_t)b*3*HWsz;
  gray[t] = 0.299f*base[p] + 0.587f*base[HWsz+p] + 0.114f*base[2*HWsz+p];
}

// ---------------- K2: sobel (edge pad) + products ----------------
__global__ void k_sobel(const float* __restrict__ gray, float* __restrict__ gxx,
                        float* __restrict__ gyy, float* __restrict__ gxy){
  int t = blockIdx.x*blockDim.x + threadIdx.x;
  if (t >= BB*HWsz) return;
  int b = t / HWsz, p = t - b*HWsz;
  int y = p / WW, x = p - y*WW;
  const float* g = gray + (size_t)b*HWsz;
  int ym = clampi(y-1,0,HH-1), yp = clampi(y+1,0,HH-1);
  int xm = clampi(x-1,0,WW-1), xp = clampi(x+1,0,WW-1);
  float g00 = g[ym*WW+xm], g01 = g[ym*WW+x], g02 = g[ym*WW+xp];
  float g10 = g[y*WW+xm],                    g12 = g[y*WW+xp];
  float g20 = g[yp*WW+xm], g21 = g[yp*WW+x], g22 = g[yp*WW+xp];
  float gx = 0.125f*(g02-g00) + 0.25f*(g12-g10) + 0.125f*(g22-g20);
  float gy = 0.125f*(g20-g00) + 0.25f*(g21-g01) + 0.125f*(g22-g02);
  gxx[t] = gx*gx; gyy[t] = gy*gy; gxy[t] = gx*gy;
}

// ---------------- K3: gaussian 7x7 (reflect) + GFTT response ----------------
__global__ void k_gauss_resp(const float* __restrict__ gxx, const float* __restrict__ gyy,
                             const float* __restrict__ gxy, float* __restrict__ resp){
  int t = blockIdx.x*blockDim.x + threadIdx.x;
  if (t >= BB*HWsz) return;
  int b = t / HWsz, p = t - b*HWsz;
  int y = p / WW, x = p - y*WW;
  float w1[7]; float s = 0.f;
  #pragma unroll
  for (int i=0;i<7;++i){ float a=(float)i-3.f; w1[i]=expf(-0.5f*a*a); s+=w1[i]; }
  #pragma unroll
  for (int i=0;i<7;++i) w1[i] = w1[i]/s;
  const float* axx = gxx + (size_t)b*HWsz;
  const float* ayy = gyy + (size_t)b*HWsz;
  const float* axy = gxy + (size_t)b*HWsz;
  float sxx=0.f, syy=0.f, sxy=0.f;
  #pragma unroll
  for (int i=0;i<7;++i){
    int ry = refl(y+i-3, HH);
    const float* rxx = axx + (size_t)ry*WW;
    const float* ryy = ayy + (size_t)ry*WW;
    const float* rxy = axy + (size_t)ry*WW;
    float wr = w1[i];
    #pragma unroll
    for (int j=0;j<7;++j){
      int rx = refl(x+j-3, WW);
      float wc = wr*w1[j];
      sxx += wc*rxx[rx]; syy += wc*ryy[rx]; sxy += wc*rxy[rx];
    }
  }
  float tr = sxx+syy, df = sxx-syy;
  float disc = sqrtf(fmaxf(df*df + 4.f*sxy*sxy, 0.f));
  resp[t] = 0.5f*(tr - disc);
}

// ---------------- K4: 5x5 NMS (pad -inf) ----------------
__global__ void k_nms5(const float* __restrict__ resp, float* __restrict__ keep){
  int t = blockIdx.x*blockDim.x + threadIdx.x;
  if (t >= BB*HWsz) return;
  int b = t / HWsz, p = t - b*HWsz;
  int y = p / WW, x = p - y*WW;
  const float* rb = resp + (size_t)b*HWsz;
  float m = -1e30f;
  for (int dy=-2; dy<=2; ++dy){
    int yy = y+dy; if (yy<0||yy>=HH) continue;
    for (int dx=-2; dx<=2; ++dx){
      int xx2 = x+dx; if (xx2<0||xx2>=WW) continue;
      m = fmaxf(m, rb[yy*WW+xx2]);
    }
  }
  float r = rb[p];
  keep[t] = (r == m) ? r : 0.f;
}

// ---------------- K5: 8x8 block max + compact positive candidates ----------------
__global__ void k_blockmax_compact(const float* __restrict__ keep,
        unsigned long long* __restrict__ ckeys, unsigned int* __restrict__ ccnt){
  int t = blockIdx.x*blockDim.x + threadIdx.x;
  const int BLKS = (HH/8)*(WW/8);
  if (t >= BB*BLKS) return;
  int b = t / BLKS; int r = t - b*BLKS;
  int by = r / (WW/8), bx = r - by*(WW/8);
  const float* k0 = keep + (size_t)b*HWsz;
  float bm = -1e30f;
  for (int dy=0; dy<8; ++dy)
    for (int dx=0; dx<8; ++dx)
      bm = fmaxf(bm, k0[(by*8+dy)*WW + bx*8+dx]);
  if (!(bm > 0.f)) return;
  for (int dy=0; dy<8; ++dy)
    for (int dx=0; dx<8; ++dx){
      int yy = by*8+dy, xx2 = bx*8+dx;
      float v = k0[yy*WW+xx2];
      if (v == bm){
        unsigned int slot = atomicAdd(&ccnt[b], 1u);
        if (slot < CAP){
          unsigned int idx = (unsigned int)(yy*WW + xx2);
          ckeys[(size_t)b*CAP + slot] =
            ((unsigned long long)__float_as_uint(bm) << 32) |
            (unsigned long long)(0xFFFFFFFFu - idx);
        }
      }
    }
}

// ---------------- K6: bitonic top-500 per batch ----------------
__global__ __launch_bounds__(1024) void k_top500(const unsigned long long* __restrict__ ckeys,
        const unsigned int* __restrict__ ccnt, float* __restrict__ cpts, float* __restrict__ cvals){
  __shared__ unsigned long long sk[CAP];
  int b = blockIdx.x;
  int tid = threadIdx.x;
  unsigned int cnt = ccnt[b]; if (cnt > CAP) cnt = CAP;
  for (int i = tid; i < CAP; i += 1024)
    sk[i] = (i < (int)cnt) ? ckeys[(size_t)b*CAP + i] : 0ull;
  __syncthreads();
  for (int k = 2; k <= CAP; k <<= 1){
    for (int j = k >> 1; j > 0; j >>= 1){
      for (int i = tid; i < CAP; i += 1024){
        int l = i ^ j;
        if (l > i){
          unsigned long long A = sk[i], Bv = sk[l];
          bool up = ((i & k) == 0);
          if ((A > Bv) == up){ sk[i] = Bv; sk[l] = A; }
        }
      }
      __syncthreads();
    }
  }
  if (tid < NC){
    unsigned long long key = sk[CAP-1-tid];   // descending order
    float val = __uint_as_float((unsigned int)(key >> 32));
    size_t o = (size_t)b*NC + tid;
    if (val > 0.f){
      unsigned int idx = 0xFFFFFFFFu - (unsigned int)(key & 0xFFFFFFFFull);
      float fx = (float)(idx % WW), fy = (float)(idx / WW);
      cpts[o*2+0] = (fx*2.0f)/(float)(WW-1) - 1.0f;
      cpts[o*2+1] = (fy*2.0f)/(float)(HH-1) - 1.0f;
      cvals[o] = val;
    } else {
      cpts[o*2+0] = __int_as_float(0x7fc00000);
      cpts[o*2+1] = __int_as_float(0x7fc00000);
      cvals[o] = 0.f;
    }
  }
}

// ---------------- K7: corner projection + scatter-max ----------------
__global__ void k_corner_scatter(const float* __restrict__ cpts, const float* __restrict__ cvals,
        const float* __restrict__ depths, const float* __restrict__ poses,
        const float* __restrict__ Km, unsigned int* __restrict__ target){
  int t = blockIdx.x*blockDim.x + threadIdx.x;
  if (t >= BB*BB*NC) return;
  int i = t / (BB*NC); int r = t - i*(BB*NC); int j = r / NC; int n = r - j*NC;
  float val = cvals[(size_t)i*NC + n];
  float ptx = cpts[((size_t)j*NC+n)*2+0];
  float pty = cpts[((size_t)j*NC+n)*2+1];
  if (!(val > 0.f) || ptx != ptx) return;
  Proj pr = project_point(ptx, pty, j, i, depths, poses, Km);
  if (!pr.vis) return;
  float nu = (pr.u*2.0f)/(float)(WW-1) - 1.0f;
  float nv = (pr.v*2.0f)/(float)(HH-1) - 1.0f;
  float px2 = ((nu+1.0f)*(float)(WW-1))*0.5f;
  float py2 = ((nv+1.0f)*(float)(HH-1))*0.5f;
  float rx = rintf(px2), ry = rintf(py2);
  if (!(rx >= 0.f && ry >= 0.f && rx <= (float)(WW-1) && ry <= (float)(HH-1))) return;
  int wf = (int)rx, hf = (int)ry;
  atomicMax(&target[(size_t)j*HWsz + hf*WW + wf], __float_as_uint(val));
}

// ---------------- K8: target NMS + BCE + laplacian reduce ----------------
__global__ void k_score_reduce(const float* __restrict__ target, const float* __restrict__ scores,
        double* __restrict__ acc){
  __shared__ float red[256];
  int t = blockIdx.x*blockDim.x + threadIdx.x;
  float bce = 0.f, extra = 0.f;
  if (t < BB*HWsz){
    int b = t / HWsz, p = t - b*HWsz;
    int y = p / WW, x = p - y*WW;
    const float* tg = target + (size_t)b*HWsz;
    float tv = tg[p];
    float m = -1e30f;
    for (int dy=-2; dy<=2; ++dy){
      int yy = y+dy; if (yy<0||yy>=HH) continue;
      for (int dx=-2; dx<=2; ++dx){
        int xx2 = x+dx; if (xx2<0||xx2>=WW) continue;
        m = fmaxf(m, tg[yy*WW+xx2]);
      }
    }
    float tb = (tv > 0.f && tv == m) ? 1.f : 0.f;
    float sc = scores[t];
    float pc = fminf(fmaxf(sc, 1e-12f), 1.0f - 1e-12f);
    bce = -(tb*logf(pc) + (1.f-tb)*logf(1.f-pc));
    const float* sb = scores + (size_t)b*HWsz;
    float S5 = 0.f;
    for (int dy=-2; dy<=2; ++dy){
      int yy = refl(y+dy, HH);
      for (int dx=-2; dx<=2; ++dx){
        int xx2 = refl(x+dx, WW);
        S5 += sb[yy*WW+xx2];
      }
    }
    float lap = (S5 - sc)*(1.0f/48.0f) - 0.5f*sc;
    extra = sc*expf(-lap);
  }
  red[threadIdx.x] = bce; __syncthreads();
  for (int s2=128; s2>0; s2>>=1){ if (threadIdx.x<s2) red[threadIdx.x]+=red[threadIdx.x+s2]; __syncthreads(); }
  if (threadIdx.x==0) atomicAdd(&acc[1], (double)red[0]);
  __syncthreads();
  red[threadIdx.x] = extra; __syncthreads();
  for (int s2=128; s2>0; s2>>=1){ if (threadIdx.x<s2) red[threadIdx.x]+=red[threadIdx.x+s2]; __syncthreads(); }
  if (threadIdx.x==0) atomicAdd(&acc[2], (double)red[0]);
}

// ---------------- K9a: row sum-of-squares + bf16 convert ----------------
__global__ void k_rownorm_bf16(const float* __restrict__ desc, float* __restrict__ xx,
                               unsigned short* __restrict__ dbf){
  int t = blockIdx.x*blockDim.x + threadIdx.x;
  if (t >= BB*NPTS) return;
  const float* dptr = desc + (size_t)t*DD;
  unsigned short* optr = dbf + (size_t)t*DD;
  float s = 0.f;
  for (int d = 0; d < DD; d += 4){
    float4 v = *(const float4*)(dptr + d);
    s += v.x*v.x + v.y*v.y + v.z*v.z + v.w*v.w;
    // RNE f32->bf16
    unsigned int u0 = __float_as_uint(v.x); optr[d+0] = (unsigned short)((u0 + 0x7fffu + ((u0>>16)&1u)) >> 16);
    unsigned int u1 = __float_as_uint(v.y); optr[d+1] = (unsigned short)((u1 + 0x7fffu + ((u1>>16)&1u)) >> 16);
    unsigned int u2 = __float_as_uint(v.z); optr[d+2] = (unsigned short)((u2 + 0x7fffu + ((u2>>16)&1u)) >> 16);
    unsigned int u3 = __float_as_uint(v.w); optr[d+3] = (unsigned short)((u3 + 0x7fffu + ((u3>>16)&1u)) >> 16);
  }
  xx[t] = s;
}

// ---------------- K9b: project input points (raw proj + vis) ----------------
__global__ void k_proj_points(const float* __restrict__ points, const float* __restrict__ depths,
        const float* __restrict__ poses, const float* __restrict__ Km,
        float* __restrict__ mproj, unsigned char* __restrict__ mvis){
  int t = blockIdx.x*blockDim.x + threadIdx.x;
  if (t >= BB*BB*NPTS) return;
  int i = t / (BB*NPTS); int r = t - i*(BB*NPTS); int j = r / NPTS; int n = r - j*NPTS;
  float ptx = points[((size_t)j*NPTS+n)*2+0];
  float pty = points[((size_t)j*NPTS+n)*2+1];
  Proj pr = project_point(ptx, pty, j, i, depths, poses, Km);
  mproj[(size_t)t*2+0] = (pr.u*2.0f)/(float)(WW-1) - 1.0f;
  mproj[(size_t)t*2+1] = (pr.v*2.0f)/(float)(HH-1) - 1.0f;
  mvis[t] = pr.vis ? 1 : 0;
}

// ---------------- K10: distinction via MFMA ----------------
// block = 4 waves; block tile 64x64; wave tile 32x32 (2x2 frags x K=128)
__global__ __launch_bounds__(256) void k_distinction_mfma(const unsigned short* __restrict__ dbf,
        const float* __restrict__ xx, double* __restrict__ acc){
  __shared__ float red[256];
  int b = blockIdx.z;
  int tid = threadIdx.x;
  int wave = tid >> 6, lane = tid & 63;
  int wr = blockIdx.x*64 + (wave&1)*32;
  int wc = blockIdx.y*64 + (wave>>1)*32;
  int r = lane & 15, kg = lane >> 4;
  const unsigned short* da = dbf + ((size_t)b*NPTS + wr)*DD;
  const unsigned short* db = dbf + ((size_t)b*NPTS + wc)*DD;
  f32x4 accf00 = {}, accf01 = {}, accf10 = {}, accf11 = {};
  #pragma unroll
  for (int ks = 0; ks < 4; ++ks){
    int ko = ks*32 + kg*8;
    bf16x8 a0 = *(const bf16x8*)(da + (size_t)r*DD + ko);
    bf16x8 a1 = *(const bf16x8*)(da + (size_t)(r+16)*DD + ko);
    bf16x8 b0 = *(const bf16x8*)(db + (size_t)r*DD + ko);
    bf16x8 b1 = *(const bf16x8*)(db + (size_t)(r+16)*DD + ko);
    accf00 = __builtin_amdgcn_mfma_f32_16x16x32_bf16(a0, b0, accf00, 0, 0, 0);
    accf01 = __builtin_amdgcn_mfma_f32_16x16x32_bf16(a0, b1, accf01, 0, 0, 0);
    accf10 = __builtin_amdgcn_mfma_f32_16x16x32_bf16(a1, b0, accf10, 0, 0, 0);
    accf11 = __builtin_amdgcn_mfma_f32_16x16x32_bf16(a1, b1, accf11, 0, 0, 0);
  }
  const float* xb = xx + (size_t)b*NPTS;
  float xn0 = xb[wc + r], xn1 = xb[wc + 16 + r];
  float local = 0.f;
  #pragma unroll
  for (int mi = 0; mi < 2; ++mi){
    #pragma unroll
    for (int j = 0; j < 4; ++j){
      int m = wr + mi*16 + 4*kg + j;
      float xm = xb[m];
      float v0 = (mi ? accf10[j] : accf00[j]);
      float v1 = (mi ? accf11[j] : accf01[j]);
      local += fmaxf(v0 / sqrtf(fmaxf(xm*xn0, 1e-16f)), 0.f);
      local += fmaxf(v1 / sqrtf(fmaxf(xm*xn1, 1e-16f)), 0.f);
    }
  }
  red[tid] = local; __syncthreads();
  for (int s2=128; s2>0; s2>>=1){ if (tid<s2) red[tid]+=red[tid+s2]; __syncthreads(); }
  if (tid==0) atomicAdd(&acc[0], (double)red[0]);
}

// ---------------- K11: match via MFMA ----------------
__global__ __launch_bounds__(256) void k_match_mfma(const unsigned short* __restrict__ dbf,
        const float* __restrict__ xx, const float* __restrict__ points,
        const float* __restrict__ mproj, const unsigned char* __restrict__ mvis,
        double* __restrict__ acc, unsigned long long* __restrict__ cnts){
  int ab = blockIdx.z; int a = ab / BB, b = ab - a*BB;
  int mt = blockIdx.x, nt = blockIdx.y;
  if (nt < mt) return;   // global tri: tiles entirely below diagonal skipped
  __shared__ float red[256];
  __shared__ unsigned int ru[256];
  int tid = threadIdx.x;
  int wave = tid >> 6, lane = tid & 63;
  int wr = mt*64 + (wave&1)*32;
  int wc = nt*64 + (wave>>1)*32;
  int r = lane & 15, kg = lane >> 4;
  const unsigned short* da = dbf + ((size_t)a*NPTS + wr)*DD;
  const unsigned short* db = dbf + ((size_t)b*NPTS + wc)*DD;
  f32x4 accf00 = {}, accf01 = {}, accf10 = {}, accf11 = {};
  #pragma unroll
  for (int ks = 0; ks < 4; ++ks){
    int ko = ks*32 + kg*8;
    bf16x8 a0 = *(const bf16x8*)(da + (size_t)r*DD + ko);
    bf16x8 a1 = *(const bf16x8*)(da + (size_t)(r+16)*DD + ko);
    bf16x8 b0 = *(const bf16x8*)(db + (size_t)r*DD + ko);
    bf16x8 b1 = *(const bf16x8*)(db + (size_t)(r+16)*DD + ko);
    accf00 = __builtin_amdgcn_mfma_f32_16x16x32_bf16(a0, b0, accf00, 0, 0, 0);
    accf01 = __builtin_amdgcn_mfma_f32_16x16x32_bf16(a0, b1, accf01, 0, 0, 0);
    accf10 = __builtin_amdgcn_mfma_f32_16x16x32_bf16(a1, b0, accf10, 0, 0, 0);
    accf11 = __builtin_amdgcn_mfma_f32_16x16x32_bf16(a1, b1, accf11, 0, 0, 0);
  }
  // per-lane n-side data (2 cols)
  float nxx[2], ndx[2], ndy[2];
  #pragma unroll
  for (int ni = 0; ni < 2; ++ni){
    int n = wc + ni*16 + r;
    nxx[ni] = xx[(size_t)b*NPTS + n];
    float qx = mproj[(((size_t)a*BB+b)*NPTS+n)*2+0];
    float qy = mproj[(((size_t)a*BB+b)*NPTS+n)*2+1];
    ndx[ni] = (qx+1.f)*(float)(WW-1)*0.5f;
    ndy[ni] = (qy+1.f)*(float)(HH-1)*0.5f;
  }
  float pos = 0.f, neg = 0.f; unsigned int pc = 0, nc = 0;
  #pragma unroll
  for (int mi = 0; mi < 2; ++mi){
    #pragma unroll
    for (int j = 0; j < 4; ++j){
      int m = wr + mi*16 + 4*kg + j;
      if (!mvis[((size_t)a*BB+b)*NPTS + m]) continue;
      float px = points[((size_t)b*NPTS+m)*2+0];
      float py = points[((size_t)b*NPTS+m)*2+1];
      float sx = (px+1.f)*(float)(WW-1)*0.5f;
      float sy = (py+1.f)*(float)(HH-1)*0.5f;
      float x2 = sx*sx + sy*sy;
      float xm = xx[(size_t)a*NPTS + m];
      #pragma unroll
      for (int ni = 0; ni < 2; ++ni){
        int n = wc + ni*16 + r;
        if (m >= n) continue;
        float dv = (mi ? (ni ? accf11[j] : accf10[j]) : (ni ? accf01[j] : accf00[j]));
        float y2 = ndx[ni]*ndx[ni] + ndy[ni]*ndy[ni];
        float d2 = x2 + y2 - 2.f*(sx*ndx[ni] + sy*ndy[ni]);
        float dist = sqrtf(fmaxf(d2, 0.f));
        float den = sqrtf(fmaxf(xm * nxx[ni], 1e-16f));
        float p = dv/den;
        if (dist <= 1.0f){ pos += p; pc++; } else { neg += p; nc++; }
      }
    }
  }
  red[tid] = pos; __syncthreads();
  for (int s2=128; s2>0; s2>>=1){ if (tid<s2) red[tid]+=red[tid+s2]; __syncthreads(); }
  if (tid==0) atomicAdd(&acc[3], (double)red[0]);
  __syncthreads();
  red[tid] = neg; __syncthreads();
  for (int s2=128; s2>0; s2>>=1){ if (tid<s2) red[tid]+=red[tid+s2]; __syncthreads(); }
  if (tid==0) atomicAdd(&acc[4], (double)red[0]);
  ru[tid] = pc; __syncthreads();
  for (int s2=128; s2>0; s2>>=1){ if (tid<s2) ru[tid]+=ru[tid+s2]; __syncthreads(); }
  if (tid==0) atomicAdd(&cnts[0], (unsigned long long)ru[0]);
  __syncthreads();
  ru[tid] = nc; __syncthreads();
  for (int s2=128; s2>0; s2>>=1){ if (tid<s2) ru[tid]+=ru[tid+s2]; __syncthreads(); }
  if (tid==0) atomicAdd(&cnts[1], (unsigned long long)ru[0]);
}

// ---------------- K12: finalize ----------------
__global__ void k_final(const double* __restrict__ acc, const unsigned long long* __restrict__ cnts,
                        float* __restrict__ out){
  double distinction = acc[0] / (double)((long long)BB*NPTS*NPTS);
  double bce = acc[1] / (double)((long long)BB*HWsz);
  double extra = acc[2] / (double)((long long)BB*HWsz);
  double cornerness = bce + 10.0*extra;
  unsigned long long pc = cnts[0], nc = cnts[1];
  double pos_mean = acc[3] / (double)(pc ? pc : 1ull);
  double neg_mean = acc[4] / (double)(nc ? nc : 1ull);
  double match = 1.0 - pos_mean + neg_mean;
  out[0] = (float)(distinction + 0.5*cornerness + match);
}

extern "C" void kernel_launch(void* const* d_in, const int* in_sizes, int n_in,
                              void* d_out, int out_size, void* d_ws, size_t ws_size,
                              hipStream_t stream) {
  (void)in_sizes; (void)n_in; (void)out_size; (void)ws_size;
  const float* desc   = (const float*)d_in[0];
  const float* points = (const float*)d_in[1];
  const float* scores = (const float*)d_in[2];
  const float* depths = (const float*)d_in[3];
  const float* poses  = (const float*)d_in[4];
  const float* Km     = (const float*)d_in[5];
  const float* imgs   = (const float*)d_in[6];
  float* out = (float*)d_out;

  const size_t S = (size_t)BB*HWsz;
  float* gray = (float*)d_ws;          // S  (later: resp)
  float* bx   = gray + S;              // S  gxx -> keep
  float* by   = bx + S;                // S  gyy -> target
  float* bxy  = by + S;                // S  gxy
  float* resp = gray;                  // reuse
  float* keep = bx;                    // reuse
  unsigned long long* ckeys = (unsigned long long*)(bxy + S);      // BB*CAP
  unsigned int* ccnt = (unsigned int*)(ckeys + (size_t)BB*CAP);    // 6
  double* acc = (double*)(ccnt + 6);                               // 5 doubles
  unsigned long long* cnts = (unsigned long long*)(acc + 5);       // 2
  float* cpts  = (float*)(cnts + 2);                               // BB*NC*2
  float* cvals = cpts + (size_t)BB*NC*2;                           // BB*NC
  float* xx    = cvals + (size_t)BB*NC;                            // BB*NPTS
  float* mproj = xx + (size_t)BB*NPTS;                             // BB*BB*NPTS*2
  unsigned char* mvis = (unsigned char*)(mproj + (size_t)BB*BB*NPTS*2); // BB*BB*NPTS (36864B, 16-aligned end)
  unsigned short* dbf = (unsigned short*)(mvis + (size_t)BB*BB*NPTS);   // BB*NPTS*DD bf16

  const int npx = BB*HWsz;
  dim3 blk(256);
  dim3 gpx((npx + 255)/256);

  k_gray<<<gpx, blk, 0, stream>>>(imgs, gray);
  k_sobel<<<gpx, blk, 0, stream>>>(gray, bx, by, bxy);
  k_gauss_resp<<<gpx, blk, 0, stream>>>(bx, by, bxy, resp);

  // zero target (reuses gyy buffer: must be AFTER k_gauss_resp), counters, accumulators
  hipMemsetAsync(by, 0, S*sizeof(float), stream);
  hipMemsetAsync(ccnt, 0, 6*sizeof(unsigned int), stream);
  hipMemsetAsync(acc, 0, 5*sizeof(double) + 2*sizeof(unsigned long long), stream);

  k_nms5<<<gpx, blk, 0, stream>>>(resp, keep);
  {
    int n = BB*(HH/8)*(WW/8);
    k_blockmax_compact<<<dim3((n+255)/256), blk, 0, stream>>>(keep, ckeys, ccnt);
  }
  k_top500<<<dim3(BB), dim3(1024), 0, stream>>>(ckeys, ccnt, cpts, cvals);
  {
    int n = BB*BB*NC;
    k_corner_scatter<<<dim3((n+255)/256), blk, 0, stream>>>(cpts, cvals, depths, poses, Km,
                                                            (unsigned int*)by);
  }
  k_score_reduce<<<gpx, blk, 0, stream>>>(by, scores, acc);
  {
    int n = BB*NPTS;
    k_rownorm_bf16<<<dim3((n+255)/256), blk, 0, stream>>>(desc, xx, dbf);
  }
  {
    int n = BB*BB*NPTS;
    k_proj_points<<<dim3((n+255)/256), blk, 0, stream>>>(points, depths, poses, Km, mproj, mvis);
  }
  k_distinction_mfma<<<dim3(NPTS/64, NPTS/64, BB), blk, 0, stream>>>(dbf, xx, acc);
  k_match_mfma<<<dim3(NPTS/64, NPTS/64, BB*BB), blk, 0, stream>>>(dbf, xx, points, mproj, mvis,
                                                                  acc, cnts);
  k_final<<<dim3(1), dim3(1), 0, stream>>>(acc, cnts, out);
}

// Round 6
// 420.807 us; speedup vs baseline: 1.4800x; 1.2912x over previous
//
#include <hip/hip_runtime.h>
#include <stdint.h>

#define BB 6
#define NPTS 1024
#define DD 128
#define HH 320
#define WW 320
#define NC 500
#define HWsz (HH*WW)
#define CAP 2048

typedef __attribute__((ext_vector_type(8))) short bf16x8;
typedef __attribute__((ext_vector_type(4))) float f32x4;

__device__ __forceinline__ int clampi(int v, int lo, int hi){ return v<lo?lo:(v>hi?hi:v); }
__device__ __forceinline__ int refl(int p, int L){ if(p<0)p=-p; if(p>=L)p=2*L-2-p; return p; }

__device__ __forceinline__ float wave_sum(float v){
  #pragma unroll
  for (int o = 32; o > 0; o >>= 1) v += __shfl_xor(v, o, 64);
  return v;
}

// 7-tap gaussian weights (sigma=1), normalized; constants from double math.
__device__ __constant__ float GW[7] = {
  0.0044330481f, 0.0540055850f, 0.2420362300f, 0.3990502700f,
  0.2420362300f, 0.0540055850f, 0.0044330481f };

// ---------------- projection (matches pairwise_project) ----------------
struct Proj { float u, v; int vis; };

__device__ Proj project_point(float ptx, float pty, int jsrc, int itgt,
                              const float* __restrict__ depths,
                              const float* __restrict__ poses,
                              const float* __restrict__ Km)
{
  float pxx = ((ptx + 1.0f)*(float)(WW-1))*0.5f;
  float pxy = ((pty + 1.0f)*(float)(HH-1))*0.5f;
  float rx = rintf(pxx), ry = rintf(pxy);
  rx = fminf(fmaxf(rx, 0.f), (float)(WW-1));
  ry = fminf(fmaxf(ry, 0.f), (float)(HH-1));
  int xi = (int)rx, yi = (int)ry;
  float d = depths[(size_t)jsrc*HWsz + yi*WW + xi];
  float a00=Km[0],a01=Km[1],a02=Km[2],a10=Km[3],a11=Km[4],a12=Km[5],a20=Km[6],a21=Km[7],a22=Km[8];
  float det = a00*(a11*a22 - a12*a21) - a01*(a10*a22 - a12*a20) + a02*(a10*a21 - a11*a20);
  float id_ = 1.0f/det;
  float i00 = (a11*a22 - a12*a21)*id_;
  float i01 = (a02*a21 - a01*a22)*id_;
  float i02 = (a01*a12 - a02*a11)*id_;
  float i10 = (a12*a20 - a10*a22)*id_;
  float i11 = (a00*a22 - a02*a20)*id_;
  float i12 = (a02*a10 - a00*a12)*id_;
  float i20 = (a10*a21 - a11*a20)*id_;
  float i21 = (a01*a20 - a00*a21)*id_;
  float i22 = (a00*a11 - a01*a10)*id_;
  float c0 = (i00*pxx + i01*pxy + i02)*d;
  float c1 = (i10*pxx + i11*pxy + i12)*d;
  float c2 = (i20*pxx + i21*pxy + i22)*d;
  const float* Pj = poses + (size_t)jsrc*16;
  float w0 = Pj[0]*c0 + Pj[1]*c1 + Pj[2]*c2  + Pj[3];
  float w1 = Pj[4]*c0 + Pj[5]*c1 + Pj[6]*c2  + Pj[7];
  float w2 = Pj[8]*c0 + Pj[9]*c1 + Pj[10]*c2 + Pj[11];
  const float* Pi = poses + (size_t)itgt*16;
  float dx = w0 - Pi[3], dy = w1 - Pi[7], dz = w2 - Pi[11];
  float e0 = Pi[0]*dx + Pi[4]*dy + Pi[8]*dz;
  float e1 = Pi[1]*dx + Pi[5]*dy + Pi[9]*dz;
  float e2 = Pi[2]*dx + Pi[6]*dy + Pi[10]*dz;
  float uu = a00*e0 + a01*e1 + a02*e2;
  float vv = a10*e0 + a11*e1 + a12*e2;
  float zz = a20*e0 + a21*e1 + a22*e2;
  float zs = (fabsf(zz) > 1e-6f) ? zz : 1e-6f;
  Proj r;
  r.u = uu/zs; r.v = vv/zs;
  r.vis = (zz > 0.1f) && (r.u >= 0.f) && (r.u <= (float)(WW-1)) && (r.v >= 0.f) && (r.v <= (float)(HH-1));
  return r;
}

// ---------------- K1: gray ----------------
__global__ void k_gray(const float* __restrict__ imgs, float* __restrict__ gray){
  int t = blockIdx.x*blockDim.x + threadIdx.x;
  if (t >= BB*HWsz) return;
  int b = t / HWsz, p = t - b*HWsz;
  const float* base = imgs + (size_t)b*3*HWsz;
  gray[t] = 0.299f*base[p] + 0.587f*base[HWsz+p] + 0.114f*base[2*HWsz+p];
}

// ---------------- K2: sobel (edge pad) + products ----------------
__global__ void k_sobel(const float* __restrict__ gray, float* __restrict__ gxx,
                        float* __restrict__ gyy, float* __restrict__ gxy){
  int t = blockIdx.x*blockDim.x + threadIdx.x;
  if (t >= BB*HWsz) return;
  int b = t / HWsz, p = t - b*HWsz;
  int y = p / WW, x = p - y*WW;
  const float* g = gray + (size_t)b*HWsz;
  int ym = clampi(y-1,0,HH-1), yp = clampi(y+1,0,HH-1);
  int xm = clampi(x-1,0,WW-1), xp = clampi(x+1,0,WW-1);
  float g00 = g[ym*WW+xm], g01 = g[ym*WW+x], g02 = g[ym*WW+xp];
  float g10 = g[y*WW+xm],                    g12 = g[y*WW+xp];
  float g20 = g[yp*WW+xm], g21 = g[yp*WW+x], g22 = g[yp*WW+xp];
  float gx = 0.125f*(g02-g00) + 0.25f*(g12-g10) + 0.125f*(g22-g20);
  float gy = 0.125f*(g20-g00) + 0.25f*(g21-g01) + 0.125f*(g22-g02);
  gxx[t] = gx*gx; gyy[t] = gy*gy; gxy[t] = gx*gy;
}

// ---------------- K3: gaussian 7x7 (reflect) + GFTT response ----------------
__global__ void k_gauss_resp(const float* __restrict__ gxx, const float* __restrict__ gyy,
                             const float* __restrict__ gxy, float* __restrict__ resp){
  int t = blockIdx.x*blockDim.x + threadIdx.x;
  if (t >= BB*HWsz) return;
  int b = t / HWsz, p = t - b*HWsz;
  int y = p / WW, x = p - y*WW;
  const float* axx = gxx + (size_t)b*HWsz;
  const float* ayy = gyy + (size_t)b*HWsz;
  const float* axy = gxy + (size_t)b*HWsz;
  float sxx=0.f, syy=0.f, sxy=0.f;
  if (y >= 3 && y < HH-3 && x >= 3 && x < WW-3){
    int base = (y-3)*WW + (x-3);
    #pragma unroll
    for (int i=0;i<7;++i){
      const float* rxx = axx + base + i*WW;
      const float* ryy = ayy + base + i*WW;
      const float* rxy = axy + base + i*WW;
      float wr = GW[i];
      #pragma unroll
      for (int j=0;j<7;++j){
        float wc = wr*GW[j];
        sxx += wc*rxx[j]; syy += wc*ryy[j]; sxy += wc*rxy[j];
      }
    }
  } else {
    #pragma unroll
    for (int i=0;i<7;++i){
      int ry = refl(y+i-3, HH);
      const float* rxx = axx + (size_t)ry*WW;
      const float* ryy = ayy + (size_t)ry*WW;
      const float* rxy = axy + (size_t)ry*WW;
      float wr = GW[i];
      #pragma unroll
      for (int j=0;j<7;++j){
        int rx = refl(x+j-3, WW);
        float wc = wr*GW[j];
        sxx += wc*rxx[rx]; syy += wc*ryy[rx]; sxy += wc*rxy[rx];
      }
    }
  }
  float tr = sxx+syy, df = sxx-syy;
  float disc = sqrtf(fmaxf(df*df + 4.f*sxy*sxy, 0.f));
  resp[t] = 0.5f*(tr - disc);
}

// ---------------- K4: 5x5 NMS (pad -inf) ----------------
__global__ void k_nms5(const float* __restrict__ resp, float* __restrict__ keep){
  int t = blockIdx.x*blockDim.x + threadIdx.x;
  if (t >= BB*HWsz) return;
  int b = t / HWsz, p = t - b*HWsz;
  int y = p / WW, x = p - y*WW;
  const float* rb = resp + (size_t)b*HWsz;
  float m = -1e30f;
  if (y >= 2 && y < HH-2 && x >= 2 && x < WW-2){
    int base = (y-2)*WW + (x-2);
    #pragma unroll
    for (int dy=0; dy<5; ++dy){
      const float* rr = rb + base + dy*WW;
      #pragma unroll
      for (int dx=0; dx<5; ++dx) m = fmaxf(m, rr[dx]);
    }
  } else {
    for (int dy=-2; dy<=2; ++dy){
      int yy = y+dy; if (yy<0||yy>=HH) continue;
      for (int dx=-2; dx<=2; ++dx){
        int xx2 = x+dx; if (xx2<0||xx2>=WW) continue;
        m = fmaxf(m, rb[yy*WW+xx2]);
      }
    }
  }
  float r = rb[p];
  keep[t] = (r == m) ? r : 0.f;
}

// ---------------- K5: 8x8 block max + compact positive candidates ----------------
__global__ void k_blockmax_compact(const float* __restrict__ keep,
        unsigned long long* __restrict__ ckeys, unsigned int* __restrict__ ccnt){
  int t = blockIdx.x*blockDim.x + threadIdx.x;
  const int BLKS = (HH/8)*(WW/8);
  if (t >= BB*BLKS) return;
  int b = t / BLKS; int r = t - b*BLKS;
  int by = r / (WW/8), bx = r - by*(WW/8);
  const float* k0 = keep + (size_t)b*HWsz;
  float bm = -1e30f;
  for (int dy=0; dy<8; ++dy)
    for (int dx=0; dx<8; ++dx)
      bm = fmaxf(bm, k0[(by*8+dy)*WW + bx*8+dx]);
  if (!(bm > 0.f)) return;
  for (int dy=0; dy<8; ++dy)
    for (int dx=0; dx<8; ++dx){
      int yy = by*8+dy, xx2 = bx*8+dx;
      float v = k0[yy*WW+xx2];
      if (v == bm){
        unsigned int slot = atomicAdd(&ccnt[b], 1u);
        if (slot < CAP){
          unsigned int idx = (unsigned int)(yy*WW + xx2);
          ckeys[(size_t)b*CAP + slot] =
            ((unsigned long long)__float_as_uint(bm) << 32) |
            (unsigned long long)(0xFFFFFFFFu - idx);
        }
      }
    }
}

// ---------------- K6: bitonic top-500 per batch (CAP=2048) ----------------
__global__ __launch_bounds__(1024) void k_top500(const unsigned long long* __restrict__ ckeys,
        const unsigned int* __restrict__ ccnt, float* __restrict__ cpts, float* __restrict__ cvals){
  __shared__ unsigned long long sk[CAP];
  int b = blockIdx.x;
  int tid = threadIdx.x;
  unsigned int cnt = ccnt[b]; if (cnt > CAP) cnt = CAP;
  for (int i = tid; i < CAP; i += 1024)
    sk[i] = (i < (int)cnt) ? ckeys[(size_t)b*CAP + i] : 0ull;
  __syncthreads();
  for (int k = 2; k <= CAP; k <<= 1){
    for (int j = k >> 1; j > 0; j >>= 1){
      for (int i = tid; i < CAP; i += 1024){
        int l = i ^ j;
        if (l > i){
          unsigned long long A = sk[i], Bv = sk[l];
          bool up = ((i & k) == 0);
          if ((A > Bv) == up){ sk[i] = Bv; sk[l] = A; }
        }
      }
      __syncthreads();
    }
  }
  if (tid < NC){
    unsigned long long key = sk[CAP-1-tid];   // descending order
    float val = __uint_as_float((unsigned int)(key >> 32));
    size_t o = (size_t)b*NC + tid;
    if (val > 0.f){
      unsigned int idx = 0xFFFFFFFFu - (unsigned int)(key & 0xFFFFFFFFull);
      float fx = (float)(idx % WW), fy = (float)(idx / WW);
      cpts[o*2+0] = (fx*2.0f)/(float)(WW-1) - 1.0f;
      cpts[o*2+1] = (fy*2.0f)/(float)(HH-1) - 1.0f;
      cvals[o] = val;
    } else {
      cpts[o*2+0] = __int_as_float(0x7fc00000);
      cpts[o*2+1] = __int_as_float(0x7fc00000);
      cvals[o] = 0.f;
    }
  }
}

// ---------------- K7: corner projection + scatter-max ----------------
__global__ void k_corner_scatter(const float* __restrict__ cpts, const float* __restrict__ cvals,
        const float* __restrict__ depths, const float* __restrict__ poses,
        const float* __restrict__ Km, unsigned int* __restrict__ target){
  int t = blockIdx.x*blockDim.x + threadIdx.x;
  if (t >= BB*BB*NC) return;
  int i = t / (BB*NC); int r = t - i*(BB*NC); int j = r / NC; int n = r - j*NC;
  float val = cvals[(size_t)i*NC + n];
  float ptx = cpts[((size_t)j*NC+n)*2+0];
  float pty = cpts[((size_t)j*NC+n)*2+1];
  if (!(val > 0.f) || ptx != ptx) return;
  Proj pr = project_point(ptx, pty, j, i, depths, poses, Km);
  if (!pr.vis) return;
  float nu = (pr.u*2.0f)/(float)(WW-1) - 1.0f;
  float nv = (pr.v*2.0f)/(float)(HH-1) - 1.0f;
  float px2 = ((nu+1.0f)*(float)(WW-1))*0.5f;
  float py2 = ((nv+1.0f)*(float)(HH-1))*0.5f;
  float rx = rintf(px2), ry = rintf(py2);
  if (!(rx >= 0.f && ry >= 0.f && rx <= (float)(WW-1) && ry <= (float)(HH-1))) return;
  int wf = (int)rx, hf = (int)ry;
  atomicMax(&target[(size_t)j*HWsz + hf*WW + wf], __float_as_uint(val));
}

// ---------------- K8: target NMS + BCE + laplacian reduce ----------------
__global__ void k_score_reduce(const float* __restrict__ target, const float* __restrict__ scores,
        double* __restrict__ acc){
  __shared__ float rb[4][2];
  int t = blockIdx.x*blockDim.x + threadIdx.x;
  float bce = 0.f, extra = 0.f;
  if (t < BB*HWsz){
    int b = t / HWsz, p = t - b*HWsz;
    int y = p / WW, x = p - y*WW;
    const float* tg = target + (size_t)b*HWsz;
    const float* sb = scores + (size_t)b*HWsz;
    float tv = tg[p];
    float m = -1e30f;
    float S5 = 0.f;
    if (y >= 2 && y < HH-2 && x >= 2 && x < WW-2){
      int base = (y-2)*WW + (x-2);
      #pragma unroll
      for (int dy=0; dy<5; ++dy){
        const float* tr = tg + base + dy*WW;
        const float* sr = sb + base + dy*WW;
        #pragma unroll
        for (int dx=0; dx<5; ++dx){ m = fmaxf(m, tr[dx]); S5 += sr[dx]; }
      }
    } else {
      for (int dy=-2; dy<=2; ++dy){
        int yy = y+dy; if (yy<0||yy>=HH) continue;
        for (int dx=-2; dx<=2; ++dx){
          int xx2 = x+dx; if (xx2<0||xx2>=WW) continue;
          m = fmaxf(m, tg[yy*WW+xx2]);
        }
      }
      for (int dy=-2; dy<=2; ++dy){
        int yy = refl(y+dy, HH);
        for (int dx=-2; dx<=2; ++dx){
          int xx2 = refl(x+dx, WW);
          S5 += sb[yy*WW+xx2];
        }
      }
    }
    float tb = (tv > 0.f && tv == m) ? 1.f : 0.f;
    float sc = sb[p];
    float pc = fminf(fmaxf(sc, 1e-12f), 1.0f - 1e-12f);
    bce = -(tb*logf(pc) + (1.f-tb)*logf(1.f-pc));
    float lap = (S5 - sc)*(1.0f/48.0f) - 0.5f*sc;
    extra = sc*expf(-lap);
  }
  bce = wave_sum(bce); extra = wave_sum(extra);
  int wave = threadIdx.x >> 6, lane = threadIdx.x & 63;
  if (lane == 0){ rb[wave][0] = bce; rb[wave][1] = extra; }
  __syncthreads();
  if (threadIdx.x == 0){
    float B0 = rb[0][0]+rb[1][0]+rb[2][0]+rb[3][0];
    float E0 = rb[0][1]+rb[1][1]+rb[2][1]+rb[3][1];
    atomicAdd(&acc[1], (double)B0);
    atomicAdd(&acc[2], (double)E0);
  }
}

// ---------------- K9a: row sum-of-squares + bf16 convert ----------------
__global__ void k_rownorm_bf16(const float* __restrict__ desc, float* __restrict__ xx,
                               unsigned short* __restrict__ dbf){
  int t = blockIdx.x*blockDim.x + threadIdx.x;
  if (t >= BB*NPTS) return;
  const float* dptr = desc + (size_t)t*DD;
  unsigned short* optr = dbf + (size_t)t*DD;
  float s = 0.f;
  for (int d = 0; d < DD; d += 4){
    float4 v = *(const float4*)(dptr + d);
    s += v.x*v.x + v.y*v.y + v.z*v.z + v.w*v.w;
    unsigned int u0 = __float_as_uint(v.x); optr[d+0] = (unsigned short)((u0 + 0x7fffu + ((u0>>16)&1u)) >> 16);
    unsigned int u1 = __float_as_uint(v.y); optr[d+1] = (unsigned short)((u1 + 0x7fffu + ((u1>>16)&1u)) >> 16);
    unsigned int u2 = __float_as_uint(v.z); optr[d+2] = (unsigned short)((u2 + 0x7fffu + ((u2>>16)&1u)) >> 16);
    unsigned int u3 = __float_as_uint(v.w); optr[d+3] = (unsigned short)((u3 + 0x7fffu + ((u3>>16)&1u)) >> 16);
  }
  xx[t] = s;
}

// ---------------- K9b: project input points (raw proj + vis) ----------------
__global__ void k_proj_points(const float* __restrict__ points, const float* __restrict__ depths,
        const float* __restrict__ poses, const float* __restrict__ Km,
        float* __restrict__ mproj, unsigned char* __restrict__ mvis){
  int t = blockIdx.x*blockDim.x + threadIdx.x;
  if (t >= BB*BB*NPTS) return;
  int i = t / (BB*NPTS); int r = t - i*(BB*NPTS); int j = r / NPTS; int n = r - j*NPTS;
  float ptx = points[((size_t)j*NPTS+n)*2+0];
  float pty = points[((size_t)j*NPTS+n)*2+1];
  Proj pr = project_point(ptx, pty, j, i, depths, poses, Km);
  mproj[(size_t)t*2+0] = (pr.u*2.0f)/(float)(WW-1) - 1.0f;
  mproj[(size_t)t*2+1] = (pr.v*2.0f)/(float)(HH-1) - 1.0f;
  mvis[t] = pr.vis ? 1 : 0;
}

// ---------------- K10: distinction via MFMA (multi-tile blocks) ----------------
// grid (16 mt, 2 nh, BB); block = 4 waves; each block: 8 column tiles
__global__ __launch_bounds__(256) void k_distinction_mfma(const unsigned short* __restrict__ dbf,
        const float* __restrict__ xx, double* __restrict__ acc){
  __shared__ float rb[4];
  int b = blockIdx.z;
  int mt = blockIdx.x, nh = blockIdx.y;
  int tid = threadIdx.x;
  int wave = tid >> 6, lane = tid & 63;
  int wr = mt*64 + (wave&1)*32;
  int wco = (wave>>1)*32;
  int r = lane & 15, kg = lane >> 4;
  const unsigned short* descb = dbf + (size_t)b*NPTS*DD;
  const float* xb = xx + (size_t)b*NPTS;
  // A frags + m-side norms (loaded once)
  bf16x8 af[4][2];
  #pragma unroll
  for (int ks = 0; ks < 4; ++ks){
    int ko = ks*32 + kg*8;
    af[ks][0] = *(const bf16x8*)(descb + (size_t)(wr+r)*DD + ko);
    af[ks][1] = *(const bf16x8*)(descb + (size_t)(wr+16+r)*DD + ko);
  }
  float mxx[2][4];
  #pragma unroll
  for (int mi = 0; mi < 2; ++mi)
    #pragma unroll
    for (int j = 0; j < 4; ++j)
      mxx[mi][j] = xb[wr + mi*16 + 4*kg + j];
  float local = 0.f;
  for (int nt = nh*8; nt < nh*8+8; ++nt){
    int wc = nt*64 + wco;
    float xn0 = xb[wc + r], xn1 = xb[wc + 16 + r];
    f32x4 c00 = {}, c01 = {}, c10 = {}, c11 = {};
    #pragma unroll
    for (int ks = 0; ks < 4; ++ks){
      int ko = ks*32 + kg*8;
      bf16x8 b0 = *(const bf16x8*)(descb + (size_t)(wc+r)*DD + ko);
      bf16x8 b1 = *(const bf16x8*)(descb + (size_t)(wc+16+r)*DD + ko);
      c00 = __builtin_amdgcn_mfma_f32_16x16x32_bf16(af[ks][0], b0, c00, 0, 0, 0);
      c01 = __builtin_amdgcn_mfma_f32_16x16x32_bf16(af[ks][0], b1, c01, 0, 0, 0);
      c10 = __builtin_amdgcn_mfma_f32_16x16x32_bf16(af[ks][1], b0, c10, 0, 0, 0);
      c11 = __builtin_amdgcn_mfma_f32_16x16x32_bf16(af[ks][1], b1, c11, 0, 0, 0);
    }
    #pragma unroll
    for (int mi = 0; mi < 2; ++mi){
      #pragma unroll
      for (int j = 0; j < 4; ++j){
        float xm = mxx[mi][j];
        float v0 = (mi ? c10[j] : c00[j]);
        float v1 = (mi ? c11[j] : c01[j]);
        local += fmaxf(v0 / sqrtf(fmaxf(xm*xn0, 1e-16f)), 0.f);
        local += fmaxf(v1 / sqrtf(fmaxf(xm*xn1, 1e-16f)), 0.f);
      }
    }
  }
  local = wave_sum(local);
  if (lane == 0) rb[wave] = local;
  __syncthreads();
  if (tid == 0) atomicAdd(&acc[0], (double)(rb[0]+rb[1]+rb[2]+rb[3]));
}

// ---------------- K11: match via MFMA (balanced multi-tile blocks) ----------------
// grid (8 pair, 1, 36); block p owns row-tiles {p, 15-p} -> 17 tiles total
__global__ __launch_bounds__(256) void k_match_mfma(const unsigned short* __restrict__ dbf,
        const float* __restrict__ xx, const float* __restrict__ points,
        const float* __restrict__ mproj, const unsigned char* __restrict__ mvis,
        double* __restrict__ acc, unsigned long long* __restrict__ cnts){
  __shared__ float rb[4][4];
  int ab = blockIdx.z; int a = ab / BB, b = ab - a*BB;
  int pairIdx = blockIdx.x;
  int tid = threadIdx.x;
  int wave = tid >> 6, lane = tid & 63;
  int wro = (wave&1)*32, wco = (wave>>1)*32;
  int r = lane & 15, kg = lane >> 4;
  const unsigned short* descA = dbf + (size_t)a*NPTS*DD;
  const unsigned short* descB = dbf + (size_t)b*NPTS*DD;
  const float* xxa = xx + (size_t)a*NPTS;
  const float* xxb = xx + (size_t)b*NPTS;
  const float* pts = points + (size_t)b*NPTS*2;
  const float* mp  = mproj + (((size_t)a*BB+b)*NPTS)*2;
  const unsigned char* mv = mvis + ((size_t)a*BB+b)*NPTS;
  float pos = 0.f, neg = 0.f, pcf = 0.f, ncf = 0.f;
  #pragma unroll
  for (int seg = 0; seg < 2; ++seg){
    int mt = seg ? (15 - pairIdx) : pairIdx;
    int wr = mt*64 + wro;
    bf16x8 af[4][2];
    #pragma unroll
    for (int ks = 0; ks < 4; ++ks){
      int ko = ks*32 + kg*8;
      af[ks][0] = *(const bf16x8*)(descA + (size_t)(wr+r)*DD + ko);
      af[ks][1] = *(const bf16x8*)(descA + (size_t)(wr+16+r)*DD + ko);
    }
    float msx[2][4], msy[2][4], mx2[2][4], mxx[2][4];
    bool  mok[2][4];
    #pragma unroll
    for (int mi = 0; mi < 2; ++mi){
      #pragma unroll
      for (int j = 0; j < 4; ++j){
        int m = wr + mi*16 + 4*kg + j;
        mok[mi][j] = (mv[m] != 0);
        float px = pts[m*2+0], py = pts[m*2+1];
        float sx = ((px+1.f)*(float)(WW-1))*0.5f;
        float sy = ((py+1.f)*(float)(HH-1))*0.5f;
        msx[mi][j] = sx; msy[mi][j] = sy;
        mx2[mi][j] = sx*sx + sy*sy;
        mxx[mi][j] = xxa[m];
      }
    }
    for (int nt = mt; nt < 16; ++nt){
      int wc = nt*64 + wco;
      float nxxv[2], ndx[2], ndy[2], ny2[2];
      #pragma unroll
      for (int ni = 0; ni < 2; ++ni){
        int n = wc + ni*16 + r;
        nxxv[ni] = xxb[n];
        float qx = mp[n*2+0], qy = mp[n*2+1];
        float dx = ((qx+1.f)*(float)(WW-1))*0.5f;
        float dy = ((qy+1.f)*(float)(HH-1))*0.5f;
        ndx[ni] = dx; ndy[ni] = dy;
        ny2[ni] = dx*dx + dy*dy;
      }
      f32x4 c00 = {}, c01 = {}, c10 = {}, c11 = {};
      #pragma unroll
      for (int ks = 0; ks < 4; ++ks){
        int ko = ks*32 + kg*8;
        bf16x8 b0 = *(const bf16x8*)(descB + (size_t)(wc+r)*DD + ko);
        bf16x8 b1 = *(const bf16x8*)(descB + (size_t)(wc+16+r)*DD + ko);
        c00 = __builtin_amdgcn_mfma_f32_16x16x32_bf16(af[ks][0], b0, c00, 0, 0, 0);
        c01 = __builtin_amdgcn_mfma_f32_16x16x32_bf16(af[ks][0], b1, c01, 0, 0, 0);
        c10 = __builtin_amdgcn_mfma_f32_16x16x32_bf16(af[ks][1], b0, c10, 0, 0, 0);
        c11 = __builtin_amdgcn_mfma_f32_16x16x32_bf16(af[ks][1], b1, c11, 0, 0, 0);
      }
      #pragma unroll
      for (int mi = 0; mi < 2; ++mi){
        #pragma unroll
        for (int j = 0; j < 4; ++j){
          if (!mok[mi][j]) continue;
          int m = wr + mi*16 + 4*kg + j;
          float sx = msx[mi][j], sy = msy[mi][j];
          float x2 = mx2[mi][j], xm = mxx[mi][j];
          #pragma unroll
          for (int ni = 0; ni < 2; ++ni){
            int n = wc + ni*16 + r;
            if (m >= n) continue;
            float dv = (mi ? (ni ? c11[j] : c10[j]) : (ni ? c01[j] : c00[j]));
            float d2 = x2 + ny2[ni] - 2.f*(sx*ndx[ni] + sy*ndy[ni]);
            float den = sqrtf(fmaxf(xm * nxxv[ni], 1e-16f));
            float p = dv/den;
            if (d2 <= 1.0f){ pos += p; pcf += 1.f; }
            else           { neg += p; ncf += 1.f; }
          }
        }
      }
    }
  }
  pos = wave_sum(pos); neg = wave_sum(neg);
  pcf = wave_sum(pcf); ncf = wave_sum(ncf);
  if (lane == 0){ rb[wave][0] = pos; rb[wave][1] = neg; rb[wave][2] = pcf; rb[wave][3] = ncf; }
  __syncthreads();
  if (tid == 0){
    float sP  = rb[0][0]+rb[1][0]+rb[2][0]+rb[3][0];
    float sN  = rb[0][1]+rb[1][1]+rb[2][1]+rb[3][1];
    float sPC = rb[0][2]+rb[1][2]+rb[2][2]+rb[3][2];
    float sNC = rb[0][3]+rb[1][3]+rb[2][3]+rb[3][3];
    atomicAdd(&acc[3], (double)sP);
    atomicAdd(&acc[4], (double)sN);
    atomicAdd(&cnts[0], (unsigned long long)(sPC + 0.5f));
    atomicAdd(&cnts[1], (unsigned long long)(sNC + 0.5f));
  }
}

// ---------------- K12: finalize ----------------
__global__ void k_final(const double* __restrict__ acc, const unsigned long long* __restrict__ cnts,
                        float* __restrict__ out){
  double distinction = acc[0] / (double)((long long)BB*NPTS*NPTS);
  double bce = acc[1] / (double)((long long)BB*HWsz);
  double extra = acc[2] / (double)((long long)BB*HWsz);
  double cornerness = bce + 10.0*extra;
  unsigned long long pc = cnts[0], nc = cnts[1];
  double pos_mean = acc[3] / (double)(pc ? pc : 1ull);
  double neg_mean = acc[4] / (double)(nc ? nc : 1ull);
  double match = 1.0 - pos_mean + neg_mean;
  out[0] = (float)(distinction + 0.5*cornerness + match);
}

extern "C" void kernel_launch(void* const* d_in, const int* in_sizes, int n_in,
                              void* d_out, int out_size, void* d_ws, size_t ws_size,
                              hipStream_t stream) {
  (void)in_sizes; (void)n_in; (void)out_size; (void)ws_size;
  const float* desc   = (const float*)d_in[0];
  const float* points = (const float*)d_in[1];
  const float* scores = (const float*)d_in[2];
  const float* depths = (const float*)d_in[3];
  const float* poses  = (const float*)d_in[4];
  const float* Km     = (const float*)d_in[5];
  const float* imgs   = (const float*)d_in[6];
  float* out = (float*)d_out;

  const size_t S = (size_t)BB*HWsz;
  float* gray = (float*)d_ws;          // S  (later: resp)
  float* bx   = gray + S;              // S  gxx -> keep
  float* by   = bx + S;                // S  gyy -> target
  float* bxy  = by + S;                // S  gxy
  float* resp = gray;                  // reuse
  float* keep = bx;                    // reuse
  unsigned long long* ckeys = (unsigned long long*)(bxy + S);      // BB*CAP
  unsigned int* ccnt = (unsigned int*)(ckeys + (size_t)BB*CAP);    // 6
  double* acc = (double*)(ccnt + 6);                               // 5 doubles
  unsigned long long* cnts = (unsigned long long*)(acc + 5);       // 2
  float* cpts  = (float*)(cnts + 2);                               // BB*NC*2
  float* cvals = cpts + (size_t)BB*NC*2;                           // BB*NC
  float* xx    = cvals + (size_t)BB*NC;                            // BB*NPTS
  float* mproj = xx + (size_t)BB*NPTS;                             // BB*BB*NPTS*2
  unsigned char* mvis = (unsigned char*)(mproj + (size_t)BB*BB*NPTS*2); // BB*BB*NPTS
  unsigned short* dbf = (unsigned short*)(mvis + (size_t)BB*BB*NPTS);   // BB*NPTS*DD bf16

  const int npx = BB*HWsz;
  dim3 blk(256);
  dim3 gpx((npx + 255)/256);

  k_gray<<<gpx, blk, 0, stream>>>(imgs, gray);
  k_sobel<<<gpx, blk, 0, stream>>>(gray, bx, by, bxy);
  k_gauss_resp<<<gpx, blk, 0, stream>>>(bx, by, bxy, resp);

  // zero target (reuses gyy buffer: must be AFTER k_gauss_resp), counters, accumulators
  hipMemsetAsync(by, 0, S*sizeof(float), stream);
  hipMemsetAsync(ccnt, 0, 6*sizeof(unsigned int), stream);
  hipMemsetAsync(acc, 0, 5*sizeof(double) + 2*sizeof(unsigned long long), stream);

  k_nms5<<<gpx, blk, 0, stream>>>(resp, keep);
  {
    int n = BB*(HH/8)*(WW/8);
    k_blockmax_compact<<<dim3((n+255)/256), blk, 0, stream>>>(keep, ckeys, ccnt);
  }
  k_top500<<<dim3(BB), dim3(1024), 0, stream>>>(ckeys, ccnt, cpts, cvals);
  {
    int n = BB*BB*NC;
    k_corner_scatter<<<dim3((n+255)/256), blk, 0, stream>>>(cpts, cvals, depths, poses, Km,
                                                            (unsigned int*)by);
  }
  k_score_reduce<<<gpx, blk, 0, stream>>>(by, scores, acc);
  {
    int n = BB*NPTS;
    k_rownorm_bf16<<<dim3((n+255)/256), blk, 0, stream>>>(desc, xx, dbf);
  }
  {
    int n = BB*BB*NPTS;
    k_proj_points<<<dim3((n+255)/256), blk, 0, stream>>>(points, depths, poses, Km, mproj, mvis);
  }
  k_distinction_mfma<<<dim3(16, 2, BB), blk, 0, stream>>>(dbf, xx, acc);
  k_match_mfma<<<dim3(8, 1, BB*BB), blk, 0, stream>>>(dbf, xx, points, mproj, mvis, acc, cnts);
  k_final<<<dim3(1), dim3(1), 0, stream>>>(acc, cnts, out);
}

// Round 7
// 418.679 us; speedup vs baseline: 1.4876x; 1.0051x over previous
//
#include <hip/hip_runtime.h>
#include <stdint.h>

#define BB 6
#define NPTS 1024
#define DD 128
#define HH 320
#define WW 320
#define NC 500
#define HWsz (HH*WW)
#define CAP 2048

typedef __attribute__((ext_vector_type(8))) short bf16x8;
typedef __attribute__((ext_vector_type(4))) float f32x4;

__device__ __forceinline__ int clampi(int v, int lo, int hi){ return v<lo?lo:(v>hi?hi:v); }
__device__ __forceinline__ int refl(int p, int L){ if(p<0)p=-p; if(p>=L)p=2*L-2-p; return p; }

__device__ __forceinline__ float wave_sum(float v){
  #pragma unroll
  for (int o = 32; o > 0; o >>= 1) v += __shfl_xor(v, o, 64);
  return v;
}
__device__ __forceinline__ float wave_max(float v){
  #pragma unroll
  for (int o = 32; o > 0; o >>= 1) v = fmaxf(v, __shfl_xor(v, o, 64));
  return v;
}

// 7-tap gaussian weights (sigma=1), normalized; constants from double math.
__device__ __constant__ float GW[7] = {
  0.0044330481f, 0.0540055850f, 0.2420362300f, 0.3990502700f,
  0.2420362300f, 0.0540055850f, 0.0044330481f };

// ---------------- projection (matches pairwise_project) ----------------
struct Proj { float u, v; int vis; };

__device__ Proj project_point(float ptx, float pty, int jsrc, int itgt,
                              const float* __restrict__ depths,
                              const float* __restrict__ poses,
                              const float* __restrict__ Km)
{
  float pxx = ((ptx + 1.0f)*(float)(WW-1))*0.5f;
  float pxy = ((pty + 1.0f)*(float)(HH-1))*0.5f;
  float rx = rintf(pxx), ry = rintf(pxy);
  rx = fminf(fmaxf(rx, 0.f), (float)(WW-1));
  ry = fminf(fmaxf(ry, 0.f), (float)(HH-1));
  int xi = (int)rx, yi = (int)ry;
  float d = depths[(size_t)jsrc*HWsz + yi*WW + xi];
  float a00=Km[0],a01=Km[1],a02=Km[2],a10=Km[3],a11=Km[4],a12=Km[5],a20=Km[6],a21=Km[7],a22=Km[8];
  float det = a00*(a11*a22 - a12*a21) - a01*(a10*a22 - a12*a20) + a02*(a10*a21 - a11*a20);
  float id_ = 1.0f/det;
  float i00 = (a11*a22 - a12*a21)*id_;
  float i01 = (a02*a21 - a01*a22)*id_;
  float i02 = (a01*a12 - a02*a11)*id_;
  float i10 = (a12*a20 - a10*a22)*id_;
  float i11 = (a00*a22 - a02*a20)*id_;
  float i12 = (a02*a10 - a00*a12)*id_;
  float i20 = (a10*a21 - a11*a20)*id_;
  float i21 = (a01*a20 - a00*a21)*id_;
  float i22 = (a00*a11 - a01*a10)*id_;
  float c0 = (i00*pxx + i01*pxy + i02)*d;
  float c1 = (i10*pxx + i11*pxy + i12)*d;
  float c2 = (i20*pxx + i21*pxy + i22)*d;
  const float* Pj = poses + (size_t)jsrc*16;
  float w0 = Pj[0]*c0 + Pj[1]*c1 + Pj[2]*c2  + Pj[3];
  float w1 = Pj[4]*c0 + Pj[5]*c1 + Pj[6]*c2  + Pj[7];
  float w2 = Pj[8]*c0 + Pj[9]*c1 + Pj[10]*c2 + Pj[11];
  const float* Pi = poses + (size_t)itgt*16;
  float dx = w0 - Pi[3], dy = w1 - Pi[7], dz = w2 - Pi[11];
  float e0 = Pi[0]*dx + Pi[4]*dy + Pi[8]*dz;
  float e1 = Pi[1]*dx + Pi[5]*dy + Pi[9]*dz;
  float e2 = Pi[2]*dx + Pi[6]*dy + Pi[10]*dz;
  float uu = a00*e0 + a01*e1 + a02*e2;
  float vv = a10*e0 + a11*e1 + a12*e2;
  float zz = a20*e0 + a21*e1 + a22*e2;
  float zs = (fabsf(zz) > 1e-6f) ? zz : 1e-6f;
  Proj r;
  r.u = uu/zs; r.v = vv/zs;
  r.vis = (zz > 0.1f) && (r.u >= 0.f) && (r.u <= (float)(WW-1)) && (r.v >= 0.f) && (r.v <= (float)(HH-1));
  return r;
}

// ---------------- K1: gray ----------------
__global__ void k_gray(const float* __restrict__ imgs, float* __restrict__ gray){
  int t = blockIdx.x*blockDim.x + threadIdx.x;
  if (t >= BB*HWsz) return;
  int b = t / HWsz, p = t - b*HWsz;
  const float* base = imgs + (size_t)b*3*HWsz;
  gray[t] = 0.299f*base[p] + 0.587f*base[HWsz+p] + 0.114f*base[2*HWsz+p];
}

// ---------------- K2: sobel (edge pad) + products ----------------
__global__ void k_sobel(const float* __restrict__ gray, float* __restrict__ gxx,
                        float* __restrict__ gyy, float* __restrict__ gxy){
  int t = blockIdx.x*blockDim.x + threadIdx.x;
  if (t >= BB*HWsz) return;
  int b = t / HWsz, p = t - b*HWsz;
  int y = p / WW, x = p - y*WW;
  const float* g = gray + (size_t)b*HWsz;
  int ym = clampi(y-1,0,HH-1), yp = clampi(y+1,0,HH-1);
  int xm = clampi(x-1,0,WW-1), xp = clampi(x+1,0,WW-1);
  float g00 = g[ym*WW+xm], g01 = g[ym*WW+x], g02 = g[ym*WW+xp];
  float g10 = g[y*WW+xm],                    g12 = g[y*WW+xp];
  float g20 = g[yp*WW+xm], g21 = g[yp*WW+x], g22 = g[yp*WW+xp];
  float gx = 0.125f*(g02-g00) + 0.25f*(g12-g10) + 0.125f*(g22-g20);
  float gy = 0.125f*(g20-g00) + 0.25f*(g21-g01) + 0.125f*(g22-g02);
  gxx[t] = gx*gx; gyy[t] = gy*gy; gxy[t] = gx*gy;
}

// ---------------- K3: gaussian 7x7 (reflect) + GFTT response ----------------
__global__ void k_gauss_resp(const float* __restrict__ gxx, const float* __restrict__ gyy,
                             const float* __restrict__ gxy, float* __restrict__ resp){
  int t = blockIdx.x*blockDim.x + threadIdx.x;
  if (t >= BB*HWsz) return;
  int b = t / HWsz, p = t - b*HWsz;
  int y = p / WW, x = p - y*WW;
  const float* axx = gxx + (size_t)b*HWsz;
  const float* ayy = gyy + (size_t)b*HWsz;
  const float* axy = gxy + (size_t)b*HWsz;
  float sxx=0.f, syy=0.f, sxy=0.f;
  if (y >= 3 && y < HH-3 && x >= 3 && x < WW-3){
    int base = (y-3)*WW + (x-3);
    #pragma unroll
    for (int i=0;i<7;++i){
      const float* rxx = axx + base + i*WW;
      const float* ryy = ayy + base + i*WW;
      const float* rxy = axy + base + i*WW;
      float wr = GW[i];
      #pragma unroll
      for (int j=0;j<7;++j){
        float wc = wr*GW[j];
        sxx += wc*rxx[j]; syy += wc*ryy[j]; sxy += wc*rxy[j];
      }
    }
  } else {
    #pragma unroll
    for (int i=0;i<7;++i){
      int ry = refl(y+i-3, HH);
      const float* rxx = axx + (size_t)ry*WW;
      const float* ryy = ayy + (size_t)ry*WW;
      const float* rxy = axy + (size_t)ry*WW;
      float wr = GW[i];
      #pragma unroll
      for (int j=0;j<7;++j){
        int rx = refl(x+j-3, WW);
        float wc = wr*GW[j];
        sxx += wc*rxx[rx]; syy += wc*ryy[rx]; sxy += wc*rxy[rx];
      }
    }
  }
  float tr = sxx+syy, df = sxx-syy;
  float disc = sqrtf(fmaxf(df*df + 4.f*sxy*sxy, 0.f));
  resp[t] = 0.5f*(tr - disc);
}

// ---------------- K4: 5x5 NMS (pad -inf) ----------------
__global__ void k_nms5(const float* __restrict__ resp, float* __restrict__ keep){
  int t = blockIdx.x*blockDim.x + threadIdx.x;
  if (t >= BB*HWsz) return;
  int b = t / HWsz, p = t - b*HWsz;
  int y = p / WW, x = p - y*WW;
  const float* rb = resp + (size_t)b*HWsz;
  float m = -1e30f;
  if (y >= 2 && y < HH-2 && x >= 2 && x < WW-2){
    int base = (y-2)*WW + (x-2);
    #pragma unroll
    for (int dy=0; dy<5; ++dy){
      const float* rr = rb + base + dy*WW;
      #pragma unroll
      for (int dx=0; dx<5; ++dx) m = fmaxf(m, rr[dx]);
    }
  } else {
    for (int dy=-2; dy<=2; ++dy){
      int yy = y+dy; if (yy<0||yy>=HH) continue;
      for (int dx=-2; dx<=2; ++dx){
        int xx2 = x+dx; if (xx2<0||xx2>=WW) continue;
        m = fmaxf(m, rb[yy*WW+xx2]);
      }
    }
  }
  float r = rb[p];
  keep[t] = (r == m) ? r : 0.f;
}

// ---------------- K5: 8x8 block max + compact (one WAVE per 8x8 block) ----------------
__global__ void k_blockmax_compact(const float* __restrict__ keep,
        unsigned long long* __restrict__ ckeys, unsigned int* __restrict__ ccnt){
  const int BLKS = (HH/8)*(WW/8);
  int gw = (blockIdx.x*(int)blockDim.x + (int)threadIdx.x) >> 6;   // global wave id
  int lane = threadIdx.x & 63;
  if (gw >= BB*BLKS) return;
  int b = gw / BLKS; int r = gw - b*BLKS;
  int by = r / (WW/8), bx = r - by*(WW/8);
  int yy = by*8 + (lane >> 3), xx2 = bx*8 + (lane & 7);
  float v = keep[(size_t)b*HWsz + (size_t)yy*WW + xx2];
  float bm = wave_max(v);
  if (bm > 0.f && v == bm){
    unsigned int slot = atomicAdd(&ccnt[b], 1u);
    if (slot < CAP){
      unsigned int idx = (unsigned int)(yy*WW + xx2);
      ckeys[(size_t)b*CAP + slot] =
        ((unsigned long long)__float_as_uint(bm) << 32) |
        (unsigned long long)(0xFFFFFFFFu - idx);
    }
  }
}

// ---------------- K6: bitonic top-500 per batch (CAP=2048) ----------------
__global__ __launch_bounds__(1024) void k_top500(const unsigned long long* __restrict__ ckeys,
        const unsigned int* __restrict__ ccnt, float* __restrict__ cpts, float* __restrict__ cvals){
  __shared__ unsigned long long sk[CAP];
  int b = blockIdx.x;
  int tid = threadIdx.x;
  unsigned int cnt = ccnt[b]; if (cnt > CAP) cnt = CAP;
  for (int i = tid; i < CAP; i += 1024)
    sk[i] = (i < (int)cnt) ? ckeys[(size_t)b*CAP + i] : 0ull;
  __syncthreads();
  for (int k = 2; k <= CAP; k <<= 1){
    for (int j = k >> 1; j > 0; j >>= 1){
      for (int i = tid; i < CAP; i += 1024){
        int l = i ^ j;
        if (l > i){
          unsigned long long A = sk[i], Bv = sk[l];
          bool up = ((i & k) == 0);
          if ((A > Bv) == up){ sk[i] = Bv; sk[l] = A; }
        }
      }
      __syncthreads();
    }
  }
  if (tid < NC){
    unsigned long long key = sk[CAP-1-tid];   // descending order
    float val = __uint_as_float((unsigned int)(key >> 32));
    size_t o = (size_t)b*NC + tid;
    if (val > 0.f){
      unsigned int idx = 0xFFFFFFFFu - (unsigned int)(key & 0xFFFFFFFFull);
      float fx = (float)(idx % WW), fy = (float)(idx / WW);
      cpts[o*2+0] = (fx*2.0f)/(float)(WW-1) - 1.0f;
      cpts[o*2+1] = (fy*2.0f)/(float)(HH-1) - 1.0f;
      cvals[o] = val;
    } else {
      cpts[o*2+0] = __int_as_float(0x7fc00000);
      cpts[o*2+1] = __int_as_float(0x7fc00000);
      cvals[o] = 0.f;
    }
  }
}

// ---------------- K7: corner projection + scatter-max ----------------
__global__ void k_corner_scatter(const float* __restrict__ cpts, const float* __restrict__ cvals,
        const float* __restrict__ depths, const float* __restrict__ poses,
        const float* __restrict__ Km, unsigned int* __restrict__ target){
  int t = blockIdx.x*blockDim.x + threadIdx.x;
  if (t >= BB*BB*NC) return;
  int i = t / (BB*NC); int r = t - i*(BB*NC); int j = r / NC; int n = r - j*NC;
  float val = cvals[(size_t)i*NC + n];
  float ptx = cpts[((size_t)j*NC+n)*2+0];
  float pty = cpts[((size_t)j*NC+n)*2+1];
  if (!(val > 0.f) || ptx != ptx) return;
  Proj pr = project_point(ptx, pty, j, i, depths, poses, Km);
  if (!pr.vis) return;
  float nu = (pr.u*2.0f)/(float)(WW-1) - 1.0f;
  float nv = (pr.v*2.0f)/(float)(HH-1) - 1.0f;
  float px2 = ((nu+1.0f)*(float)(WW-1))*0.5f;
  float py2 = ((nv+1.0f)*(float)(HH-1))*0.5f;
  float rx = rintf(px2), ry = rintf(py2);
  if (!(rx >= 0.f && ry >= 0.f && rx <= (float)(WW-1) && ry <= (float)(HH-1))) return;
  int wf = (int)rx, hf = (int)ry;
  atomicMax(&target[(size_t)j*HWsz + hf*WW + wf], __float_as_uint(val));
}

// ---------------- K8: target NMS + BCE + laplacian reduce ----------------
__global__ void k_score_reduce(const float* __restrict__ target, const float* __restrict__ scores,
        double* __restrict__ acc){
  __shared__ float rb[4][2];
  int t = blockIdx.x*blockDim.x + threadIdx.x;
  float bce = 0.f, extra = 0.f;
  if (t < BB*HWsz){
    int b = t / HWsz, p = t - b*HWsz;
    int y = p / WW, x = p - y*WW;
    const float* tg = target + (size_t)b*HWsz;
    const float* sb = scores + (size_t)b*HWsz;
    float tv = tg[p];
    float m = -1e30f;
    float S5 = 0.f;
    if (y >= 2 && y < HH-2 && x >= 2 && x < WW-2){
      int base = (y-2)*WW + (x-2);
      #pragma unroll
      for (int dy=0; dy<5; ++dy){
        const float* tr = tg + base + dy*WW;
        const float* sr = sb + base + dy*WW;
        #pragma unroll
        for (int dx=0; dx<5; ++dx){ m = fmaxf(m, tr[dx]); S5 += sr[dx]; }
      }
    } else {
      for (int dy=-2; dy<=2; ++dy){
        int yy = y+dy; if (yy<0||yy>=HH) continue;
        for (int dx=-2; dx<=2; ++dx){
          int xx2 = x+dx; if (xx2<0||xx2>=WW) continue;
          m = fmaxf(m, tg[yy*WW+xx2]);
        }
      }
      for (int dy=-2; dy<=2; ++dy){
        int yy = refl(y+dy, HH);
        for (int dx=-2; dx<=2; ++dx){
          int xx2 = refl(x+dx, WW);
          S5 += sb[yy*WW+xx2];
        }
      }
    }
    float tb = (tv > 0.f && tv == m) ? 1.f : 0.f;
    float sc = sb[p];
    float pc = fminf(fmaxf(sc, 1e-12f), 1.0f - 1e-12f);
    bce = -(tb*logf(pc) + (1.f-tb)*logf(1.f-pc));
    float lap = (S5 - sc)*(1.0f/48.0f) - 0.5f*sc;
    extra = sc*expf(-lap);
  }
  bce = wave_sum(bce); extra = wave_sum(extra);
  int wave = threadIdx.x >> 6, lane = threadIdx.x & 63;
  if (lane == 0){ rb[wave][0] = bce; rb[wave][1] = extra; }
  __syncthreads();
  if (threadIdx.x == 0){
    float B0 = rb[0][0]+rb[1][0]+rb[2][0]+rb[3][0];
    float E0 = rb[0][1]+rb[1][1]+rb[2][1]+rb[3][1];
    atomicAdd(&acc[1], (double)B0);
    atomicAdd(&acc[2], (double)E0);
  }
}

// ---------------- K9a: row sum-of-squares + bf16 convert ----------------
__global__ void k_rownorm_bf16(const float* __restrict__ desc, float* __restrict__ xx,
                               unsigned short* __restrict__ dbf){
  int t = blockIdx.x*blockDim.x + threadIdx.x;
  if (t >= BB*NPTS) return;
  const float* dptr = desc + (size_t)t*DD;
  unsigned short* optr = dbf + (size_t)t*DD;
  float s = 0.f;
  for (int d = 0; d < DD; d += 4){
    float4 v = *(const float4*)(dptr + d);
    s += v.x*v.x + v.y*v.y + v.z*v.z + v.w*v.w;
    unsigned int u0 = __float_as_uint(v.x); optr[d+0] = (unsigned short)((u0 + 0x7fffu + ((u0>>16)&1u)) >> 16);
    unsigned int u1 = __float_as_uint(v.y); optr[d+1] = (unsigned short)((u1 + 0x7fffu + ((u1>>16)&1u)) >> 16);
    unsigned int u2 = __float_as_uint(v.z); optr[d+2] = (unsigned short)((u2 + 0x7fffu + ((u2>>16)&1u)) >> 16);
    unsigned int u3 = __float_as_uint(v.w); optr[d+3] = (unsigned short)((u3 + 0x7fffu + ((u3>>16)&1u)) >> 16);
  }
  xx[t] = s;
}

// ---------------- K9b: project input points (raw proj + vis) ----------------
__global__ void k_proj_points(const float* __restrict__ points, const float* __restrict__ depths,
        const float* __restrict__ poses, const float* __restrict__ Km,
        float* __restrict__ mproj, unsigned char* __restrict__ mvis){
  int t = blockIdx.x*blockDim.x + threadIdx.x;
  if (t >= BB*BB*NPTS) return;
  int i = t / (BB*NPTS); int r = t - i*(BB*NPTS); int j = r / NPTS; int n = r - j*NPTS;
  float ptx = points[((size_t)j*NPTS+n)*2+0];
  float pty = points[((size_t)j*NPTS+n)*2+1];
  Proj pr = project_point(ptx, pty, j, i, depths, poses, Km);
  mproj[(size_t)t*2+0] = (pr.u*2.0f)/(float)(WW-1) - 1.0f;
  mproj[(size_t)t*2+1] = (pr.v*2.0f)/(float)(HH-1) - 1.0f;
  mvis[t] = pr.vis ? 1 : 0;
}

// ---------------- K10: distinction via MFMA (multi-tile blocks) ----------------
// grid (16 mt, 2 nh, BB); block = 4 waves; each block: 8 column tiles
__global__ __launch_bounds__(256) void k_distinction_mfma(const unsigned short* __restrict__ dbf,
        const float* __restrict__ xx, double* __restrict__ acc){
  __shared__ float rb[4];
  int b = blockIdx.z;
  int mt = blockIdx.x, nh = blockIdx.y;
  int tid = threadIdx.x;
  int wave = tid >> 6, lane = tid & 63;
  int wr = mt*64 + (wave&1)*32;
  int wco = (wave>>1)*32;
  int r = lane & 15, kg = lane >> 4;
  const unsigned short* descb = dbf + (size_t)b*NPTS*DD;
  const float* xb = xx + (size_t)b*NPTS;
  // A frags + m-side norms (loaded once)
  bf16x8 af[4][2];
  #pragma unroll
  for (int ks = 0; ks < 4; ++ks){
    int ko = ks*32 + kg*8;
    af[ks][0] = *(const bf16x8*)(descb + (size_t)(wr+r)*DD + ko);
    af[ks][1] = *(const bf16x8*)(descb + (size_t)(wr+16+r)*DD + ko);
  }
  float mxx[2][4];
  #pragma unroll
  for (int mi = 0; mi < 2; ++mi)
    #pragma unroll
    for (int j = 0; j < 4; ++j)
      mxx[mi][j] = xb[wr + mi*16 + 4*kg + j];
  float local = 0.f;
  for (int nt = nh*8; nt < nh*8+8; ++nt){
    int wc = nt*64 + wco;
    float xn0 = xb[wc + r], xn1 = xb[wc + 16 + r];
    f32x4 c00 = {}, c01 = {}, c10 = {}, c11 = {};
    #pragma unroll
    for (int ks = 0; ks < 4; ++ks){
      int ko = ks*32 + kg*8;
      bf16x8 b0 = *(const bf16x8*)(descb + (size_t)(wc+r)*DD + ko);
      bf16x8 b1 = *(const bf16x8*)(descb + (size_t)(wc+16+r)*DD + ko);
      c00 = __builtin_amdgcn_mfma_f32_16x16x32_bf16(af[ks][0], b0, c00, 0, 0, 0);
      c01 = __builtin_amdgcn_mfma_f32_16x16x32_bf16(af[ks][0], b1, c01, 0, 0, 0);
      c10 = __builtin_amdgcn_mfma_f32_16x16x32_bf16(af[ks][1], b0, c10, 0, 0, 0);
      c11 = __builtin_amdgcn_mfma_f32_16x16x32_bf16(af[ks][1], b1, c11, 0, 0, 0);
    }
    #pragma unroll
    for (int mi = 0; mi < 2; ++mi){
      #pragma unroll
      for (int j = 0; j < 4; ++j){
        float xm = mxx[mi][j];
        float v0 = (mi ? c10[j] : c00[j]);
        float v1 = (mi ? c11[j] : c01[j]);
        local += fmaxf(v0 / sqrtf(fmaxf(xm*xn0, 1e-16f)), 0.f);
        local += fmaxf(v1 / sqrtf(fmaxf(xm*xn1, 1e-16f)), 0.f);
      }
    }
  }
  local = wave_sum(local);
  if (lane == 0) rb[wave] = local;
  __syncthreads();
  if (tid == 0) atomicAdd(&acc[0], (double)(rb[0]+rb[1]+rb[2]+rb[3]));
}

// ---------------- K11: match via MFMA (balanced multi-tile blocks) ----------------
// grid (8 pair, 1, 36); block p owns row-tiles {p, 15-p} -> 17 tiles total
__global__ __launch_bounds__(256) void k_match_mfma(const unsigned short* __restrict__ dbf,
        const float* __restrict__ xx, const float* __restrict__ points,
        const float* __restrict__ mproj, const unsigned char* __restrict__ mvis,
        double* __restrict__ acc, unsigned long long* __restrict__ cnts){
  __shared__ float rb[4][4];
  int ab = blockIdx.z; int a = ab / BB, b = ab - a*BB;
  int pairIdx = blockIdx.x;
  int tid = threadIdx.x;
  int wave = tid >> 6, lane = tid & 63;
  int wro = (wave&1)*32, wco = (wave>>1)*32;
  int r = lane & 15, kg = lane >> 4;
  const unsigned short* descA = dbf + (size_t)a*NPTS*DD;
  const unsigned short* descB = dbf + (size_t)b*NPTS*DD;
  const float* xxa = xx + (size_t)a*NPTS;
  const float* xxb = xx + (size_t)b*NPTS;
  const float* pts = points + (size_t)b*NPTS*2;
  const float* mp  = mproj + (((size_t)a*BB+b)*NPTS)*2;
  const unsigned char* mv = mvis + ((size_t)a*BB+b)*NPTS;
  float pos = 0.f, neg = 0.f, pcf = 0.f, ncf = 0.f;
  #pragma unroll
  for (int seg = 0; seg < 2; ++seg){
    int mt = seg ? (15 - pairIdx) : pairIdx;
    int wr = mt*64 + wro;
    bf16x8 af[4][2];
    #pragma unroll
    for (int ks = 0; ks < 4; ++ks){
      int ko = ks*32 + kg*8;
      af[ks][0] = *(const bf16x8*)(descA + (size_t)(wr+r)*DD + ko);
      af[ks][1] = *(const bf16x8*)(descA + (size_t)(wr+16+r)*DD + ko);
    }
    float msx[2][4], msy[2][4], mx2[2][4], mxx[2][4];
    bool  mok[2][4];
    #pragma unroll
    for (int mi = 0; mi < 2; ++mi){
      #pragma unroll
      for (int j = 0; j < 4; ++j){
        int m = wr + mi*16 + 4*kg + j;
        mok[mi][j] = (mv[m] != 0);
        float px = pts[m*2+0], py = pts[m*2+1];
        float sx = ((px+1.f)*(float)(WW-1))*0.5f;
        float sy = ((py+1.f)*(float)(HH-1))*0.5f;
        msx[mi][j] = sx; msy[mi][j] = sy;
        mx2[mi][j] = sx*sx + sy*sy;
        mxx[mi][j] = xxa[m];
      }
    }
    for (int nt = mt; nt < 16; ++nt){
      int wc = nt*64 + wco;
      float nxxv[2], ndx[2], ndy[2], ny2[2];
      #pragma unroll
      for (int ni = 0; ni < 2; ++ni){
        int n = wc + ni*16 + r;
        nxxv[ni] = xxb[n];
        float qx = mp[n*2+0], qy = mp[n*2+1];
        float dx = ((qx+1.f)*(float)(WW-1))*0.5f;
        float dy = ((qy+1.f)*(float)(HH-1))*0.5f;
        ndx[ni] = dx; ndy[ni] = dy;
        ny2[ni] = dx*dx + dy*dy;
      }
      f32x4 c00 = {}, c01 = {}, c10 = {}, c11 = {};
      #pragma unroll
      for (int ks = 0; ks < 4; ++ks){
        int ko = ks*32 + kg*8;
        bf16x8 b0 = *(const bf16x8*)(descB + (size_t)(wc+r)*DD + ko);
        bf16x8 b1 = *(const bf16x8*)(descB + (size_t)(wc+16+r)*DD + ko);
        c00 = __builtin_amdgcn_mfma_f32_16x16x32_bf16(af[ks][0], b0, c00, 0, 0, 0);
        c01 = __builtin_amdgcn_mfma_f32_16x16x32_bf16(af[ks][0], b1, c01, 0, 0, 0);
        c10 = __builtin_amdgcn_mfma_f32_16x16x32_bf16(af[ks][1], b0, c10, 0, 0, 0);
        c11 = __builtin_amdgcn_mfma_f32_16x16x32_bf16(af[ks][1], b1, c11, 0, 0, 0);
      }
      #pragma unroll
      for (int mi = 0; mi < 2; ++mi){
        #pragma unroll
        for (int j = 0; j < 4; ++j){
          if (!mok[mi][j]) continue;
          int m = wr + mi*16 + 4*kg + j;
          float sx = msx[mi][j], sy = msy[mi][j];
          float x2 = mx2[mi][j], xm = mxx[mi][j];
          #pragma unroll
          for (int ni = 0; ni < 2; ++ni){
            int n = wc + ni*16 + r;
            if (m >= n) continue;
            float dv = (mi ? (ni ? c11[j] : c10[j]) : (ni ? c01[j] : c00[j]));
            float d2 = x2 + ny2[ni] - 2.f*(sx*ndx[ni] + sy*ndy[ni]);
            float den = sqrtf(fmaxf(xm * nxxv[ni], 1e-16f));
            float p = dv/den;
            if (d2 <= 1.0f){ pos += p; pcf += 1.f; }
            else           { neg += p; ncf += 1.f; }
          }
        }
      }
    }
  }
  pos = wave_sum(pos); neg = wave_sum(neg);
  pcf = wave_sum(pcf); ncf = wave_sum(ncf);
  if (lane == 0){ rb[wave][0] = pos; rb[wave][1] = neg; rb[wave][2] = pcf; rb[wave][3] = ncf; }
  __syncthreads();
  if (tid == 0){
    float sP  = rb[0][0]+rb[1][0]+rb[2][0]+rb[3][0];
    float sN  = rb[0][1]+rb[1][1]+rb[2][1]+rb[3][1];
    float sPC = rb[0][2]+rb[1][2]+rb[2][2]+rb[3][2];
    float sNC = rb[0][3]+rb[1][3]+rb[2][3]+rb[3][3];
    atomicAdd(&acc[3], (double)sP);
    atomicAdd(&acc[4], (double)sN);
    atomicAdd(&cnts[0], (unsigned long long)(sPC + 0.5f));
    atomicAdd(&cnts[1], (unsigned long long)(sNC + 0.5f));
  }
}

// ---------------- K12: finalize ----------------
__global__ void k_final(const double* __restrict__ acc, const unsigned long long* __restrict__ cnts,
                        float* __restrict__ out){
  double distinction = acc[0] / (double)((long long)BB*NPTS*NPTS);
  double bce = acc[1] / (double)((long long)BB*HWsz);
  double extra = acc[2] / (double)((long long)BB*HWsz);
  double cornerness = bce + 10.0*extra;
  unsigned long long pc = cnts[0], nc = cnts[1];
  double pos_mean = acc[3] / (double)(pc ? pc : 1ull);
  double neg_mean = acc[4] / (double)(nc ? nc : 1ull);
  double match = 1.0 - pos_mean + neg_mean;
  out[0] = (float)(distinction + 0.5*cornerness + match);
}

extern "C" void kernel_launch(void* const* d_in, const int* in_sizes, int n_in,
                              void* d_out, int out_size, void* d_ws, size_t ws_size,
                              hipStream_t stream) {
  (void)in_sizes; (void)n_in; (void)out_size; (void)ws_size;
  const float* desc   = (const float*)d_in[0];
  const float* points = (const float*)d_in[1];
  const float* scores = (const float*)d_in[2];
  const float* depths = (const float*)d_in[3];
  const float* poses  = (const float*)d_in[4];
  const float* Km     = (const float*)d_in[5];
  const float* imgs   = (const float*)d_in[6];
  float* out = (float*)d_out;

  const size_t S = (size_t)BB*HWsz;
  float* gray = (float*)d_ws;          // S  (later: resp)
  float* bx   = gray + S;              // S  gxx -> keep
  float* by   = bx + S;                // S  gyy -> target
  float* bxy  = by + S;                // S  gxy
  float* resp = gray;                  // reuse
  float* keep = bx;                    // reuse
  unsigned long long* ckeys = (unsigned long long*)(bxy + S);      // BB*CAP
  unsigned int* ccnt = (unsigned int*)(ckeys + (size_t)BB*CAP);    // 6
  double* acc = (double*)(ccnt + 6);                               // 5 doubles
  unsigned long long* cnts = (unsigned long long*)(acc + 5);       // 2
  float* cpts  = (float*)(cnts + 2);                               // BB*NC*2
  float* cvals = cpts + (size_t)BB*NC*2;                           // BB*NC
  float* xx    = cvals + (size_t)BB*NC;                            // BB*NPTS
  float* mproj = xx + (size_t)BB*NPTS;                             // BB*BB*NPTS*2
  unsigned char* mvis = (unsigned char*)(mproj + (size_t)BB*BB*NPTS*2); // BB*BB*NPTS
  unsigned short* dbf = (unsigned short*)(mvis + (size_t)BB*BB*NPTS);   // BB*NPTS*DD bf16

  const int npx = BB*HWsz;
  dim3 blk(256);
  dim3 gpx((npx + 255)/256);

  k_gray<<<gpx, blk, 0, stream>>>(imgs, gray);
  k_sobel<<<gpx, blk, 0, stream>>>(gray, bx, by, bxy);
  k_gauss_resp<<<gpx, blk, 0, stream>>>(bx, by, bxy, resp);

  // zero target (reuses gyy buffer: must be AFTER k_gauss_resp), counters, accumulators
  hipMemsetAsync(by, 0, S*sizeof(float), stream);
  hipMemsetAsync(ccnt, 0, 6*sizeof(unsigned int), stream);
  hipMemsetAsync(acc, 0, 5*sizeof(double) + 2*sizeof(unsigned long long), stream);

  k_nms5<<<gpx, blk, 0, stream>>>(resp, keep);
  {
    int n = BB*(HH/8)*(WW/8)*64;   // one wave per 8x8 block
    k_blockmax_compact<<<dim3((n+255)/256), blk, 0, stream>>>(keep, ckeys, ccnt);
  }
  k_top500<<<dim3(BB), dim3(1024), 0, stream>>>(ckeys, ccnt, cpts, cvals);
  {
    int n = BB*BB*NC;
    k_corner_scatter<<<dim3((n+255)/256), blk, 0, stream>>>(cpts, cvals, depths, poses, Km,
                                                            (unsigned int*)by);
  }
  k_score_reduce<<<gpx, blk, 0, stream>>>(by, scores, acc);
  {
    int n = BB*NPTS;
    k_rownorm_bf16<<<dim3((n+255)/256), blk, 0, stream>>>(desc, xx, dbf);
  }
  {
    int n = BB*BB*NPTS;
    k_proj_points<<<dim3((n+255)/256), blk, 0, stream>>>(points, depths, poses, Km, mproj, mvis);
  }
  k_distinction_mfma<<<dim3(16, 2, BB), blk, 0, stream>>>(dbf, xx, acc);
  k_match_mfma<<<dim3(8, 1, BB*BB), blk, 0, stream>>>(dbf, xx, points, mproj, mvis, acc, cnts);
  k_final<<<dim3(1), dim3(1), 0, stream>>>(acc, cnts, out);
}

// Round 8
// 314.721 us; speedup vs baseline: 1.9789x; 1.3303x over previous
//
#include <hip/hip_runtime.h>
#include <stdint.h>

#define BB 6
#define NPTS 1024
#define DD 128
#define HH 320
#define WW 320
#define NC 500
#define HWsz (HH*WW)
#define CAP 2048
#define NBLK ((HH/8)*(WW/8))   // 1600 8x8 blocks per batch

typedef __attribute__((ext_vector_type(8))) short bf16x8;
typedef __attribute__((ext_vector_type(4))) float f32x4;

__device__ __forceinline__ int clampi(int v, int lo, int hi){ return v<lo?lo:(v>hi?hi:v); }
__device__ __forceinline__ int refl(int p, int L){ if(p<0)p=-p; if(p>=L)p=2*L-2-p; return p; }

__device__ __forceinline__ float wave_sum(float v){
  #pragma unroll
  for (int o = 32; o > 0; o >>= 1) v += __shfl_xor(v, o, 64);
  return v;
}
__device__ __forceinline__ float wave_max(float v){
  #pragma unroll
  for (int o = 32; o > 0; o >>= 1) v = fmaxf(v, __shfl_xor(v, o, 64));
  return v;
}

// 7-tap gaussian weights (sigma=1), normalized; constants from double math.
__device__ __constant__ float GW[7] = {
  0.0044330481f, 0.0540055850f, 0.2420362300f, 0.3990502700f,
  0.2420362300f, 0.0540055850f, 0.0044330481f };

// ---------------- projection (matches pairwise_project) ----------------
struct Proj { float u, v; int vis; };

__device__ Proj project_point(float ptx, float pty, int jsrc, int itgt,
                              const float* __restrict__ depths,
                              const float* __restrict__ poses,
                              const float* __restrict__ Km)
{
  float pxx = ((ptx + 1.0f)*(float)(WW-1))*0.5f;
  float pxy = ((pty + 1.0f)*(float)(HH-1))*0.5f;
  float rx = rintf(pxx), ry = rintf(pxy);
  rx = fminf(fmaxf(rx, 0.f), (float)(WW-1));
  ry = fminf(fmaxf(ry, 0.f), (float)(HH-1));
  int xi = (int)rx, yi = (int)ry;
  float d = depths[(size_t)jsrc*HWsz + yi*WW + xi];
  float a00=Km[0],a01=Km[1],a02=Km[2],a10=Km[3],a11=Km[4],a12=Km[5],a20=Km[6],a21=Km[7],a22=Km[8];
  float det = a00*(a11*a22 - a12*a21) - a01*(a10*a22 - a12*a20) + a02*(a10*a21 - a11*a20);
  float id_ = 1.0f/det;
  float i00 = (a11*a22 - a12*a21)*id_;
  float i01 = (a02*a21 - a01*a22)*id_;
  float i02 = (a01*a12 - a02*a11)*id_;
  float i10 = (a12*a20 - a10*a22)*id_;
  float i11 = (a00*a22 - a02*a20)*id_;
  float i12 = (a02*a10 - a00*a12)*id_;
  float i20 = (a10*a21 - a11*a20)*id_;
  float i21 = (a01*a20 - a00*a21)*id_;
  float i22 = (a00*a11 - a01*a10)*id_;
  float c0 = (i00*pxx + i01*pxy + i02)*d;
  float c1 = (i10*pxx + i11*pxy + i12)*d;
  float c2 = (i20*pxx + i21*pxy + i22)*d;
  const float* Pj = poses + (size_t)jsrc*16;
  float w0 = Pj[0]*c0 + Pj[1]*c1 + Pj[2]*c2  + Pj[3];
  float w1 = Pj[4]*c0 + Pj[5]*c1 + Pj[6]*c2  + Pj[7];
  float w2 = Pj[8]*c0 + Pj[9]*c1 + Pj[10]*c2 + Pj[11];
  const float* Pi = poses + (size_t)itgt*16;
  float dx = w0 - Pi[3], dy = w1 - Pi[7], dz = w2 - Pi[11];
  float e0 = Pi[0]*dx + Pi[4]*dy + Pi[8]*dz;
  float e1 = Pi[1]*dx + Pi[5]*dy + Pi[9]*dz;
  float e2 = Pi[2]*dx + Pi[6]*dy + Pi[10]*dz;
  float uu = a00*e0 + a01*e1 + a02*e2;
  float vv = a10*e0 + a11*e1 + a12*e2;
  float zz = a20*e0 + a21*e1 + a22*e2;
  float zs = (fabsf(zz) > 1e-6f) ? zz : 1e-6f;
  Proj r;
  r.u = uu/zs; r.v = vv/zs;
  r.vis = (zz > 0.1f) && (r.u >= 0.f) && (r.u <= (float)(WW-1)) && (r.v >= 0.f) && (r.v <= (float)(HH-1));
  return r;
}

// ---------------- K1: gray ----------------
__global__ void k_gray(const float* __restrict__ imgs, float* __restrict__ gray){
  int t = blockIdx.x*blockDim.x + threadIdx.x;
  if (t >= BB*HWsz) return;
  int b = t / HWsz, p = t - b*HWsz;
  const float* base = imgs + (size_t)b*3*HWsz;
  gray[t] = 0.299f*base[p] + 0.587f*base[HWsz+p] + 0.114f*base[2*HWsz+p];
}

// ---------------- K2: sobel (edge pad) + products ----------------
__global__ void k_sobel(const float* __restrict__ gray, float* __restrict__ gxx,
                        float* __restrict__ gyy, float* __restrict__ gxy){
  int t = blockIdx.x*blockDim.x + threadIdx.x;
  if (t >= BB*HWsz) return;
  int b = t / HWsz, p = t - b*HWsz;
  int y = p / WW, x = p - y*WW;
  const float* g = gray + (size_t)b*HWsz;
  int ym = clampi(y-1,0,HH-1), yp = clampi(y+1,0,HH-1);
  int xm = clampi(x-1,0,WW-1), xp = clampi(x+1,0,WW-1);
  float g00 = g[ym*WW+xm], g01 = g[ym*WW+x], g02 = g[ym*WW+xp];
  float g10 = g[y*WW+xm],                    g12 = g[y*WW+xp];
  float g20 = g[yp*WW+xm], g21 = g[yp*WW+x], g22 = g[yp*WW+xp];
  float gx = 0.125f*(g02-g00) + 0.25f*(g12-g10) + 0.125f*(g22-g20);
  float gy = 0.125f*(g20-g00) + 0.25f*(g21-g01) + 0.125f*(g22-g02);
  gxx[t] = gx*gx; gyy[t] = gy*gy; gxy[t] = gx*gy;
}

// ---------------- K3: gaussian 7x7 (reflect) + GFTT response ----------------
__global__ void k_gauss_resp(const float* __restrict__ gxx, const float* __restrict__ gyy,
                             const float* __restrict__ gxy, float* __restrict__ resp){
  int t = blockIdx.x*blockDim.x + threadIdx.x;
  if (t >= BB*HWsz) return;
  int b = t / HWsz, p = t - b*HWsz;
  int y = p / WW, x = p - y*WW;
  const float* axx = gxx + (size_t)b*HWsz;
  const float* ayy = gyy + (size_t)b*HWsz;
  const float* axy = gxy + (size_t)b*HWsz;
  float sxx=0.f, syy=0.f, sxy=0.f;
  if (y >= 3 && y < HH-3 && x >= 3 && x < WW-3){
    int base = (y-3)*WW + (x-3);
    #pragma unroll
    for (int i=0;i<7;++i){
      const float* rxx = axx + base + i*WW;
      const float* ryy = ayy + base + i*WW;
      const float* rxy = axy + base + i*WW;
      float wr = GW[i];
      #pragma unroll
      for (int j=0;j<7;++j){
        float wc = wr*GW[j];
        sxx += wc*rxx[j]; syy += wc*ryy[j]; sxy += wc*rxy[j];
      }
    }
  } else {
    #pragma unroll
    for (int i=0;i<7;++i){
      int ry = refl(y+i-3, HH);
      const float* rxx = axx + (size_t)ry*WW;
      const float* ryy = ayy + (size_t)ry*WW;
      const float* rxy = axy + (size_t)ry*WW;
      float wr = GW[i];
      #pragma unroll
      for (int j=0;j<7;++j){
        int rx = refl(x+j-3, WW);
        float wc = wr*GW[j];
        sxx += wc*rxx[rx]; syy += wc*ryy[rx]; sxy += wc*rxy[rx];
      }
    }
  }
  float tr = sxx+syy, df = sxx-syy;
  float disc = sqrtf(fmaxf(df*df + 4.f*sxy*sxy, 0.f));
  resp[t] = 0.5f*(tr - disc);
}

// ---------------- K4: 5x5 NMS (pad -inf) ----------------
__global__ void k_nms5(const float* __restrict__ resp, float* __restrict__ keep){
  int t = blockIdx.x*blockDim.x + threadIdx.x;
  if (t >= BB*HWsz) return;
  int b = t / HWsz, p = t - b*HWsz;
  int y = p / WW, x = p - y*WW;
  const float* rb = resp + (size_t)b*HWsz;
  float m = -1e30f;
  if (y >= 2 && y < HH-2 && x >= 2 && x < WW-2){
    int base = (y-2)*WW + (x-2);
    #pragma unroll
    for (int dy=0; dy<5; ++dy){
      const float* rr = rb + base + dy*WW;
      #pragma unroll
      for (int dx=0; dx<5; ++dx) m = fmaxf(m, rr[dx]);
    }
  } else {
    for (int dy=-2; dy<=2; ++dy){
      int yy = y+dy; if (yy<0||yy>=HH) continue;
      for (int dx=-2; dx<=2; ++dx){
        int xx2 = x+dx; if (xx2<0||xx2>=WW) continue;
        m = fmaxf(m, rb[yy*WW+xx2]);
      }
    }
  }
  float r = rb[p];
  keep[t] = (r == m) ? r : 0.f;
}

// ---------------- K5: 8x8 block max, DETERMINISTIC slot per block (no hot atomics) ----------------
// one wave per 8x8 block; winner rank-0 writes ckeys[b][r]; tie ranks >=1 overflow past NBLK.
__global__ void k_blockmax_compact(const float* __restrict__ keep,
        unsigned long long* __restrict__ ckeys, unsigned int* __restrict__ ccnt){
  int gw = (blockIdx.x*(int)blockDim.x + (int)threadIdx.x) >> 6;   // global wave id
  int lane = threadIdx.x & 63;
  if (gw >= BB*NBLK) return;
  int b = gw / NBLK; int r = gw - b*NBLK;
  int by = r / (WW/8), bx = r - by*(WW/8);
  int yy = by*8 + (lane >> 3), xx2 = bx*8 + (lane & 7);
  float v = keep[(size_t)b*HWsz + (size_t)yy*WW + xx2];
  float bm = wave_max(v);
  if (!(bm > 0.f)) return;
  unsigned long long mask = __ballot(v == bm);
  if (v == bm){
    unsigned long long key =
      ((unsigned long long)__float_as_uint(bm) << 32) |
      (unsigned long long)(0xFFFFFFFFu - (unsigned int)(yy*WW + xx2));
    int rank = __popcll(mask & ((1ull << lane) - 1ull));
    if (rank == 0){
      ckeys[(size_t)b*CAP + r] = key;               // fixed slot, no atomic
    } else {
      unsigned int slot = NBLK + atomicAdd(&ccnt[b], 1u);  // ties only (~never)
      if (slot < CAP) ckeys[(size_t)b*CAP + slot] = key;
    }
  }
}

// ---------------- K6: bitonic top-500 per batch (sorts all CAP slots) ----------------
__global__ __launch_bounds__(1024) void k_top500(const unsigned long long* __restrict__ ckeys,
        float* __restrict__ cpts, float* __restrict__ cvals){
  __shared__ unsigned long long sk[CAP];
  int b = blockIdx.x;
  int tid = threadIdx.x;
  for (int i = tid; i < CAP; i += 1024)
    sk[i] = ckeys[(size_t)b*CAP + i];
  __syncthreads();
  for (int k = 2; k <= CAP; k <<= 1){
    for (int j = k >> 1; j > 0; j >>= 1){
      for (int i = tid; i < CAP; i += 1024){
        int l = i ^ j;
        if (l > i){
          unsigned long long A = sk[i], Bv = sk[l];
          bool up = ((i & k) == 0);
          if ((A > Bv) == up){ sk[i] = Bv; sk[l] = A; }
        }
      }
      __syncthreads();
    }
  }
  if (tid < NC){
    unsigned long long key = sk[CAP-1-tid];   // descending order
    float val = __uint_as_float((unsigned int)(key >> 32));
    size_t o = (size_t)b*NC + tid;
    if (val > 0.f){
      unsigned int idx = 0xFFFFFFFFu - (unsigned int)(key & 0xFFFFFFFFull);
      float fx = (float)(idx % WW), fy = (float)(idx / WW);
      cpts[o*2+0] = (fx*2.0f)/(float)(WW-1) - 1.0f;
      cpts[o*2+1] = (fy*2.0f)/(float)(HH-1) - 1.0f;
      cvals[o] = val;
    } else {
      cpts[o*2+0] = __int_as_float(0x7fc00000);
      cpts[o*2+1] = __int_as_float(0x7fc00000);
      cvals[o] = 0.f;
    }
  }
}

// ---------------- K7: corner projection + scatter-max ----------------
__global__ void k_corner_scatter(const float* __restrict__ cpts, const float* __restrict__ cvals,
        const float* __restrict__ depths, const float* __restrict__ poses,
        const float* __restrict__ Km, unsigned int* __restrict__ target){
  int t = blockIdx.x*blockDim.x + threadIdx.x;
  if (t >= BB*BB*NC) return;
  int i = t / (BB*NC); int r = t - i*(BB*NC); int j = r / NC; int n = r - j*NC;
  float val = cvals[(size_t)i*NC + n];
  float ptx = cpts[((size_t)j*NC+n)*2+0];
  float pty = cpts[((size_t)j*NC+n)*2+1];
  if (!(val > 0.f) || ptx != ptx) return;
  Proj pr = project_point(ptx, pty, j, i, depths, poses, Km);
  if (!pr.vis) return;
  float nu = (pr.u*2.0f)/(float)(WW-1) - 1.0f;
  float nv = (pr.v*2.0f)/(float)(HH-1) - 1.0f;
  float px2 = ((nu+1.0f)*(float)(WW-1))*0.5f;
  float py2 = ((nv+1.0f)*(float)(HH-1))*0.5f;
  float rx = rintf(px2), ry = rintf(py2);
  if (!(rx >= 0.f && ry >= 0.f && rx <= (float)(WW-1) && ry <= (float)(HH-1))) return;
  int wf = (int)rx, hf = (int)ry;
  atomicMax(&target[(size_t)j*HWsz + hf*WW + wf], __float_as_uint(val));
}

// ---------------- K8: target NMS + BCE + laplacian reduce ----------------
__global__ void k_score_reduce(const float* __restrict__ target, const float* __restrict__ scores,
        double* __restrict__ acc){
  __shared__ float rb[4][2];
  int t = blockIdx.x*blockDim.x + threadIdx.x;
  float bce = 0.f, extra = 0.f;
  if (t < BB*HWsz){
    int b = t / HWsz, p = t - b*HWsz;
    int y = p / WW, x = p - y*WW;
    const float* tg = target + (size_t)b*HWsz;
    const float* sb = scores + (size_t)b*HWsz;
    float tv = tg[p];
    float m = -1e30f;
    float S5 = 0.f;
    if (y >= 2 && y < HH-2 && x >= 2 && x < WW-2){
      int base = (y-2)*WW + (x-2);
      #pragma unroll
      for (int dy=0; dy<5; ++dy){
        const float* tr = tg + base + dy*WW;
        const float* sr = sb + base + dy*WW;
        #pragma unroll
        for (int dx=0; dx<5; ++dx){ m = fmaxf(m, tr[dx]); S5 += sr[dx]; }
      }
    } else {
      for (int dy=-2; dy<=2; ++dy){
        int yy = y+dy; if (yy<0||yy>=HH) continue;
        for (int dx=-2; dx<=2; ++dx){
          int xx2 = x+dx; if (xx2<0||xx2>=WW) continue;
          m = fmaxf(m, tg[yy*WW+xx2]);
        }
      }
      for (int dy=-2; dy<=2; ++dy){
        int yy = refl(y+dy, HH);
        for (int dx=-2; dx<=2; ++dx){
          int xx2 = refl(x+dx, WW);
          S5 += sb[yy*WW+xx2];
        }
      }
    }
    float tb = (tv > 0.f && tv == m) ? 1.f : 0.f;
    float sc = sb[p];
    float pc = fminf(fmaxf(sc, 1e-12f), 1.0f - 1e-12f);
    bce = -(tb*logf(pc) + (1.f-tb)*logf(1.f-pc));
    float lap = (S5 - sc)*(1.0f/48.0f) - 0.5f*sc;
    extra = sc*expf(-lap);
  }
  bce = wave_sum(bce); extra = wave_sum(extra);
  int wave = threadIdx.x >> 6, lane = threadIdx.x & 63;
  if (lane == 0){ rb[wave][0] = bce; rb[wave][1] = extra; }
  __syncthreads();
  if (threadIdx.x == 0){
    float B0 = rb[0][0]+rb[1][0]+rb[2][0]+rb[3][0];
    float E0 = rb[0][1]+rb[1][1]+rb[2][1]+rb[3][1];
    atomicAdd(&acc[1], (double)B0);
    atomicAdd(&acc[2], (double)E0);
  }
}

// ---------------- K9a: row sum-of-squares + bf16 convert ----------------
__global__ void k_rownorm_bf16(const float* __restrict__ desc, float* __restrict__ xx,
                               unsigned short* __restrict__ dbf){
  int t = blockIdx.x*blockDim.x + threadIdx.x;
  if (t >= BB*NPTS) return;
  const float* dptr = desc + (size_t)t*DD;
  unsigned short* optr = dbf + (size_t)t*DD;
  float s = 0.f;
  for (int d = 0; d < DD; d += 4){
    float4 v = *(const float4*)(dptr + d);
    s += v.x*v.x + v.y*v.y + v.z*v.z + v.w*v.w;
    unsigned int u0 = __float_as_uint(v.x); optr[d+0] = (unsigned short)((u0 + 0x7fffu + ((u0>>16)&1u)) >> 16);
    unsigned int u1 = __float_as_uint(v.y); optr[d+1] = (unsigned short)((u1 + 0x7fffu + ((u1>>16)&1u)) >> 16);
    unsigned int u2 = __float_as_uint(v.z); optr[d+2] = (unsigned short)((u2 + 0x7fffu + ((u2>>16)&1u)) >> 16);
    unsigned int u3 = __float_as_uint(v.w); optr[d+3] = (unsigned short)((u3 + 0x7fffu + ((u3>>16)&1u)) >> 16);
  }
  xx[t] = s;
}

// ---------------- K9b: project input points (raw proj + vis) ----------------
__global__ void k_proj_points(const float* __restrict__ points, const float* __restrict__ depths,
        const float* __restrict__ poses, const float* __restrict__ Km,
        float* __restrict__ mproj, unsigned char* __restrict__ mvis){
  int t = blockIdx.x*blockDim.x + threadIdx.x;
  if (t >= BB*BB*NPTS) return;
  int i = t / (BB*NPTS); int r = t - i*(BB*NPTS); int j = r / NPTS; int n = r - j*NPTS;
  float ptx = points[((size_t)j*NPTS+n)*2+0];
  float pty = points[((size_t)j*NPTS+n)*2+1];
  Proj pr = project_point(ptx, pty, j, i, depths, poses, Km);
  mproj[(size_t)t*2+0] = (pr.u*2.0f)/(float)(WW-1) - 1.0f;
  mproj[(size_t)t*2+1] = (pr.v*2.0f)/(float)(HH-1) - 1.0f;
  mvis[t] = pr.vis ? 1 : 0;
}

// ---------------- K10: distinction via MFMA (multi-tile blocks) ----------------
// grid (16 mt, 2 nh, BB); block = 4 waves; each block: 8 column tiles
__global__ __launch_bounds__(256) void k_distinction_mfma(const unsigned short* __restrict__ dbf,
        const float* __restrict__ xx, double* __restrict__ acc){
  __shared__ float rb[4];
  int b = blockIdx.z;
  int mt = blockIdx.x, nh = blockIdx.y;
  int tid = threadIdx.x;
  int wave = tid >> 6, lane = tid & 63;
  int wr = mt*64 + (wave&1)*32;
  int wco = (wave>>1)*32;
  int r = lane & 15, kg = lane >> 4;
  const unsigned short* descb = dbf + (size_t)b*NPTS*DD;
  const float* xb = xx + (size_t)b*NPTS;
  // A frags + m-side norms (loaded once)
  bf16x8 af[4][2];
  #pragma unroll
  for (int ks = 0; ks < 4; ++ks){
    int ko = ks*32 + kg*8;
    af[ks][0] = *(const bf16x8*)(descb + (size_t)(wr+r)*DD + ko);
    af[ks][1] = *(const bf16x8*)(descb + (size_t)(wr+16+r)*DD + ko);
  }
  float mxx[2][4];
  #pragma unroll
  for (int mi = 0; mi < 2; ++mi)
    #pragma unroll
    for (int j = 0; j < 4; ++j)
      mxx[mi][j] = xb[wr + mi*16 + 4*kg + j];
  float local = 0.f;
  for (int nt = nh*8; nt < nh*8+8; ++nt){
    int wc = nt*64 + wco;
    float xn0 = xb[wc + r], xn1 = xb[wc + 16 + r];
    f32x4 c00 = {}, c01 = {}, c10 = {}, c11 = {};
    #pragma unroll
    for (int ks = 0; ks < 4; ++ks){
      int ko = ks*32 + kg*8;
      bf16x8 b0 = *(const bf16x8*)(descb + (size_t)(wc+r)*DD + ko);
      bf16x8 b1 = *(const bf16x8*)(descb + (size_t)(wc+16+r)*DD + ko);
      c00 = __builtin_amdgcn_mfma_f32_16x16x32_bf16(af[ks][0], b0, c00, 0, 0, 0);
      c01 = __builtin_amdgcn_mfma_f32_16x16x32_bf16(af[ks][0], b1, c01, 0, 0, 0);
      c10 = __builtin_amdgcn_mfma_f32_16x16x32_bf16(af[ks][1], b0, c10, 0, 0, 0);
      c11 = __builtin_amdgcn_mfma_f32_16x16x32_bf16(af[ks][1], b1, c11, 0, 0, 0);
    }
    #pragma unroll
    for (int mi = 0; mi < 2; ++mi){
      #pragma unroll
      for (int j = 0; j < 4; ++j){
        float xm = mxx[mi][j];
        float v0 = (mi ? c10[j] : c00[j]);
        float v1 = (mi ? c11[j] : c01[j]);
        local += fmaxf(v0 / sqrtf(fmaxf(xm*xn0, 1e-16f)), 0.f);
        local += fmaxf(v1 / sqrtf(fmaxf(xm*xn1, 1e-16f)), 0.f);
      }
    }
  }
  local = wave_sum(local);
  if (lane == 0) rb[wave] = local;
  __syncthreads();
  if (tid == 0) atomicAdd(&acc[0], (double)(rb[0]+rb[1]+rb[2]+rb[3]));
}

// ---------------- K11: match via MFMA (balanced multi-tile blocks) ----------------
// grid (8 pair, 1, 36); block p owns row-tiles {p, 15-p} -> 17 tiles total
__global__ __launch_bounds__(256) void k_match_mfma(const unsigned short* __restrict__ dbf,
        const float* __restrict__ xx, const float* __restrict__ points,
        const float* __restrict__ mproj, const unsigned char* __restrict__ mvis,
        double* __restrict__ acc, unsigned long long* __restrict__ cnts){
  __shared__ float rb[4][4];
  int ab = blockIdx.z; int a = ab / BB, b = ab - a*BB;
  int pairIdx = blockIdx.x;
  int tid = threadIdx.x;
  int wave = tid >> 6, lane = tid & 63;
  int wro = (wave&1)*32, wco = (wave>>1)*32;
  int r = lane & 15, kg = lane >> 4;
  const unsigned short* descA = dbf + (size_t)a*NPTS*DD;
  const unsigned short* descB = dbf + (size_t)b*NPTS*DD;
  const float* xxa = xx + (size_t)a*NPTS;
  const float* xxb = xx + (size_t)b*NPTS;
  const float* pts = points + (size_t)b*NPTS*2;
  const float* mp  = mproj + (((size_t)a*BB+b)*NPTS)*2;
  const unsigned char* mv = mvis + ((size_t)a*BB+b)*NPTS;
  float pos = 0.f, neg = 0.f, pcf = 0.f, ncf = 0.f;
  #pragma unroll
  for (int seg = 0; seg < 2; ++seg){
    int mt = seg ? (15 - pairIdx) : pairIdx;
    int wr = mt*64 + wro;
    bf16x8 af[4][2];
    #pragma unroll
    for (int ks = 0; ks < 4; ++ks){
      int ko = ks*32 + kg*8;
      af[ks][0] = *(const bf16x8*)(descA + (size_t)(wr+r)*DD + ko);
      af[ks][1] = *(const bf16x8*)(descA + (size_t)(wr+16+r)*DD + ko);
    }
    float msx[2][4], msy[2][4], mx2[2][4], mxx[2][4];
    bool  mok[2][4];
    #pragma unroll
    for (int mi = 0; mi < 2; ++mi){
      #pragma unroll
      for (int j = 0; j < 4; ++j){
        int m = wr + mi*16 + 4*kg + j;
        mok[mi][j] = (mv[m] != 0);
        float px = pts[m*2+0], py = pts[m*2+1];
        float sx = ((px+1.f)*(float)(WW-1))*0.5f;
        float sy = ((py+1.f)*(float)(HH-1))*0.5f;
        msx[mi][j] = sx; msy[mi][j] = sy;
        mx2[mi][j] = sx*sx + sy*sy;
        mxx[mi][j] = xxa[m];
      }
    }
    for (int nt = mt; nt < 16; ++nt){
      int wc = nt*64 + wco;
      float nxxv[2], ndx[2], ndy[2], ny2[2];
      #pragma unroll
      for (int ni = 0; ni < 2; ++ni){
        int n = wc + ni*16 + r;
        nxxv[ni] = xxb[n];
        float qx = mp[n*2+0], qy = mp[n*2+1];
        float dx = ((qx+1.f)*(float)(WW-1))*0.5f;
        float dy = ((qy+1.f)*(float)(HH-1))*0.5f;
        ndx[ni] = dx; ndy[ni] = dy;
        ny2[ni] = dx*dx + dy*dy;
      }
      f32x4 c00 = {}, c01 = {}, c10 = {}, c11 = {};
      #pragma unroll
      for (int ks = 0; ks < 4; ++ks){
        int ko = ks*32 + kg*8;
        bf16x8 b0 = *(const bf16x8*)(descB + (size_t)(wc+r)*DD + ko);
        bf16x8 b1 = *(const bf16x8*)(descB + (size_t)(wc+16+r)*DD + ko);
        c00 = __builtin_amdgcn_mfma_f32_16x16x32_bf16(af[ks][0], b0, c00, 0, 0, 0);
        c01 = __builtin_amdgcn_mfma_f32_16x16x32_bf16(af[ks][0], b1, c01, 0, 0, 0);
        c10 = __builtin_amdgcn_mfma_f32_16x16x32_bf16(af[ks][1], b0, c10, 0, 0, 0);
        c11 = __builtin_amdgcn_mfma_f32_16x16x32_bf16(af[ks][1], b1, c11, 0, 0, 0);
      }
      #pragma unroll
      for (int mi = 0; mi < 2; ++mi){
        #pragma unroll
        for (int j = 0; j < 4; ++j){
          if (!mok[mi][j]) continue;
          int m = wr + mi*16 + 4*kg + j;
          float sx = msx[mi][j], sy = msy[mi][j];
          float x2 = mx2[mi][j], xm = mxx[mi][j];
          #pragma unroll
          for (int ni = 0; ni < 2; ++ni){
            int n = wc + ni*16 + r;
            if (m >= n) continue;
            float dv = (mi ? (ni ? c11[j] : c10[j]) : (ni ? c01[j] : c00[j]));
            float d2 = x2 + ny2[ni] - 2.f*(sx*ndx[ni] + sy*ndy[ni]);
            float den = sqrtf(fmaxf(xm * nxxv[ni], 1e-16f));
            float p = dv/den;
            if (d2 <= 1.0f){ pos += p; pcf += 1.f; }
            else           { neg += p; ncf += 1.f; }
          }
        }
      }
    }
  }
  pos = wave_sum(pos); neg = wave_sum(neg);
  pcf = wave_sum(pcf); ncf = wave_sum(ncf);
  if (lane == 0){ rb[wave][0] = pos; rb[wave][1] = neg; rb[wave][2] = pcf; rb[wave][3] = ncf; }
  __syncthreads();
  if (tid == 0){
    float sP  = rb[0][0]+rb[1][0]+rb[2][0]+rb[3][0];
    float sN  = rb[0][1]+rb[1][1]+rb[2][1]+rb[3][1];
    float sPC = rb[0][2]+rb[1][2]+rb[2][2]+rb[3][2];
    float sNC = rb[0][3]+rb[1][3]+rb[2][3]+rb[3][3];
    atomicAdd(&acc[3], (double)sP);
    atomicAdd(&acc[4], (double)sN);
    atomicAdd(&cnts[0], (unsigned long long)(sPC + 0.5f));
    atomicAdd(&cnts[1], (unsigned long long)(sNC + 0.5f));
  }
}

// ---------------- K12: finalize ----------------
__global__ void k_final(const double* __restrict__ acc, const unsigned long long* __restrict__ cnts,
                        float* __restrict__ out){
  double distinction = acc[0] / (double)((long long)BB*NPTS*NPTS);
  double bce = acc[1] / (double)((long long)BB*HWsz);
  double extra = acc[2] / (double)((long long)BB*HWsz);
  double cornerness = bce + 10.0*extra;
  unsigned long long pc = cnts[0], nc = cnts[1];
  double pos_mean = acc[3] / (double)(pc ? pc : 1ull);
  double neg_mean = acc[4] / (double)(nc ? nc : 1ull);
  double match = 1.0 - pos_mean + neg_mean;
  out[0] = (float)(distinction + 0.5*cornerness + match);
}

extern "C" void kernel_launch(void* const* d_in, const int* in_sizes, int n_in,
                              void* d_out, int out_size, void* d_ws, size_t ws_size,
                              hipStream_t stream) {
  (void)in_sizes; (void)n_in; (void)out_size; (void)ws_size;
  const float* desc   = (const float*)d_in[0];
  const float* points = (const float*)d_in[1];
  const float* scores = (const float*)d_in[2];
  const float* depths = (const float*)d_in[3];
  const float* poses  = (const float*)d_in[4];
  const float* Km     = (const float*)d_in[5];
  const float* imgs   = (const float*)d_in[6];
  float* out = (float*)d_out;

  const size_t S = (size_t)BB*HWsz;
  float* gray = (float*)d_ws;          // S  (later: resp)
  float* bx   = gray + S;              // S  gxx -> keep
  float* by   = bx + S;                // S  gyy -> target
  float* bxy  = by + S;                // S  gxy
  float* resp = gray;                  // reuse
  float* keep = bx;                    // reuse
  unsigned long long* ckeys = (unsigned long long*)(bxy + S);      // BB*CAP
  unsigned int* ccnt = (unsigned int*)(ckeys + (size_t)BB*CAP);    // 6
  double* acc = (double*)(ccnt + 6);                               // 5 doubles
  unsigned long long* cnts = (unsigned long long*)(acc + 5);       // 2
  float* cpts  = (float*)(cnts + 2);                               // BB*NC*2
  float* cvals = cpts + (size_t)BB*NC*2;                           // BB*NC
  float* xx    = cvals + (size_t)BB*NC;                            // BB*NPTS
  float* mproj = xx + (size_t)BB*NPTS;                             // BB*BB*NPTS*2
  unsigned char* mvis = (unsigned char*)(mproj + (size_t)BB*BB*NPTS*2); // BB*BB*NPTS
  unsigned short* dbf = (unsigned short*)(mvis + (size_t)BB*BB*NPTS);   // BB*NPTS*DD bf16

  const int npx = BB*HWsz;
  dim3 blk(256);
  dim3 gpx((npx + 255)/256);

  k_gray<<<gpx, blk, 0, stream>>>(imgs, gray);
  k_sobel<<<gpx, blk, 0, stream>>>(gray, bx, by, bxy);
  k_gauss_resp<<<gpx, blk, 0, stream>>>(bx, by, bxy, resp);

  // zero target (reuses gyy buffer: must be AFTER k_gauss_resp) and
  // the contiguous ckeys/ccnt/acc/cnts region (ckeys MUST be zeroed: fixed-slot writes)
  hipMemsetAsync(by, 0, S*sizeof(float), stream);
  hipMemsetAsync(ckeys, 0,
      (size_t)BB*CAP*sizeof(unsigned long long) + 6*sizeof(unsigned int) +
      5*sizeof(double) + 2*sizeof(unsigned long long), stream);

  k_nms5<<<gpx, blk, 0, stream>>>(resp, keep);
  {
    int n = BB*NBLK*64;   // one wave per 8x8 block
    k_blockmax_compact<<<dim3((n+255)/256), blk, 0, stream>>>(keep, ckeys, ccnt);
  }
  k_top500<<<dim3(BB), dim3(1024), 0, stream>>>(ckeys, cpts, cvals);
  {
    int n = BB*BB*NC;
    k_corner_scatter<<<dim3((n+255)/256), blk, 0, stream>>>(cpts, cvals, depths, poses, Km,
                                                            (unsigned int*)by);
  }
  k_score_reduce<<<gpx, blk, 0, stream>>>(by, scores, acc);
  {
    int n = BB*NPTS;
    k_rownorm_bf16<<<dim3((n+255)/256), blk, 0, stream>>>(desc, xx, dbf);
  }
  {
    int n = BB*BB*NPTS;
    k_proj_points<<<dim3((n+255)/256), blk, 0, stream>>>(points, depths, poses, Km, mproj, mvis);
  }
  k_distinction_mfma<<<dim3(16, 2, BB), blk, 0, stream>>>(dbf, xx, acc);
  k_match_mfma<<<dim3(8, 1, BB*BB), blk, 0, stream>>>(dbf, xx, points, mproj, mvis, acc, cnts);
  k_final<<<dim3(1), dim3(1), 0, stream>>>(acc, cnts, out);
}

// Round 9
// 238.454 us; speedup vs baseline: 2.6119x; 1.3198x over previous
//
#include <hip/hip_runtime.h>
#include <stdint.h>

#define BB 6
#define NPTS 1024
#define DD 128
#define HH 320
#define WW 320
#define NC 500
#define HWsz (HH*WW)
#define CAP 2048
#define NBLK ((HH/8)*(WW/8))   // 1600 8x8 blocks per batch
#define TX 32
#define TY 8
#define NSLOT 64
// slot accumulators: 7 quantities x 64 slots, each slot on its own 64B line
// q: 0=distinction 1=bce 2=extra 3=pos 4=neg 5=pcnt 6=ncnt

typedef __attribute__((ext_vector_type(8))) short bf16x8;
typedef __attribute__((ext_vector_type(4))) float f32x4;

__device__ __forceinline__ int clampi(int v, int lo, int hi){ return v<lo?lo:(v>hi?hi:v); }
__device__ __forceinline__ int refl(int p, int L){ if(p<0)p=-p; if(p>=L)p=2*L-2-p; return p; }

__device__ __forceinline__ float wave_sum(float v){
  #pragma unroll
  for (int o = 32; o > 0; o >>= 1) v += __shfl_xor(v, o, 64);
  return v;
}
__device__ __forceinline__ double wave_sumd(double v){
  #pragma unroll
  for (int o = 32; o > 0; o >>= 1) v += __shfl_xor(v, o, 64);
  return v;
}
__device__ __forceinline__ float wave_max(float v){
  #pragma unroll
  for (int o = 32; o > 0; o >>= 1) v = fmaxf(v, __shfl_xor(v, o, 64));
  return v;
}

__device__ __constant__ float GW[7] = {
  0.0044330481f, 0.0540055850f, 0.2420362300f, 0.3990502700f,
  0.2420362300f, 0.0540055850f, 0.0044330481f };

// ---------------- projection (matches pairwise_project) ----------------
struct Proj { float u, v; int vis; };

__device__ Proj project_point(float ptx, float pty, int jsrc, int itgt,
                              const float* __restrict__ depths,
                              const float* __restrict__ poses,
                              const float* __restrict__ Km)
{
  float pxx = ((ptx + 1.0f)*(float)(WW-1))*0.5f;
  float pxy = ((pty + 1.0f)*(float)(HH-1))*0.5f;
  float rx = rintf(pxx), ry = rintf(pxy);
  rx = fminf(fmaxf(rx, 0.f), (float)(WW-1));
  ry = fminf(fmaxf(ry, 0.f), (float)(HH-1));
  int xi = (int)rx, yi = (int)ry;
  float d = depths[(size_t)jsrc*HWsz + yi*WW + xi];
  float a00=Km[0],a01=Km[1],a02=Km[2],a10=Km[3],a11=Km[4],a12=Km[5],a20=Km[6],a21=Km[7],a22=Km[8];
  float det = a00*(a11*a22 - a12*a21) - a01*(a10*a22 - a12*a20) + a02*(a10*a21 - a11*a20);
  float id_ = 1.0f/det;
  float i00 = (a11*a22 - a12*a21)*id_;
  float i01 = (a02*a21 - a01*a22)*id_;
  float i02 = (a01*a12 - a02*a11)*id_;
  float i10 = (a12*a20 - a10*a22)*id_;
  float i11 = (a00*a22 - a02*a20)*id_;
  float i12 = (a02*a10 - a00*a12)*id_;
  float i20 = (a10*a21 - a11*a20)*id_;
  float i21 = (a01*a20 - a00*a21)*id_;
  float i22 = (a00*a11 - a01*a10)*id_;
  float c0 = (i00*pxx + i01*pxy + i02)*d;
  float c1 = (i10*pxx + i11*pxy + i12)*d;
  float c2 = (i20*pxx + i21*pxy + i22)*d;
  const float* Pj = poses + (size_t)jsrc*16;
  float w0 = Pj[0]*c0 + Pj[1]*c1 + Pj[2]*c2  + Pj[3];
  float w1 = Pj[4]*c0 + Pj[5]*c1 + Pj[6]*c2  + Pj[7];
  float w2 = Pj[8]*c0 + Pj[9]*c1 + Pj[10]*c2 + Pj[11];
  const float* Pi = poses + (size_t)itgt*16;
  float dx = w0 - Pi[3], dy = w1 - Pi[7], dz = w2 - Pi[11];
  float e0 = Pi[0]*dx + Pi[4]*dy + Pi[8]*dz;
  float e1 = Pi[1]*dx + Pi[5]*dy + Pi[9]*dz;
  float e2 = Pi[2]*dx + Pi[6]*dy + Pi[10]*dz;
  float uu = a00*e0 + a01*e1 + a02*e2;
  float vv = a10*e0 + a11*e1 + a12*e2;
  float zz = a20*e0 + a21*e1 + a22*e2;
  float zs = (fabsf(zz) > 1e-6f) ? zz : 1e-6f;
  Proj r;
  r.u = uu/zs; r.v = vv/zs;
  r.vis = (zz > 0.1f) && (r.u >= 0.f) && (r.u <= (float)(WW-1)) && (r.v >= 0.f) && (r.v <= (float)(HH-1));
  return r;
}

// ---------------- K1: gray ----------------
__global__ void k_gray(const float* __restrict__ imgs, float* __restrict__ gray){
  int t = blockIdx.x*blockDim.x + threadIdx.x;
  if (t >= BB*HWsz) return;
  int b = t / HWsz, p = t - b*HWsz;
  const float* base = imgs + (size_t)b*3*HWsz;
  gray[t] = 0.299f*base[p] + 0.587f*base[HWsz+p] + 0.114f*base[2*HWsz+p];
}

// ---------------- K2: sobel (edge pad) + products ----------------
__global__ void k_sobel(const float* __restrict__ gray, float* __restrict__ gxx,
                        float* __restrict__ gyy, float* __restrict__ gxy){
  int t = blockIdx.x*blockDim.x + threadIdx.x;
  if (t >= BB*HWsz) return;
  int b = t / HWsz, p = t - b*HWsz;
  int y = p / WW, x = p - y*WW;
  const float* g = gray + (size_t)b*HWsz;
  int ym = clampi(y-1,0,HH-1), yp = clampi(y+1,0,HH-1);
  int xm = clampi(x-1,0,WW-1), xp = clampi(x+1,0,WW-1);
  float g00 = g[ym*WW+xm], g01 = g[ym*WW+x], g02 = g[ym*WW+xp];
  float g10 = g[y*WW+xm],                    g12 = g[y*WW+xp];
  float g20 = g[yp*WW+xm], g21 = g[yp*WW+x], g22 = g[yp*WW+xp];
  float gx = 0.125f*(g02-g00) + 0.25f*(g12-g10) + 0.125f*(g22-g20);
  float gy = 0.125f*(g20-g00) + 0.25f*(g21-g01) + 0.125f*(g22-g02);
  gxx[t] = gx*gx; gyy[t] = gy*gy; gxy[t] = gx*gy;
}

// ---------------- K3: gaussian 7x7 (reflect) + GFTT response, LDS-tiled ----------------
// grid (WW/TX, HH/TY, BB), block 256 = TX*TY
__global__ __launch_bounds__(256) void k_gauss_resp(const float* __restrict__ gxx,
        const float* __restrict__ gyy, const float* __restrict__ gxy, float* __restrict__ resp){
  __shared__ float lxx[TY+6][TX+6], lyy[TY+6][TX+6], lxy[TY+6][TX+6];
  int b = blockIdx.z;
  int x0 = blockIdx.x*TX, y0 = blockIdx.y*TY;
  const float* axx = gxx + (size_t)b*HWsz;
  const float* ayy = gyy + (size_t)b*HWsz;
  const float* axy = gxy + (size_t)b*HWsz;
  const int W2 = TX+6, H2 = TY+6;
  for (int i = threadIdx.x; i < H2*W2; i += 256){
    int ly = i / W2, lx = i - ly*W2;
    int gy = refl(y0 - 3 + ly, HH), gx = refl(x0 - 3 + lx, WW);
    size_t off = (size_t)gy*WW + gx;
    lxx[ly][lx] = axx[off]; lyy[ly][lx] = ayy[off]; lxy[ly][lx] = axy[off];
  }
  __syncthreads();
  int tx = threadIdx.x & (TX-1), ty = threadIdx.x / TX;
  float sxx=0.f, syy=0.f, sxy=0.f;
  #pragma unroll
  for (int i=0;i<7;++i){
    float wr = GW[i];
    #pragma unroll
    for (int j=0;j<7;++j){
      float wc = wr*GW[j];
      sxx += wc*lxx[ty+i][tx+j];
      syy += wc*lyy[ty+i][tx+j];
      sxy += wc*lxy[ty+i][tx+j];
    }
  }
  float tr = sxx+syy, df = sxx-syy;
  float disc = sqrtf(fmaxf(df*df + 4.f*sxy*sxy, 0.f));
  resp[(size_t)b*HWsz + (size_t)(y0+ty)*WW + (x0+tx)] = 0.5f*(tr - disc);
}

// ---------------- K4: 5x5 NMS (pad -inf), LDS-tiled ----------------
__global__ __launch_bounds__(256) void k_nms5(const float* __restrict__ resp, float* __restrict__ keep){
  __shared__ float lr[TY+4][TX+4];
  int b = blockIdx.z;
  int x0 = blockIdx.x*TX, y0 = blockIdx.y*TY;
  const float* rb = resp + (size_t)b*HWsz;
  const int W2 = TX+4, H2 = TY+4;
  for (int i = threadIdx.x; i < H2*W2; i += 256){
    int ly = i / W2, lx = i - ly*W2;
    int gy = y0 - 2 + ly, gx = x0 - 2 + lx;
    lr[ly][lx] = (gy >= 0 && gy < HH && gx >= 0 && gx < WW) ? rb[(size_t)gy*WW + gx] : -1e30f;
  }
  __syncthreads();
  int tx = threadIdx.x & (TX-1), ty = threadIdx.x / TX;
  float m = -1e30f;
  #pragma unroll
  for (int dy=0; dy<5; ++dy)
    #pragma unroll
    for (int dx=0; dx<5; ++dx) m = fmaxf(m, lr[ty+dy][tx+dx]);
  float r = lr[ty+2][tx+2];
  keep[(size_t)b*HWsz + (size_t)(y0+ty)*WW + (x0+tx)] = (r == m) ? r : 0.f;
}

// ---------------- K5: 8x8 block max, deterministic slot per block ----------------
__global__ void k_blockmax_compact(const float* __restrict__ keep,
        unsigned long long* __restrict__ ckeys, unsigned int* __restrict__ ccnt){
  int gw = (blockIdx.x*(int)blockDim.x + (int)threadIdx.x) >> 6;
  int lane = threadIdx.x & 63;
  if (gw >= BB*NBLK) return;
  int b = gw / NBLK; int r = gw - b*NBLK;
  int by = r / (WW/8), bx = r - by*(WW/8);
  int yy = by*8 + (lane >> 3), xx2 = bx*8 + (lane & 7);
  float v = keep[(size_t)b*HWsz + (size_t)yy*WW + xx2];
  float bm = wave_max(v);
  if (!(bm > 0.f)) return;
  unsigned long long mask = __ballot(v == bm);
  if (v == bm){
    unsigned long long key =
      ((unsigned long long)__float_as_uint(bm) << 32) |
      (unsigned long long)(0xFFFFFFFFu - (unsigned int)(yy*WW + xx2));
    int rank = __popcll(mask & ((1ull << lane) - 1ull));
    if (rank == 0){
      ckeys[(size_t)b*CAP + r] = key;               // fixed slot, no atomic
    } else {
      unsigned int slot = NBLK + atomicAdd(&ccnt[b], 1u);  // ties only (~never)
      if (slot < CAP) ckeys[(size_t)b*CAP + slot] = key;
    }
  }
}

// ---------------- K6: bitonic top-500 per batch ----------------
__global__ __launch_bounds__(1024) void k_top500(const unsigned long long* __restrict__ ckeys,
        float* __restrict__ cpts, float* __restrict__ cvals){
  __shared__ unsigned long long sk[CAP];
  int b = blockIdx.x;
  int tid = threadIdx.x;
  for (int i = tid; i < CAP; i += 1024)
    sk[i] = ckeys[(size_t)b*CAP + i];
  __syncthreads();
  for (int k = 2; k <= CAP; k <<= 1){
    for (int j = k >> 1; j > 0; j >>= 1){
      for (int i = tid; i < CAP; i += 1024){
        int l = i ^ j;
        if (l > i){
          unsigned long long A = sk[i], Bv = sk[l];
          bool up = ((i & k) == 0);
          if ((A > Bv) == up){ sk[i] = Bv; sk[l] = A; }
        }
      }
      __syncthreads();
    }
  }
  if (tid < NC){
    unsigned long long key = sk[CAP-1-tid];
    float val = __uint_as_float((unsigned int)(key >> 32));
    size_t o = (size_t)b*NC + tid;
    if (val > 0.f){
      unsigned int idx = 0xFFFFFFFFu - (unsigned int)(key & 0xFFFFFFFFull);
      float fx = (float)(idx % WW), fy = (float)(idx / WW);
      cpts[o*2+0] = (fx*2.0f)/(float)(WW-1) - 1.0f;
      cpts[o*2+1] = (fy*2.0f)/(float)(HH-1) - 1.0f;
      cvals[o] = val;
    } else {
      cpts[o*2+0] = __int_as_float(0x7fc00000);
      cpts[o*2+1] = __int_as_float(0x7fc00000);
      cvals[o] = 0.f;
    }
  }
}

// ---------------- K7: corner projection + scatter-max ----------------
__global__ void k_corner_scatter(const float* __restrict__ cpts, const float* __restrict__ cvals,
        const float* __restrict__ depths, const float* __restrict__ poses,
        const float* __restrict__ Km, unsigned int* __restrict__ target){
  int t = blockIdx.x*blockDim.x + threadIdx.x;
  if (t >= BB*BB*NC) return;
  int i = t / (BB*NC); int r = t - i*(BB*NC); int j = r / NC; int n = r - j*NC;
  float val = cvals[(size_t)i*NC + n];
  float ptx = cpts[((size_t)j*NC+n)*2+0];
  float pty = cpts[((size_t)j*NC+n)*2+1];
  if (!(val > 0.f) || ptx != ptx) return;
  Proj pr = project_point(ptx, pty, j, i, depths, poses, Km);
  if (!pr.vis) return;
  float nu = (pr.u*2.0f)/(float)(WW-1) - 1.0f;
  float nv = (pr.v*2.0f)/(float)(HH-1) - 1.0f;
  float px2 = ((nu+1.0f)*(float)(WW-1))*0.5f;
  float py2 = ((nv+1.0f)*(float)(HH-1))*0.5f;
  float rx = rintf(px2), ry = rintf(py2);
  if (!(rx >= 0.f && ry >= 0.f && rx <= (float)(WW-1) && ry <= (float)(HH-1))) return;
  int wf = (int)rx, hf = (int)ry;
  atomicMax(&target[(size_t)j*HWsz + hf*WW + wf], __float_as_uint(val));
}

// ---------------- K8: target NMS + BCE + laplacian, LDS-tiled + slot atomics ----------------
__global__ __launch_bounds__(256) void k_score_reduce(const float* __restrict__ target,
        const float* __restrict__ scores, double* __restrict__ accs){
  __shared__ float ltg[TY+4][TX+4], lsc[TY+4][TX+4];
  __shared__ float rbuf[4][2];
  int b = blockIdx.z;
  int x0 = blockIdx.x*TX, y0 = blockIdx.y*TY;
  const float* tg = target + (size_t)b*HWsz;
  const float* sb = scores + (size_t)b*HWsz;
  const int W2 = TX+4, H2 = TY+4;
  for (int i = threadIdx.x; i < H2*W2; i += 256){
    int ly = i / W2, lx = i - ly*W2;
    int gy = y0 - 2 + ly, gx = x0 - 2 + lx;
    ltg[ly][lx] = (gy >= 0 && gy < HH && gx >= 0 && gx < WW) ? tg[(size_t)gy*WW + gx] : -1e30f;
    lsc[ly][lx] = sb[(size_t)refl(gy,HH)*WW + refl(gx,WW)];
  }
  __syncthreads();
  int tx = threadIdx.x & (TX-1), ty = threadIdx.x / TX;
  float m = -1e30f, S5 = 0.f;
  #pragma unroll
  for (int dy=0; dy<5; ++dy)
    #pragma unroll
    for (int dx=0; dx<5; ++dx){
      m = fmaxf(m, ltg[ty+dy][tx+dx]);
      S5 += lsc[ty+dy][tx+dx];
    }
  float tv = ltg[ty+2][tx+2];
  float sc = lsc[ty+2][tx+2];
  float tb = (tv > 0.f && tv == m) ? 1.f : 0.f;
  float pc = fminf(fmaxf(sc, 1e-12f), 1.0f - 1e-12f);
  float bce = -(tb*logf(pc) + (1.f-tb)*logf(1.f-pc));
  float lap = (S5 - sc)*(1.0f/48.0f) - 0.5f*sc;
  float extra = sc*expf(-lap);
  bce = wave_sum(bce); extra = wave_sum(extra);
  int wave = threadIdx.x >> 6, lane = threadIdx.x & 63;
  if (lane == 0){ rbuf[wave][0] = bce; rbuf[wave][1] = extra; }
  __syncthreads();
  if (threadIdx.x == 0){
    int slot = (blockIdx.x + blockIdx.y*(WW/TX) + blockIdx.z*400) & (NSLOT-1);
    atomicAdd(&accs[(1*NSLOT + slot)*8], (double)(rbuf[0][0]+rbuf[1][0]+rbuf[2][0]+rbuf[3][0]));
    atomicAdd(&accs[(2*NSLOT + slot)*8], (double)(rbuf[0][1]+rbuf[1][1]+rbuf[2][1]+rbuf[3][1]));
  }
}

// ---------------- K9a: row sum-of-squares + bf16 convert ----------------
__global__ void k_rownorm_bf16(const float* __restrict__ desc, float* __restrict__ xx,
                               unsigned short* __restrict__ dbf){
  int t = blockIdx.x*blockDim.x + threadIdx.x;
  if (t >= BB*NPTS) return;
  const float* dptr = desc + (size_t)t*DD;
  unsigned short* optr = dbf + (size_t)t*DD;
  float s = 0.f;
  for (int d = 0; d < DD; d += 4){
    float4 v = *(const float4*)(dptr + d);
    s += v.x*v.x + v.y*v.y + v.z*v.z + v.w*v.w;
    unsigned int u0 = __float_as_uint(v.x); optr[d+0] = (unsigned short)((u0 + 0x7fffu + ((u0>>16)&1u)) >> 16);
    unsigned int u1 = __float_as_uint(v.y); optr[d+1] = (unsigned short)((u1 + 0x7fffu + ((u1>>16)&1u)) >> 16);
    unsigned int u2 = __float_as_uint(v.z); optr[d+2] = (unsigned short)((u2 + 0x7fffu + ((u2>>16)&1u)) >> 16);
    unsigned int u3 = __float_as_uint(v.w); optr[d+3] = (unsigned short)((u3 + 0x7fffu + ((u3>>16)&1u)) >> 16);
  }
  xx[t] = s;
}

// ---------------- K9b: project input points (raw proj + vis) ----------------
__global__ void k_proj_points(const float* __restrict__ points, const float* __restrict__ depths,
        const float* __restrict__ poses, const float* __restrict__ Km,
        float* __restrict__ mproj, unsigned char* __restrict__ mvis){
  int t = blockIdx.x*blockDim.x + threadIdx.x;
  if (t >= BB*BB*NPTS) return;
  int i = t / (BB*NPTS); int r = t - i*(BB*NPTS); int j = r / NPTS; int n = r - j*NPTS;
  float ptx = points[((size_t)j*NPTS+n)*2+0];
  float pty = points[((size_t)j*NPTS+n)*2+1];
  Proj pr = project_point(ptx, pty, j, i, depths, poses, Km);
  mproj[(size_t)t*2+0] = (pr.u*2.0f)/(float)(WW-1) - 1.0f;
  mproj[(size_t)t*2+1] = (pr.v*2.0f)/(float)(HH-1) - 1.0f;
  mvis[t] = pr.vis ? 1 : 0;
}

// ---------------- K10: distinction via MFMA (multi-tile blocks) ----------------
__global__ __launch_bounds__(256) void k_distinction_mfma(const unsigned short* __restrict__ dbf,
        const float* __restrict__ xx, double* __restrict__ accs){
  __shared__ float rbuf[4];
  int b = blockIdx.z;
  int mt = blockIdx.x, nh = blockIdx.y;
  int tid = threadIdx.x;
  int wave = tid >> 6, lane = tid & 63;
  int wr = mt*64 + (wave&1)*32;
  int wco = (wave>>1)*32;
  int r = lane & 15, kg = lane >> 4;
  const unsigned short* descb = dbf + (size_t)b*NPTS*DD;
  const float* xb = xx + (size_t)b*NPTS;
  bf16x8 af[4][2];
  #pragma unroll
  for (int ks = 0; ks < 4; ++ks){
    int ko = ks*32 + kg*8;
    af[ks][0] = *(const bf16x8*)(descb + (size_t)(wr+r)*DD + ko);
    af[ks][1] = *(const bf16x8*)(descb + (size_t)(wr+16+r)*DD + ko);
  }
  float mxx[2][4];
  #pragma unroll
  for (int mi = 0; mi < 2; ++mi)
    #pragma unroll
    for (int j = 0; j < 4; ++j)
      mxx[mi][j] = xb[wr + mi*16 + 4*kg + j];
  float local = 0.f;
  for (int nt = nh*8; nt < nh*8+8; ++nt){
    int wc = nt*64 + wco;
    float xn0 = xb[wc + r], xn1 = xb[wc + 16 + r];
    f32x4 c00 = {}, c01 = {}, c10 = {}, c11 = {};
    #pragma unroll
    for (int ks = 0; ks < 4; ++ks){
      int ko = ks*32 + kg*8;
      bf16x8 b0 = *(const bf16x8*)(descb + (size_t)(wc+r)*DD + ko);
      bf16x8 b1 = *(const bf16x8*)(descb + (size_t)(wc+16+r)*DD + ko);
      c00 = __builtin_amdgcn_mfma_f32_16x16x32_bf16(af[ks][0], b0, c00, 0, 0, 0);
      c01 = __builtin_amdgcn_mfma_f32_16x16x32_bf16(af[ks][0], b1, c01, 0, 0, 0);
      c10 = __builtin_amdgcn_mfma_f32_16x16x32_bf16(af[ks][1], b0, c10, 0, 0, 0);
      c11 = __builtin_amdgcn_mfma_f32_16x16x32_bf16(af[ks][1], b1, c11, 0, 0, 0);
    }
    #pragma unroll
    for (int mi = 0; mi < 2; ++mi){
      #pragma unroll
      for (int j = 0; j < 4; ++j){
        float xm = mxx[mi][j];
        float v0 = (mi ? c10[j] : c00[j]);
        float v1 = (mi ? c11[j] : c01[j]);
        local += fmaxf(v0 / sqrtf(fmaxf(xm*xn0, 1e-16f)), 0.f);
        local += fmaxf(v1 / sqrtf(fmaxf(xm*xn1, 1e-16f)), 0.f);
      }
    }
  }
  local = wave_sum(local);
  if (lane == 0) rbuf[wave] = local;
  __syncthreads();
  if (tid == 0){
    int slot = (blockIdx.x + blockIdx.y*16 + blockIdx.z*32) & (NSLOT-1);
    atomicAdd(&accs[(0*NSLOT + slot)*8], (double)(rbuf[0]+rbuf[1]+rbuf[2]+rbuf[3]));
  }
}

// ---------------- K11: match via MFMA (balanced multi-tile blocks) ----------------
__global__ __launch_bounds__(256) void k_match_mfma(const unsigned short* __restrict__ dbf,
        const float* __restrict__ xx, const float* __restrict__ points,
        const float* __restrict__ mproj, const unsigned char* __restrict__ mvis,
        double* __restrict__ accs){
  __shared__ float rbuf[4][4];
  int ab = blockIdx.z; int a = ab / BB, b = ab - a*BB;
  int pairIdx = blockIdx.x;
  int tid = threadIdx.x;
  int wave = tid >> 6, lane = tid & 63;
  int wro = (wave&1)*32, wco = (wave>>1)*32;
  int r = lane & 15, kg = lane >> 4;
  const unsigned short* descA = dbf + (size_t)a*NPTS*DD;
  const unsigned short* descB = dbf + (size_t)b*NPTS*DD;
  const float* xxa = xx + (size_t)a*NPTS;
  const float* xxb = xx + (size_t)b*NPTS;
  const float* pts = points + (size_t)b*NPTS*2;
  const float* mp  = mproj + (((size_t)a*BB+b)*NPTS)*2;
  const unsigned char* mv = mvis + ((size_t)a*BB+b)*NPTS;
  float pos = 0.f, neg = 0.f, pcf = 0.f, ncf = 0.f;
  #pragma unroll
  for (int seg = 0; seg < 2; ++seg){
    int mt = seg ? (15 - pairIdx) : pairIdx;
    int wr = mt*64 + wro;
    bf16x8 af[4][2];
    #pragma unroll
    for (int ks = 0; ks < 4; ++ks){
      int ko = ks*32 + kg*8;
      af[ks][0] = *(const bf16x8*)(descA + (size_t)(wr+r)*DD + ko);
      af[ks][1] = *(const bf16x8*)(descA + (size_t)(wr+16+r)*DD + ko);
    }
    float msx[2][4], msy[2][4], mx2[2][4], mxx[2][4];
    bool  mok[2][4];
    #pragma unroll
    for (int mi = 0; mi < 2; ++mi){
      #pragma unroll
      for (int j = 0; j < 4; ++j){
        int m = wr + mi*16 + 4*kg + j;
        mok[mi][j] = (mv[m] != 0);
        float px = pts[m*2+0], py = pts[m*2+1];
        float sx = ((px+1.f)*(float)(WW-1))*0.5f;
        float sy = ((py+1.f)*(float)(HH-1))*0.5f;
        msx[mi][j] = sx; msy[mi][j] = sy;
        mx2[mi][j] = sx*sx + sy*sy;
        mxx[mi][j] = xxa[m];
      }
    }
    for (int nt = mt; nt < 16; ++nt){
      int wc = nt*64 + wco;
      float nxxv[2], ndx[2], ndy[2], ny2[2];
      #pragma unroll
      for (int ni = 0; ni < 2; ++ni){
        int n = wc + ni*16 + r;
        nxxv[ni] = xxb[n];
        float qx = mp[n*2+0], qy = mp[n*2+1];
        float dx = ((qx+1.f)*(float)(WW-1))*0.5f;
        float dy = ((qy+1.f)*(float)(HH-1))*0.5f;
        ndx[ni] = dx; ndy[ni] = dy;
        ny2[ni] = dx*dx + dy*dy;
      }
      f32x4 c00 = {}, c01 = {}, c10 = {}, c11 = {};
      #pragma unroll
      for (int ks = 0; ks < 4; ++ks){
        int ko = ks*32 + kg*8;
        bf16x8 b0 = *(const bf16x8*)(descB + (size_t)(wc+r)*DD + ko);
        bf16x8 b1 = *(const bf16x8*)(descB + (size_t)(wc+16+r)*DD + ko);
        c00 = __builtin_amdgcn_mfma_f32_16x16x32_bf16(af[ks][0], b0, c00, 0, 0, 0);
        c01 = __builtin_amdgcn_mfma_f32_16x16x32_bf16(af[ks][0], b1, c01, 0, 0, 0);
        c10 = __builtin_amdgcn_mfma_f32_16x16x32_bf16(af[ks][1], b0, c10, 0, 0, 0);
        c11 = __builtin_amdgcn_mfma_f32_16x16x32_bf16(af[ks][1], b1, c11, 0, 0, 0);
      }
      #pragma unroll
      for (int mi = 0; mi < 2; ++mi){
        #pragma unroll
        for (int j = 0; j < 4; ++j){
          if (!mok[mi][j]) continue;
          int m = wr + mi*16 + 4*kg + j;
          float sx = msx[mi][j], sy = msy[mi][j];
          float x2 = mx2[mi][j], xm = mxx[mi][j];
          #pragma unroll
          for (int ni = 0; ni < 2; ++ni){
            int n = wc + ni*16 + r;
            if (m >= n) continue;
            float dv = (mi ? (ni ? c11[j] : c10[j]) : (ni ? c01[j] : c00[j]));
            float d2 = x2 + ny2[ni] - 2.f*(sx*ndx[ni] + sy*ndy[ni]);
            float den = sqrtf(fmaxf(xm * nxxv[ni], 1e-16f));
            float p = dv/den;
            if (d2 <= 1.0f){ pos += p; pcf += 1.f; }
            else           { neg += p; ncf += 1.f; }
          }
        }
      }
    }
  }
  pos = wave_sum(pos); neg = wave_sum(neg);
  pcf = wave_sum(pcf); ncf = wave_sum(ncf);
  if (lane == 0){ rbuf[wave][0] = pos; rbuf[wave][1] = neg; rbuf[wave][2] = pcf; rbuf[wave][3] = ncf; }
  __syncthreads();
  if (tid == 0){
    int slot = (blockIdx.x + blockIdx.z*8) & (NSLOT-1);
    atomicAdd(&accs[(3*NSLOT + slot)*8], (double)(rbuf[0][0]+rbuf[1][0]+rbuf[2][0]+rbuf[3][0]));
    atomicAdd(&accs[(4*NSLOT + slot)*8], (double)(rbuf[0][1]+rbuf[1][1]+rbuf[2][1]+rbuf[3][1]));
    atomicAdd(&accs[(5*NSLOT + slot)*8], (double)(rbuf[0][2]+rbuf[1][2]+rbuf[2][2]+rbuf[3][2]));
    atomicAdd(&accs[(6*NSLOT + slot)*8], (double)(rbuf[0][3]+rbuf[1][3]+rbuf[2][3]+rbuf[3][3]));
  }
}

// ---------------- K12: finalize (64 threads, wave-reduce the slots) ----------------
__global__ void k_final(const double* __restrict__ accs, float* __restrict__ out){
  int lane = threadIdx.x;
  double tot[7];
  #pragma unroll
  for (int q = 0; q < 7; ++q)
    tot[q] = wave_sumd(accs[((size_t)q*NSLOT + lane)*8]);
  if (lane == 0){
    double distinction = tot[0] / (double)((long long)BB*NPTS*NPTS);
    double bce = tot[1] / (double)((long long)BB*HWsz);
    double extra = tot[2] / (double)((long long)BB*HWsz);
    double cornerness = bce + 10.0*extra;
    double pcd = tot[5] < 0.5 ? 1.0 : tot[5];
    double ncd = tot[6] < 0.5 ? 1.0 : tot[6];
    double pos_mean = tot[3] / pcd;
    double neg_mean = tot[4] / ncd;
    double match = 1.0 - pos_mean + neg_mean;
    out[0] = (float)(distinction + 0.5*cornerness + match);
  }
}

extern "C" void kernel_launch(void* const* d_in, const int* in_sizes, int n_in,
                              void* d_out, int out_size, void* d_ws, size_t ws_size,
                              hipStream_t stream) {
  (void)in_sizes; (void)n_in; (void)out_size; (void)ws_size;
  const float* desc   = (const float*)d_in[0];
  const float* points = (const float*)d_in[1];
  const float* scores = (const float*)d_in[2];
  const float* depths = (const float*)d_in[3];
  const float* poses  = (const float*)d_in[4];
  const float* Km     = (const float*)d_in[5];
  const float* imgs   = (const float*)d_in[6];
  float* out = (float*)d_out;

  const size_t S = (size_t)BB*HWsz;
  float* gray = (float*)d_ws;          // S  (later: resp)
  float* bx   = gray + S;              // S  gxx -> keep
  float* by   = bx + S;                // S  gyy -> target
  float* bxy  = by + S;                // S  gxy
  float* resp = gray;                  // reuse
  float* keep = bx;                    // reuse
  // all sub-allocations below are multiples of 16 bytes (dbf needs 16B alignment)
  unsigned long long* ckeys = (unsigned long long*)(bxy + S);      // BB*CAP*8 = 98304
  unsigned int* ccnt = (unsigned int*)(ckeys + (size_t)BB*CAP);    // 8 uints = 32
  double* accs = (double*)(ccnt + 8);                              // 7*64*8 doubles = 28672
  float* cpts  = (float*)(accs + 7*NSLOT*8);                       // BB*NC*2*4 = 24000
  float* cvals = cpts + (size_t)BB*NC*2;                           // 12000
  float* xx    = cvals + (size_t)BB*NC;                            // 24576
  float* mproj = xx + (size_t)BB*NPTS;                             // 294912
  unsigned char* mvis = (unsigned char*)(mproj + (size_t)BB*BB*NPTS*2); // 36864
  unsigned short* dbf = (unsigned short*)(mvis + (size_t)BB*BB*NPTS);   // bf16 desc

  const int npx = BB*HWsz;
  dim3 blk(256);
  dim3 gpx((npx + 255)/256);
  dim3 gtile(WW/TX, HH/TY, BB);

  k_gray<<<gpx, blk, 0, stream>>>(imgs, gray);
  k_sobel<<<gpx, blk, 0, stream>>>(gray, bx, by, bxy);
  k_gauss_resp<<<gtile, blk, 0, stream>>>(bx, by, bxy, resp);

  // zero target (reuses gyy: must be AFTER k_gauss_resp) and ckeys/ccnt/accs region
  hipMemsetAsync(by, 0, S*sizeof(float), stream);
  hipMemsetAsync(ckeys, 0,
      (size_t)BB*CAP*sizeof(unsigned long long) + 8*sizeof(unsigned int) +
      (size_t)7*NSLOT*8*sizeof(double), stream);

  k_nms5<<<gtile, blk, 0, stream>>>(resp, keep);
  {
    int n = BB*NBLK*64;   // one wave per 8x8 block
    k_blockmax_compact<<<dim3((n+255)/256), blk, 0, stream>>>(keep, ckeys, ccnt);
  }
  k_top500<<<dim3(BB), dim3(1024), 0, stream>>>(ckeys, cpts, cvals);
  {
    int n = BB*BB*NC;
    k_corner_scatter<<<dim3((n+255)/256), blk, 0, stream>>>(cpts, cvals, depths, poses, Km,
                                                            (unsigned int*)by);
  }
  k_score_reduce<<<gtile, blk, 0, stream>>>(by, scores, accs);
  {
    int n = BB*NPTS;
    k_rownorm_bf16<<<dim3((n+255)/256), blk, 0, stream>>>(desc, xx, dbf);
  }
  {
    int n = BB*BB*NPTS;
    k_proj_points<<<dim3((n+255)/256), blk, 0, stream>>>(points, depths, poses, Km, mproj, mvis);
  }
  k_distinction_mfma<<<dim3(16, 2, BB), blk, 0, stream>>>(dbf, xx, accs);
  k_match_mfma<<<dim3(8, 1, BB*BB), blk, 0, stream>>>(dbf, xx, points, mproj, mvis, accs);
  k_final<<<dim3(1), dim3(64), 0, stream>>>(accs, out);
}

// Round 10
// 231.682 us; speedup vs baseline: 2.6882x; 1.0292x over previous
//
#include <hip/hip_runtime.h>
#include <stdint.h>

#define BB 6
#define NPTS 1024
#define DD 128
#define HH 320
#define WW 320
#define NC 500
#define HWsz (HH*WW)
#define CAP 2048
#define NBLK ((HH/8)*(WW/8))   // 1600 8x8 blocks per batch
#define TX 32
#define TY 8
#define NSLOT 64
// slot accumulators: 7 quantities x 64 slots, each slot on its own 64B line
// q: 0=distinction 1=bce 2=extra 3=pos 4=neg 5=pcnt 6=ncnt

typedef __attribute__((ext_vector_type(8))) short bf16x8;
typedef __attribute__((ext_vector_type(4))) float f32x4;

__device__ __forceinline__ int clampi(int v, int lo, int hi){ return v<lo?lo:(v>hi?hi:v); }
__device__ __forceinline__ int refl(int p, int L){ if(p<0)p=-p; if(p>=L)p=2*L-2-p; return p; }

__device__ __forceinline__ float wave_sum(float v){
  #pragma unroll
  for (int o = 32; o > 0; o >>= 1) v += __shfl_xor(v, o, 64);
  return v;
}
__device__ __forceinline__ double wave_sumd(double v){
  #pragma unroll
  for (int o = 32; o > 0; o >>= 1) v += __shfl_xor(v, o, 64);
  return v;
}
__device__ __forceinline__ float wave_max(float v){
  #pragma unroll
  for (int o = 32; o > 0; o >>= 1) v = fmaxf(v, __shfl_xor(v, o, 64));
  return v;
}

__device__ __constant__ float GW[7] = {
  0.0044330481f, 0.0540055850f, 0.2420362300f, 0.3990502700f,
  0.2420362300f, 0.0540055850f, 0.0044330481f };

// ---------------- projection (matches pairwise_project) ----------------
struct Proj { float u, v; int vis; };

__device__ Proj project_point(float ptx, float pty, int jsrc, int itgt,
                              const float* __restrict__ depths,
                              const float* __restrict__ poses,
                              const float* __restrict__ Km)
{
  float pxx = ((ptx + 1.0f)*(float)(WW-1))*0.5f;
  float pxy = ((pty + 1.0f)*(float)(HH-1))*0.5f;
  float rx = rintf(pxx), ry = rintf(pxy);
  rx = fminf(fmaxf(rx, 0.f), (float)(WW-1));
  ry = fminf(fmaxf(ry, 0.f), (float)(HH-1));
  int xi = (int)rx, yi = (int)ry;
  float d = depths[(size_t)jsrc*HWsz + yi*WW + xi];
  float a00=Km[0],a01=Km[1],a02=Km[2],a10=Km[3],a11=Km[4],a12=Km[5],a20=Km[6],a21=Km[7],a22=Km[8];
  float det = a00*(a11*a22 - a12*a21) - a01*(a10*a22 - a12*a20) + a02*(a10*a21 - a11*a20);
  float id_ = 1.0f/det;
  float i00 = (a11*a22 - a12*a21)*id_;
  float i01 = (a02*a21 - a01*a22)*id_;
  float i02 = (a01*a12 - a02*a11)*id_;
  float i10 = (a12*a20 - a10*a22)*id_;
  float i11 = (a00*a22 - a02*a20)*id_;
  float i12 = (a02*a10 - a00*a12)*id_;
  float i20 = (a10*a21 - a11*a20)*id_;
  float i21 = (a01*a20 - a00*a21)*id_;
  float i22 = (a00*a11 - a01*a10)*id_;
  float c0 = (i00*pxx + i01*pxy + i02)*d;
  float c1 = (i10*pxx + i11*pxy + i12)*d;
  float c2 = (i20*pxx + i21*pxy + i22)*d;
  const float* Pj = poses + (size_t)jsrc*16;
  float w0 = Pj[0]*c0 + Pj[1]*c1 + Pj[2]*c2  + Pj[3];
  float w1 = Pj[4]*c0 + Pj[5]*c1 + Pj[6]*c2  + Pj[7];
  float w2 = Pj[8]*c0 + Pj[9]*c1 + Pj[10]*c2 + Pj[11];
  const float* Pi = poses + (size_t)itgt*16;
  float dx = w0 - Pi[3], dy = w1 - Pi[7], dz = w2 - Pi[11];
  float e0 = Pi[0]*dx + Pi[4]*dy + Pi[8]*dz;
  float e1 = Pi[1]*dx + Pi[5]*dy + Pi[9]*dz;
  float e2 = Pi[2]*dx + Pi[6]*dy + Pi[10]*dz;
  float uu = a00*e0 + a01*e1 + a02*e2;
  float vv = a10*e0 + a11*e1 + a12*e2;
  float zz = a20*e0 + a21*e1 + a22*e2;
  float zs = (fabsf(zz) > 1e-6f) ? zz : 1e-6f;
  Proj r;
  r.u = uu/zs; r.v = vv/zs;
  r.vis = (zz > 0.1f) && (r.u >= 0.f) && (r.u <= (float)(WW-1)) && (r.v >= 0.f) && (r.v <= (float)(HH-1));
  return r;
}

// ---------------- K1: gray ----------------
__global__ void k_gray(const float* __restrict__ imgs, float* __restrict__ gray){
  int t = blockIdx.x*blockDim.x + threadIdx.x;
  if (t >= BB*HWsz) return;
  int b = t / HWsz, p = t - b*HWsz;
  const float* base = imgs + (size_t)b*3*HWsz;
  gray[t] = 0.299f*base[p] + 0.587f*base[HWsz+p] + 0.114f*base[2*HWsz+p];
}

// ---------------- K2: sobel (edge pad) + products ----------------
__global__ void k_sobel(const float* __restrict__ gray, float* __restrict__ gxx,
                        float* __restrict__ gyy, float* __restrict__ gxy){
  int t = blockIdx.x*blockDim.x + threadIdx.x;
  if (t >= BB*HWsz) return;
  int b = t / HWsz, p = t - b*HWsz;
  int y = p / WW, x = p - y*WW;
  const float* g = gray + (size_t)b*HWsz;
  int ym = clampi(y-1,0,HH-1), yp = clampi(y+1,0,HH-1);
  int xm = clampi(x-1,0,WW-1), xp = clampi(x+1,0,WW-1);
  float g00 = g[ym*WW+xm], g01 = g[ym*WW+x], g02 = g[ym*WW+xp];
  float g10 = g[y*WW+xm],                    g12 = g[y*WW+xp];
  float g20 = g[yp*WW+xm], g21 = g[yp*WW+x], g22 = g[yp*WW+xp];
  float gx = 0.125f*(g02-g00) + 0.25f*(g12-g10) + 0.125f*(g22-g20);
  float gy = 0.125f*(g20-g00) + 0.25f*(g21-g01) + 0.125f*(g22-g02);
  gxx[t] = gx*gx; gyy[t] = gy*gy; gxy[t] = gx*gy;
}

// ---------------- K3: gaussian 7x7 (reflect) + GFTT response, LDS-tiled ----------------
__global__ __launch_bounds__(256) void k_gauss_resp(const float* __restrict__ gxx,
        const float* __restrict__ gyy, const float* __restrict__ gxy, float* __restrict__ resp){
  __shared__ float lxx[TY+6][TX+6], lyy[TY+6][TX+6], lxy[TY+6][TX+6];
  int b = blockIdx.z;
  int x0 = blockIdx.x*TX, y0 = blockIdx.y*TY;
  const float* axx = gxx + (size_t)b*HWsz;
  const float* ayy = gyy + (size_t)b*HWsz;
  const float* axy = gxy + (size_t)b*HWsz;
  const int W2 = TX+6, H2 = TY+6;
  for (int i = threadIdx.x; i < H2*W2; i += 256){
    int ly = i / W2, lx = i - ly*W2;
    int gy = refl(y0 - 3 + ly, HH), gx = refl(x0 - 3 + lx, WW);
    size_t off = (size_t)gy*WW + gx;
    lxx[ly][lx] = axx[off]; lyy[ly][lx] = ayy[off]; lxy[ly][lx] = axy[off];
  }
  __syncthreads();
  int tx = threadIdx.x & (TX-1), ty = threadIdx.x / TX;
  float sxx=0.f, syy=0.f, sxy=0.f;
  #pragma unroll
  for (int i=0;i<7;++i){
    float wr = GW[i];
    #pragma unroll
    for (int j=0;j<7;++j){
      float wc = wr*GW[j];
      sxx += wc*lxx[ty+i][tx+j];
      syy += wc*lyy[ty+i][tx+j];
      sxy += wc*lxy[ty+i][tx+j];
    }
  }
  float tr = sxx+syy, df = sxx-syy;
  float disc = sqrtf(fmaxf(df*df + 4.f*sxy*sxy, 0.f));
  resp[(size_t)b*HWsz + (size_t)(y0+ty)*WW + (x0+tx)] = 0.5f*(tr - disc);
}

// ---------------- K4: 5x5 NMS (pad -inf), LDS-tiled ----------------
__global__ __launch_bounds__(256) void k_nms5(const float* __restrict__ resp, float* __restrict__ keep){
  __shared__ float lr[TY+4][TX+4];
  int b = blockIdx.z;
  int x0 = blockIdx.x*TX, y0 = blockIdx.y*TY;
  const float* rb = resp + (size_t)b*HWsz;
  const int W2 = TX+4, H2 = TY+4;
  for (int i = threadIdx.x; i < H2*W2; i += 256){
    int ly = i / W2, lx = i - ly*W2;
    int gy = y0 - 2 + ly, gx = x0 - 2 + lx;
    lr[ly][lx] = (gy >= 0 && gy < HH && gx >= 0 && gx < WW) ? rb[(size_t)gy*WW + gx] : -1e30f;
  }
  __syncthreads();
  int tx = threadIdx.x & (TX-1), ty = threadIdx.x / TX;
  float m = -1e30f;
  #pragma unroll
  for (int dy=0; dy<5; ++dy)
    #pragma unroll
    for (int dx=0; dx<5; ++dx) m = fmaxf(m, lr[ty+dy][tx+dx]);
  float r = lr[ty+2][tx+2];
  keep[(size_t)b*HWsz + (size_t)(y0+ty)*WW + (x0+tx)] = (r == m) ? r : 0.f;
}

// ---------------- K5: 8x8 block max, deterministic slot per block ----------------
__global__ void k_blockmax_compact(const float* __restrict__ keep,
        unsigned long long* __restrict__ ckeys, unsigned int* __restrict__ ccnt){
  int gw = (blockIdx.x*(int)blockDim.x + (int)threadIdx.x) >> 6;
  int lane = threadIdx.x & 63;
  if (gw >= BB*NBLK) return;
  int b = gw / NBLK; int r = gw - b*NBLK;
  int by = r / (WW/8), bx = r - by*(WW/8);
  int yy = by*8 + (lane >> 3), xx2 = bx*8 + (lane & 7);
  float v = keep[(size_t)b*HWsz + (size_t)yy*WW + xx2];
  float bm = wave_max(v);
  if (!(bm > 0.f)) return;
  unsigned long long mask = __ballot(v == bm);
  if (v == bm){
    unsigned long long key =
      ((unsigned long long)__float_as_uint(bm) << 32) |
      (unsigned long long)(0xFFFFFFFFu - (unsigned int)(yy*WW + xx2));
    int rank = __popcll(mask & ((1ull << lane) - 1ull));
    if (rank == 0){
      ckeys[(size_t)b*CAP + r] = key;               // fixed slot, no atomic
    } else {
      unsigned int slot = NBLK + atomicAdd(&ccnt[b], 1u);  // ties only (~never)
      if (slot < CAP) ckeys[(size_t)b*CAP + slot] = key;
    }
  }
}

// ---------------- K6: bitonic top-500 per batch ----------------
__global__ __launch_bounds__(1024) void k_top500(const unsigned long long* __restrict__ ckeys,
        float* __restrict__ cpts, float* __restrict__ cvals){
  __shared__ unsigned long long sk[CAP];
  int b = blockIdx.x;
  int tid = threadIdx.x;
  for (int i = tid; i < CAP; i += 1024)
    sk[i] = ckeys[(size_t)b*CAP + i];
  __syncthreads();
  for (int k = 2; k <= CAP; k <<= 1){
    for (int j = k >> 1; j > 0; j >>= 1){
      for (int i = tid; i < CAP; i += 1024){
        int l = i ^ j;
        if (l > i){
          unsigned long long A = sk[i], Bv = sk[l];
          bool up = ((i & k) == 0);
          if ((A > Bv) == up){ sk[i] = Bv; sk[l] = A; }
        }
      }
      __syncthreads();
    }
  }
  if (tid < NC){
    unsigned long long key = sk[CAP-1-tid];
    float val = __uint_as_float((unsigned int)(key >> 32));
    size_t o = (size_t)b*NC + tid;
    if (val > 0.f){
      unsigned int idx = 0xFFFFFFFFu - (unsigned int)(key & 0xFFFFFFFFull);
      float fx = (float)(idx % WW), fy = (float)(idx / WW);
      cpts[o*2+0] = (fx*2.0f)/(float)(WW-1) - 1.0f;
      cpts[o*2+1] = (fy*2.0f)/(float)(HH-1) - 1.0f;
      cvals[o] = val;
    } else {
      cpts[o*2+0] = __int_as_float(0x7fc00000);
      cpts[o*2+1] = __int_as_float(0x7fc00000);
      cvals[o] = 0.f;
    }
  }
}

// ---------------- K7: corner projection + scatter-max ----------------
__global__ void k_corner_scatter(const float* __restrict__ cpts, const float* __restrict__ cvals,
        const float* __restrict__ depths, const float* __restrict__ poses,
        const float* __restrict__ Km, unsigned int* __restrict__ target){
  int t = blockIdx.x*blockDim.x + threadIdx.x;
  if (t >= BB*BB*NC) return;
  int i = t / (BB*NC); int r = t - i*(BB*NC); int j = r / NC; int n = r - j*NC;
  float val = cvals[(size_t)i*NC + n];
  float ptx = cpts[((size_t)j*NC+n)*2+0];
  float pty = cpts[((size_t)j*NC+n)*2+1];
  if (!(val > 0.f) || ptx != ptx) return;
  Proj pr = project_point(ptx, pty, j, i, depths, poses, Km);
  if (!pr.vis) return;
  float nu = (pr.u*2.0f)/(float)(WW-1) - 1.0f;
  float nv = (pr.v*2.0f)/(float)(HH-1) - 1.0f;
  float px2 = ((nu+1.0f)*(float)(WW-1))*0.5f;
  float py2 = ((nv+1.0f)*(float)(HH-1))*0.5f;
  float rx = rintf(px2), ry = rintf(py2);
  if (!(rx >= 0.f && ry >= 0.f && rx <= (float)(WW-1) && ry <= (float)(HH-1))) return;
  int wf = (int)rx, hf = (int)ry;
  atomicMax(&target[(size_t)j*HWsz + hf*WW + wf], __float_as_uint(val));
}

// ---------------- K8: target NMS + BCE + laplacian, LDS-tiled + slot atomics ----------------
__global__ __launch_bounds__(256) void k_score_reduce(const float* __restrict__ target,
        const float* __restrict__ scores, double* __restrict__ accs){
  __shared__ float ltg[TY+4][TX+4], lsc[TY+4][TX+4];
  __shared__ float rbuf[4][2];
  int b = blockIdx.z;
  int x0 = blockIdx.x*TX, y0 = blockIdx.y*TY;
  const float* tg = target + (size_t)b*HWsz;
  const float* sb = scores + (size_t)b*HWsz;
  const int W2 = TX+4, H2 = TY+4;
  for (int i = threadIdx.x; i < H2*W2; i += 256){
    int ly = i / W2, lx = i - ly*W2;
    int gy = y0 - 2 + ly, gx = x0 - 2 + lx;
    ltg[ly][lx] = (gy >= 0 && gy < HH && gx >= 0 && gx < WW) ? tg[(size_t)gy*WW + gx] : -1e30f;
    lsc[ly][lx] = sb[(size_t)refl(gy,HH)*WW + refl(gx,WW)];
  }
  __syncthreads();
  int tx = threadIdx.x & (TX-1), ty = threadIdx.x / TX;
  float m = -1e30f, S5 = 0.f;
  #pragma unroll
  for (int dy=0; dy<5; ++dy)
    #pragma unroll
    for (int dx=0; dx<5; ++dx){
      m = fmaxf(m, ltg[ty+dy][tx+dx]);
      S5 += lsc[ty+dy][tx+dx];
    }
  float tv = ltg[ty+2][tx+2];
  float sc = lsc[ty+2][tx+2];
  float tb = (tv > 0.f && tv == m) ? 1.f : 0.f;
  float pc = fminf(fmaxf(sc, 1e-12f), 1.0f - 1e-12f);
  float bce = -(tb*logf(pc) + (1.f-tb)*logf(1.f-pc));
  float lap = (S5 - sc)*(1.0f/48.0f) - 0.5f*sc;
  float extra = sc*expf(-lap);
  bce = wave_sum(bce); extra = wave_sum(extra);
  int wave = threadIdx.x >> 6, lane = threadIdx.x & 63;
  if (lane == 0){ rbuf[wave][0] = bce; rbuf[wave][1] = extra; }
  __syncthreads();
  if (threadIdx.x == 0){
    int slot = (blockIdx.x + blockIdx.y*(WW/TX) + blockIdx.z*400) & (NSLOT-1);
    atomicAdd(&accs[(1*NSLOT + slot)*8], (double)(rbuf[0][0]+rbuf[1][0]+rbuf[2][0]+rbuf[3][0]));
    atomicAdd(&accs[(2*NSLOT + slot)*8], (double)(rbuf[0][1]+rbuf[1][1]+rbuf[2][1]+rbuf[3][1]));
  }
}

// ---------------- K9a: row sum-of-squares + bf16 convert ----------------
__global__ void k_rownorm_bf16(const float* __restrict__ desc, float* __restrict__ xx,
                               unsigned short* __restrict__ dbf){
  int t = blockIdx.x*blockDim.x + threadIdx.x;
  if (t >= BB*NPTS) return;
  const float* dptr = desc + (size_t)t*DD;
  unsigned short* optr = dbf + (size_t)t*DD;
  float s = 0.f;
  for (int d = 0; d < DD; d += 4){
    float4 v = *(const float4*)(dptr + d);
    s += v.x*v.x + v.y*v.y + v.z*v.z + v.w*v.w;
    unsigned int u0 = __float_as_uint(v.x); optr[d+0] = (unsigned short)((u0 + 0x7fffu + ((u0>>16)&1u)) >> 16);
    unsigned int u1 = __float_as_uint(v.y); optr[d+1] = (unsigned short)((u1 + 0x7fffu + ((u1>>16)&1u)) >> 16);
    unsigned int u2 = __float_as_uint(v.z); optr[d+2] = (unsigned short)((u2 + 0x7fffu + ((u2>>16)&1u)) >> 16);
    unsigned int u3 = __float_as_uint(v.w); optr[d+3] = (unsigned short)((u3 + 0x7fffu + ((u3>>16)&1u)) >> 16);
  }
  xx[t] = s;
}

// ---------------- K9b: project input points (raw proj + vis) ----------------
__global__ void k_proj_points(const float* __restrict__ points, const float* __restrict__ depths,
        const float* __restrict__ poses, const float* __restrict__ Km,
        float* __restrict__ mproj, unsigned char* __restrict__ mvis){
  int t = blockIdx.x*blockDim.x + threadIdx.x;
  if (t >= BB*BB*NPTS) return;
  int i = t / (BB*NPTS); int r = t - i*(BB*NPTS); int j = r / NPTS; int n = r - j*NPTS;
  float ptx = points[((size_t)j*NPTS+n)*2+0];
  float pty = points[((size_t)j*NPTS+n)*2+1];
  Proj pr = project_point(ptx, pty, j, i, depths, poses, Km);
  mproj[(size_t)t*2+0] = (pr.u*2.0f)/(float)(WW-1) - 1.0f;
  mproj[(size_t)t*2+1] = (pr.v*2.0f)/(float)(HH-1) - 1.0f;
  mvis[t] = pr.vis ? 1 : 0;
}

// ---------------- K10: distinction via MFMA, ONE 64x64 tile per block ----------------
// grid (16 mt, 16 nt, BB)
__global__ __launch_bounds__(256) void k_distinction_mfma(const unsigned short* __restrict__ dbf,
        const float* __restrict__ xx, double* __restrict__ accs){
  __shared__ float rbuf[4];
  int b = blockIdx.z;
  int tid = threadIdx.x;
  int wave = tid >> 6, lane = tid & 63;
  int wr = blockIdx.x*64 + (wave&1)*32;
  int wc = blockIdx.y*64 + (wave>>1)*32;
  int r = lane & 15, kg = lane >> 4;
  const unsigned short* descb = dbf + (size_t)b*NPTS*DD;
  const float* xb = xx + (size_t)b*NPTS;
  f32x4 c00 = {}, c01 = {}, c10 = {}, c11 = {};
  #pragma unroll
  for (int ks = 0; ks < 4; ++ks){
    int ko = ks*32 + kg*8;
    bf16x8 a0 = *(const bf16x8*)(descb + (size_t)(wr+r)*DD + ko);
    bf16x8 a1 = *(const bf16x8*)(descb + (size_t)(wr+16+r)*DD + ko);
    bf16x8 b0 = *(const bf16x8*)(descb + (size_t)(wc+r)*DD + ko);
    bf16x8 b1 = *(const bf16x8*)(descb + (size_t)(wc+16+r)*DD + ko);
    c00 = __builtin_amdgcn_mfma_f32_16x16x32_bf16(a0, b0, c00, 0, 0, 0);
    c01 = __builtin_amdgcn_mfma_f32_16x16x32_bf16(a0, b1, c01, 0, 0, 0);
    c10 = __builtin_amdgcn_mfma_f32_16x16x32_bf16(a1, b0, c10, 0, 0, 0);
    c11 = __builtin_amdgcn_mfma_f32_16x16x32_bf16(a1, b1, c11, 0, 0, 0);
  }
  float xn0 = xb[wc + r], xn1 = xb[wc + 16 + r];
  float local = 0.f;
  #pragma unroll
  for (int mi = 0; mi < 2; ++mi){
    #pragma unroll
    for (int j = 0; j < 4; ++j){
      float xm = xb[wr + mi*16 + 4*kg + j];
      float v0 = (mi ? c10[j] : c00[j]);
      float v1 = (mi ? c11[j] : c01[j]);
      local += fmaxf(v0 / sqrtf(fmaxf(xm*xn0, 1e-16f)), 0.f);
      local += fmaxf(v1 / sqrtf(fmaxf(xm*xn1, 1e-16f)), 0.f);
    }
  }
  local = wave_sum(local);
  if (lane == 0) rbuf[wave] = local;
  __syncthreads();
  if (tid == 0){
    int slot = (blockIdx.x + blockIdx.y*16 + blockIdx.z*32) & (NSLOT-1);
    atomicAdd(&accs[(0*NSLOT + slot)*8], (double)(rbuf[0]+rbuf[1]+rbuf[2]+rbuf[3]));
  }
}

// ---------------- K11: match via MFMA, ONE 64x64 tile per block ----------------
// grid (136 triangular tiles, 1, 36): ti -> (mt, nt) with nt >= mt
__global__ __launch_bounds__(256) void k_match_mfma(const unsigned short* __restrict__ dbf,
        const float* __restrict__ xx, const float* __restrict__ points,
        const float* __restrict__ mproj, const unsigned char* __restrict__ mvis,
        double* __restrict__ accs){
  __shared__ float rbuf[4][4];
  int ab = blockIdx.z; int a = ab / BB, b = ab - a*BB;
  int ti = blockIdx.x;
  int mt = 0;
  while (ti >= 16 - mt){ ti -= 16 - mt; ++mt; }
  int nt = mt + ti;
  int tid = threadIdx.x;
  int wave = tid >> 6, lane = tid & 63;
  int wr = mt*64 + (wave&1)*32;
  int wc = nt*64 + (wave>>1)*32;
  int r = lane & 15, kg = lane >> 4;
  const unsigned short* descA = dbf + (size_t)a*NPTS*DD;
  const unsigned short* descB = dbf + (size_t)b*NPTS*DD;
  const float* xxa = xx + (size_t)a*NPTS;
  const float* xxb = xx + (size_t)b*NPTS;
  const float* pts = points + (size_t)b*NPTS*2;
  const float* mp  = mproj + (((size_t)a*BB+b)*NPTS)*2;
  const unsigned char* mv = mvis + ((size_t)a*BB+b)*NPTS;
  f32x4 c00 = {}, c01 = {}, c10 = {}, c11 = {};
  #pragma unroll
  for (int ks = 0; ks < 4; ++ks){
    int ko = ks*32 + kg*8;
    bf16x8 a0 = *(const bf16x8*)(descA + (size_t)(wr+r)*DD + ko);
    bf16x8 a1 = *(const bf16x8*)(descA + (size_t)(wr+16+r)*DD + ko);
    bf16x8 b0 = *(const bf16x8*)(descB + (size_t)(wc+r)*DD + ko);
    bf16x8 b1 = *(const bf16x8*)(descB + (size_t)(wc+16+r)*DD + ko);
    c00 = __builtin_amdgcn_mfma_f32_16x16x32_bf16(a0, b0, c00, 0, 0, 0);
    c01 = __builtin_amdgcn_mfma_f32_16x16x32_bf16(a0, b1, c01, 0, 0, 0);
    c10 = __builtin_amdgcn_mfma_f32_16x16x32_bf16(a1, b0, c10, 0, 0, 0);
    c11 = __builtin_amdgcn_mfma_f32_16x16x32_bf16(a1, b1, c11, 0, 0, 0);
  }
  // n-side per-lane data (2 cols)
  float nxxv[2], ndx[2], ndy[2], ny2[2];
  #pragma unroll
  for (int ni = 0; ni < 2; ++ni){
    int n = wc + ni*16 + r;
    nxxv[ni] = xxb[n];
    float qx = mp[n*2+0], qy = mp[n*2+1];
    float dx = ((qx+1.f)*(float)(WW-1))*0.5f;
    float dy = ((qy+1.f)*(float)(HH-1))*0.5f;
    ndx[ni] = dx; ndy[ni] = dy;
    ny2[ni] = dx*dx + dy*dy;
  }
  float pos = 0.f, neg = 0.f, pcf = 0.f, ncf = 0.f;
  #pragma unroll
  for (int mi = 0; mi < 2; ++mi){
    #pragma unroll
    for (int j = 0; j < 4; ++j){
      int m = wr + mi*16 + 4*kg + j;
      if (!mv[m]) continue;
      float px = pts[m*2+0], py = pts[m*2+1];
      float sx = ((px+1.f)*(float)(WW-1))*0.5f;
      float sy = ((py+1.f)*(float)(HH-1))*0.5f;
      float x2 = sx*sx + sy*sy;
      float xm = xxa[m];
      #pragma unroll
      for (int ni = 0; ni < 2; ++ni){
        int n = wc + ni*16 + r;
        if (m >= n) continue;
        float dv = (mi ? (ni ? c11[j] : c10[j]) : (ni ? c01[j] : c00[j]));
        float d2 = x2 + ny2[ni] - 2.f*(sx*ndx[ni] + sy*ndy[ni]);
        float den = sqrtf(fmaxf(xm * nxxv[ni], 1e-16f));
        float p = dv/den;
        if (d2 <= 1.0f){ pos += p; pcf += 1.f; }
        else           { neg += p; ncf += 1.f; }
      }
    }
  }
  pos = wave_sum(pos); neg = wave_sum(neg);
  pcf = wave_sum(pcf); ncf = wave_sum(ncf);
  if (lane == 0){ rbuf[wave][0] = pos; rbuf[wave][1] = neg; rbuf[wave][2] = pcf; rbuf[wave][3] = ncf; }
  __syncthreads();
  if (tid == 0){
    int slot = (blockIdx.x + blockIdx.z*8) & (NSLOT-1);
    atomicAdd(&accs[(3*NSLOT + slot)*8], (double)(rbuf[0][0]+rbuf[1][0]+rbuf[2][0]+rbuf[3][0]));
    atomicAdd(&accs[(4*NSLOT + slot)*8], (double)(rbuf[0][1]+rbuf[1][1]+rbuf[2][1]+rbuf[3][1]));
    atomicAdd(&accs[(5*NSLOT + slot)*8], (double)(rbuf[0][2]+rbuf[1][2]+rbuf[2][2]+rbuf[3][2]));
    atomicAdd(&accs[(6*NSLOT + slot)*8], (double)(rbuf[0][3]+rbuf[1][3]+rbuf[2][3]+rbuf[3][3]));
  }
}

// ---------------- K12: finalize (64 threads, wave-reduce the slots) ----------------
__global__ void k_final(const double* __restrict__ accs, float* __restrict__ out){
  int lane = threadIdx.x;
  double tot[7];
  #pragma unroll
  for (int q = 0; q < 7; ++q)
    tot[q] = wave_sumd(accs[((size_t)q*NSLOT + lane)*8]);
  if (lane == 0){
    double distinction = tot[0] / (double)((long long)BB*NPTS*NPTS);
    double bce = tot[1] / (double)((long long)BB*HWsz);
    double extra = tot[2] / (double)((long long)BB*HWsz);
    double cornerness = bce + 10.0*extra;
    double pcd = tot[5] < 0.5 ? 1.0 : tot[5];
    double ncd = tot[6] < 0.5 ? 1.0 : tot[6];
    double pos_mean = tot[3] / pcd;
    double neg_mean = tot[4] / ncd;
    double match = 1.0 - pos_mean + neg_mean;
    out[0] = (float)(distinction + 0.5*cornerness + match);
  }
}

extern "C" void kernel_launch(void* const* d_in, const int* in_sizes, int n_in,
                              void* d_out, int out_size, void* d_ws, size_t ws_size,
                              hipStream_t stream) {
  (void)in_sizes; (void)n_in; (void)out_size; (void)ws_size;
  const float* desc   = (const float*)d_in[0];
  const float* points = (const float*)d_in[1];
  const float* scores = (const float*)d_in[2];
  const float* depths = (const float*)d_in[3];
  const float* poses  = (const float*)d_in[4];
  const float* Km     = (const float*)d_in[5];
  const float* imgs   = (const float*)d_in[6];
  float* out = (float*)d_out;

  const size_t S = (size_t)BB*HWsz;
  float* gray = (float*)d_ws;          // S  (later: resp)
  float* bx   = gray + S;              // S  gxx -> keep
  float* by   = bx + S;                // S  gyy -> target
  float* bxy  = by + S;                // S  gxy
  float* resp = gray;                  // reuse
  float* keep = bx;                    // reuse
  unsigned long long* ckeys = (unsigned long long*)(bxy + S);      // BB*CAP*8
  unsigned int* ccnt = (unsigned int*)(ckeys + (size_t)BB*CAP);    // 8 uints
  double* accs = (double*)(ccnt + 8);                              // 7*64*8 doubles
  float* cpts  = (float*)(accs + 7*NSLOT*8);                       // BB*NC*2
  float* cvals = cpts + (size_t)BB*NC*2;                           // BB*NC
  float* xx    = cvals + (size_t)BB*NC;                            // BB*NPTS
  float* mproj = xx + (size_t)BB*NPTS;                             // BB*BB*NPTS*2
  unsigned char* mvis = (unsigned char*)(mproj + (size_t)BB*BB*NPTS*2); // BB*BB*NPTS
  unsigned short* dbf = (unsigned short*)(mvis + (size_t)BB*BB*NPTS);   // bf16 desc

  const int npx = BB*HWsz;
  dim3 blk(256);
  dim3 gpx((npx + 255)/256);
  dim3 gtile(WW/TX, HH/TY, BB);

  k_gray<<<gpx, blk, 0, stream>>>(imgs, gray);
  k_sobel<<<gpx, blk, 0, stream>>>(gray, bx, by, bxy);
  k_gauss_resp<<<gtile, blk, 0, stream>>>(bx, by, bxy, resp);

  // zero target (reuses gyy: must be AFTER k_gauss_resp) and ckeys/ccnt/accs region
  hipMemsetAsync(by, 0, S*sizeof(float), stream);
  hipMemsetAsync(ckeys, 0,
      (size_t)BB*CAP*sizeof(unsigned long long) + 8*sizeof(unsigned int) +
      (size_t)7*NSLOT*8*sizeof(double), stream);

  k_nms5<<<gtile, blk, 0, stream>>>(resp, keep);
  {
    int n = BB*NBLK*64;   // one wave per 8x8 block
    k_blockmax_compact<<<dim3((n+255)/256), blk, 0, stream>>>(keep, ckeys, ccnt);
  }
  k_top500<<<dim3(BB), dim3(1024), 0, stream>>>(ckeys, cpts, cvals);
  {
    int n = BB*BB*NC;
    k_corner_scatter<<<dim3((n+255)/256), blk, 0, stream>>>(cpts, cvals, depths, poses, Km,
                                                            (unsigned int*)by);
  }
  k_score_reduce<<<gtile, blk, 0, stream>>>(by, scores, accs);
  {
    int n = BB*NPTS;
    k_rownorm_bf16<<<dim3((n+255)/256), blk, 0, stream>>>(desc, xx, dbf);
  }
  {
    int n = BB*BB*NPTS;
    k_proj_points<<<dim3((n+255)/256), blk, 0, stream>>>(points, depths, poses, Km, mproj, mvis);
  }
  k_distinction_mfma<<<dim3(16, 16, BB), blk, 0, stream>>>(dbf, xx, accs);
  k_match_mfma<<<dim3(136, 1, BB*BB), blk, 0, stream>>>(dbf, xx, points, mproj, mvis, accs);
  k_final<<<dim3(1), dim3(64), 0, stream>>>(accs, out);
}

// Round 11
// 215.304 us; speedup vs baseline: 2.8927x; 1.0761x over previous
//
#include <hip/hip_runtime.h>
#include <stdint.h>

#define BB 6
#define NPTS 1024
#define DD 128
#define HH 320
#define WW 320
#define NC 500
#define HWsz (HH*WW)
#define CAP 2048
#define NBLK ((HH/8)*(WW/8))   // 1600 8x8 blocks per batch
#define TX 32
#define TY 8
#define NSLOT 64
// slot accumulators: 7 quantities x 64 slots, each slot on its own 64B line
// q: 0=distinction 1=bce 2=extra 3=pos 4=neg 5=pcnt 6=ncnt

typedef __attribute__((ext_vector_type(8))) short bf16x8;
typedef __attribute__((ext_vector_type(4))) float f32x4;

__device__ __forceinline__ int clampi(int v, int lo, int hi){ return v<lo?lo:(v>hi?hi:v); }
__device__ __forceinline__ int refl(int p, int L){ if(p<0)p=-p; if(p>=L)p=2*L-2-p; return p; }

__device__ __forceinline__ float wave_sum(float v){
  #pragma unroll
  for (int o = 32; o > 0; o >>= 1) v += __shfl_xor(v, o, 64);
  return v;
}
__device__ __forceinline__ double wave_sumd(double v){
  #pragma unroll
  for (int o = 32; o > 0; o >>= 1) v += __shfl_xor(v, o, 64);
  return v;
}
__device__ __forceinline__ float wave_max(float v){
  #pragma unroll
  for (int o = 32; o > 0; o >>= 1) v = fmaxf(v, __shfl_xor(v, o, 64));
  return v;
}

__device__ __constant__ float GW[7] = {
  0.0044330481f, 0.0540055850f, 0.2420362300f, 0.3990502700f,
  0.2420362300f, 0.0540055850f, 0.0044330481f };

// ---------------- projection (matches pairwise_project) ----------------
struct Proj { float u, v; int vis; };

__device__ Proj project_point(float ptx, float pty, int jsrc, int itgt,
                              const float* __restrict__ depths,
                              const float* __restrict__ poses,
                              const float* __restrict__ Km)
{
  float pxx = ((ptx + 1.0f)*(float)(WW-1))*0.5f;
  float pxy = ((pty + 1.0f)*(float)(HH-1))*0.5f;
  float rx = rintf(pxx), ry = rintf(pxy);
  rx = fminf(fmaxf(rx, 0.f), (float)(WW-1));
  ry = fminf(fmaxf(ry, 0.f), (float)(HH-1));
  int xi = (int)rx, yi = (int)ry;
  float d = depths[(size_t)jsrc*HWsz + yi*WW + xi];
  float a00=Km[0],a01=Km[1],a02=Km[2],a10=Km[3],a11=Km[4],a12=Km[5],a20=Km[6],a21=Km[7],a22=Km[8];
  float det = a00*(a11*a22 - a12*a21) - a01*(a10*a22 - a12*a20) + a02*(a10*a21 - a11*a20);
  float id_ = 1.0f/det;
  float i00 = (a11*a22 - a12*a21)*id_;
  float i01 = (a02*a21 - a01*a22)*id_;
  float i02 = (a01*a12 - a02*a11)*id_;
  float i10 = (a12*a20 - a10*a22)*id_;
  float i11 = (a00*a22 - a02*a20)*id_;
  float i12 = (a02*a10 - a00*a12)*id_;
  float i20 = (a10*a21 - a11*a20)*id_;
  float i21 = (a01*a20 - a00*a21)*id_;
  float i22 = (a00*a11 - a01*a10)*id_;
  float c0 = (i00*pxx + i01*pxy + i02)*d;
  float c1 = (i10*pxx + i11*pxy + i12)*d;
  float c2 = (i20*pxx + i21*pxy + i22)*d;
  const float* Pj = poses + (size_t)jsrc*16;
  float w0 = Pj[0]*c0 + Pj[1]*c1 + Pj[2]*c2  + Pj[3];
  float w1 = Pj[4]*c0 + Pj[5]*c1 + Pj[6]*c2  + Pj[7];
  float w2 = Pj[8]*c0 + Pj[9]*c1 + Pj[10]*c2 + Pj[11];
  const float* Pi = poses + (size_t)itgt*16;
  float dx = w0 - Pi[3], dy = w1 - Pi[7], dz = w2 - Pi[11];
  float e0 = Pi[0]*dx + Pi[4]*dy + Pi[8]*dz;
  float e1 = Pi[1]*dx + Pi[5]*dy + Pi[9]*dz;
  float e2 = Pi[2]*dx + Pi[6]*dy + Pi[10]*dz;
  float uu = a00*e0 + a01*e1 + a02*e2;
  float vv = a10*e0 + a11*e1 + a12*e2;
  float zz = a20*e0 + a21*e1 + a22*e2;
  float zs = (fabsf(zz) > 1e-6f) ? zz : 1e-6f;
  Proj r;
  r.u = uu/zs; r.v = vv/zs;
  r.vis = (zz > 0.1f) && (r.u >= 0.f) && (r.u <= (float)(WW-1)) && (r.v >= 0.f) && (r.v <= (float)(HH-1));
  return r;
}

// ---------------- K1: fused gray + sobel (edge pad) + products, LDS-tiled ----------------
__global__ __launch_bounds__(256) void k_graysobel(const float* __restrict__ imgs,
        float* __restrict__ gxx, float* __restrict__ gyy, float* __restrict__ gxy){
  __shared__ float lg[TY+2][TX+2];
  int b = blockIdx.z;
  int x0 = blockIdx.x*TX, y0 = blockIdx.y*TY;
  const float* br = imgs + (size_t)b*3*HWsz;
  const float* bg = br + HWsz;
  const float* bb = bg + HWsz;
  const int W2 = TX+2, H2 = TY+2;
  for (int i = threadIdx.x; i < H2*W2; i += 256){
    int ly = i / W2, lx = i - ly*W2;
    int gy = clampi(y0 - 1 + ly, 0, HH-1), gx = clampi(x0 - 1 + lx, 0, WW-1);
    size_t off = (size_t)gy*WW + gx;
    lg[ly][lx] = 0.299f*br[off] + 0.587f*bg[off] + 0.114f*bb[off];
  }
  __syncthreads();
  int tx = threadIdx.x & (TX-1), ty = threadIdx.x / TX;
  float g00 = lg[ty][tx],   g01 = lg[ty][tx+1],   g02 = lg[ty][tx+2];
  float g10 = lg[ty+1][tx],                        g12 = lg[ty+1][tx+2];
  float g20 = lg[ty+2][tx], g21 = lg[ty+2][tx+1], g22 = lg[ty+2][tx+2];
  float gx = 0.125f*(g02-g00) + 0.25f*(g12-g10) + 0.125f*(g22-g20);
  float gy = 0.125f*(g20-g00) + 0.25f*(g21-g01) + 0.125f*(g22-g02);
  size_t o = (size_t)b*HWsz + (size_t)(y0+ty)*WW + (x0+tx);
  gxx[o] = gx*gx; gyy[o] = gy*gy; gxy[o] = gx*gy;
}

// ---------------- K3: gaussian 7x7 (reflect) + GFTT response, LDS-tiled ----------------
__global__ __launch_bounds__(256) void k_gauss_resp(const float* __restrict__ gxx,
        const float* __restrict__ gyy, const float* __restrict__ gxy, float* __restrict__ resp){
  __shared__ float lxx[TY+6][TX+6], lyy[TY+6][TX+6], lxy[TY+6][TX+6];
  int b = blockIdx.z;
  int x0 = blockIdx.x*TX, y0 = blockIdx.y*TY;
  const float* axx = gxx + (size_t)b*HWsz;
  const float* ayy = gyy + (size_t)b*HWsz;
  const float* axy = gxy + (size_t)b*HWsz;
  const int W2 = TX+6, H2 = TY+6;
  for (int i = threadIdx.x; i < H2*W2; i += 256){
    int ly = i / W2, lx = i - ly*W2;
    int gy = refl(y0 - 3 + ly, HH), gx = refl(x0 - 3 + lx, WW);
    size_t off = (size_t)gy*WW + gx;
    lxx[ly][lx] = axx[off]; lyy[ly][lx] = ayy[off]; lxy[ly][lx] = axy[off];
  }
  __syncthreads();
  int tx = threadIdx.x & (TX-1), ty = threadIdx.x / TX;
  float sxx=0.f, syy=0.f, sxy=0.f;
  #pragma unroll
  for (int i=0;i<7;++i){
    float wr = GW[i];
    #pragma unroll
    for (int j=0;j<7;++j){
      float wc = wr*GW[j];
      sxx += wc*lxx[ty+i][tx+j];
      syy += wc*lyy[ty+i][tx+j];
      sxy += wc*lxy[ty+i][tx+j];
    }
  }
  float tr = sxx+syy, df = sxx-syy;
  float disc = sqrtf(fmaxf(df*df + 4.f*sxy*sxy, 0.f));
  resp[(size_t)b*HWsz + (size_t)(y0+ty)*WW + (x0+tx)] = 0.5f*(tr - disc);
}

// ---------------- K4+K5 fused: 5x5 NMS + 8x8 blockmax + slot write ----------------
// tile 32x8 covers exactly four 8x8 blocks; wave w reduces block w.
__global__ __launch_bounds__(256) void k_nmsblk(const float* __restrict__ resp,
        unsigned long long* __restrict__ ckeys, unsigned int* __restrict__ ccnt){
  __shared__ float lr[TY+4][TX+4];
  __shared__ float lk[TY][TX];
  int b = blockIdx.z;
  int x0 = blockIdx.x*TX, y0 = blockIdx.y*TY;
  const float* rb = resp + (size_t)b*HWsz;
  const int W2 = TX+4, H2 = TY+4;
  for (int i = threadIdx.x; i < H2*W2; i += 256){
    int ly = i / W2, lx = i - ly*W2;
    int gy = y0 - 2 + ly, gx = x0 - 2 + lx;
    lr[ly][lx] = (gy >= 0 && gy < HH && gx >= 0 && gx < WW) ? rb[(size_t)gy*WW + gx] : -1e30f;
  }
  __syncthreads();
  int tx = threadIdx.x & (TX-1), ty = threadIdx.x / TX;
  float m = -1e30f;
  #pragma unroll
  for (int dy=0; dy<5; ++dy)
    #pragma unroll
    for (int dx=0; dx<5; ++dx) m = fmaxf(m, lr[ty+dy][tx+dx]);
  float r = lr[ty+2][tx+2];
  lk[ty][tx] = (r == m) ? r : 0.f;
  __syncthreads();
  int wave = threadIdx.x >> 6, lane = threadIdx.x & 63;
  int ly = lane >> 3, lx = wave*8 + (lane & 7);   // wave w handles 8x8 block w
  float v = lk[ly][lx];
  float bm = wave_max(v);
  if (!(bm > 0.f)) return;
  unsigned long long mask = __ballot(v == bm);
  if (v == bm){
    int yy = y0 + ly, xx2 = x0 + lx;
    unsigned long long key =
      ((unsigned long long)__float_as_uint(bm) << 32) |
      (unsigned long long)(0xFFFFFFFFu - (unsigned int)(yy*WW + xx2));
    int rank = __popcll(mask & ((1ull << lane) - 1ull));
    int rblk = blockIdx.y*(WW/8) + blockIdx.x*4 + wave;
    if (rank == 0){
      ckeys[(size_t)b*CAP + rblk] = key;            // fixed slot, no atomic
    } else {
      unsigned int slot = NBLK + atomicAdd(&ccnt[b], 1u);  // ties only (~never)
      if (slot < CAP) ckeys[(size_t)b*CAP + slot] = key;
    }
  }
}

// ---------------- K6: bitonic top-500 per batch ----------------
__global__ __launch_bounds__(1024) void k_top500(const unsigned long long* __restrict__ ckeys,
        float* __restrict__ cpts, float* __restrict__ cvals){
  __shared__ unsigned long long sk[CAP];
  int b = blockIdx.x;
  int tid = threadIdx.x;
  for (int i = tid; i < CAP; i += 1024)
    sk[i] = ckeys[(size_t)b*CAP + i];
  __syncthreads();
  for (int k = 2; k <= CAP; k <<= 1){
    for (int j = k >> 1; j > 0; j >>= 1){
      for (int i = tid; i < CAP; i += 1024){
        int l = i ^ j;
        if (l > i){
          unsigned long long A = sk[i], Bv = sk[l];
          bool up = ((i & k) == 0);
          if ((A > Bv) == up){ sk[i] = Bv; sk[l] = A; }
        }
      }
      __syncthreads();
    }
  }
  if (tid < NC){
    unsigned long long key = sk[CAP-1-tid];
    float val = __uint_as_float((unsigned int)(key >> 32));
    size_t o = (size_t)b*NC + tid;
    if (val > 0.f){
      unsigned int idx = 0xFFFFFFFFu - (unsigned int)(key & 0xFFFFFFFFull);
      float fx = (float)(idx % WW), fy = (float)(idx / WW);
      cpts[o*2+0] = (fx*2.0f)/(float)(WW-1) - 1.0f;
      cpts[o*2+1] = (fy*2.0f)/(float)(HH-1) - 1.0f;
      cvals[o] = val;
    } else {
      cpts[o*2+0] = __int_as_float(0x7fc00000);
      cpts[o*2+1] = __int_as_float(0x7fc00000);
      cvals[o] = 0.f;
    }
  }
}

// ---------------- K7: corner projection + scatter-max ----------------
__global__ void k_corner_scatter(const float* __restrict__ cpts, const float* __restrict__ cvals,
        const float* __restrict__ depths, const float* __restrict__ poses,
        const float* __restrict__ Km, unsigned int* __restrict__ target){
  int t = blockIdx.x*blockDim.x + threadIdx.x;
  if (t >= BB*BB*NC) return;
  int i = t / (BB*NC); int r = t - i*(BB*NC); int j = r / NC; int n = r - j*NC;
  float val = cvals[(size_t)i*NC + n];
  float ptx = cpts[((size_t)j*NC+n)*2+0];
  float pty = cpts[((size_t)j*NC+n)*2+1];
  if (!(val > 0.f) || ptx != ptx) return;
  Proj pr = project_point(ptx, pty, j, i, depths, poses, Km);
  if (!pr.vis) return;
  float nu = (pr.u*2.0f)/(float)(WW-1) - 1.0f;
  float nv = (pr.v*2.0f)/(float)(HH-1) - 1.0f;
  float px2 = ((nu+1.0f)*(float)(WW-1))*0.5f;
  float py2 = ((nv+1.0f)*(float)(HH-1))*0.5f;
  float rx = rintf(px2), ry = rintf(py2);
  if (!(rx >= 0.f && ry >= 0.f && rx <= (float)(WW-1) && ry <= (float)(HH-1))) return;
  int wf = (int)rx, hf = (int)ry;
  atomicMax(&target[(size_t)j*HWsz + hf*WW + wf], __float_as_uint(val));
}

// ---------------- K8: target NMS + BCE + laplacian, LDS-tiled + slot atomics ----------------
__global__ __launch_bounds__(256) void k_score_reduce(const float* __restrict__ target,
        const float* __restrict__ scores, double* __restrict__ accs){
  __shared__ float ltg[TY+4][TX+4], lsc[TY+4][TX+4];
  __shared__ float rbuf[4][2];
  int b = blockIdx.z;
  int x0 = blockIdx.x*TX, y0 = blockIdx.y*TY;
  const float* tg = target + (size_t)b*HWsz;
  const float* sb = scores + (size_t)b*HWsz;
  const int W2 = TX+4, H2 = TY+4;
  for (int i = threadIdx.x; i < H2*W2; i += 256){
    int ly = i / W2, lx = i - ly*W2;
    int gy = y0 - 2 + ly, gx = x0 - 2 + lx;
    ltg[ly][lx] = (gy >= 0 && gy < HH && gx >= 0 && gx < WW) ? tg[(size_t)gy*WW + gx] : -1e30f;
    lsc[ly][lx] = sb[(size_t)refl(gy,HH)*WW + refl(gx,WW)];
  }
  __syncthreads();
  int tx = threadIdx.x & (TX-1), ty = threadIdx.x / TX;
  float m = -1e30f, S5 = 0.f;
  #pragma unroll
  for (int dy=0; dy<5; ++dy)
    #pragma unroll
    for (int dx=0; dx<5; ++dx){
      m = fmaxf(m, ltg[ty+dy][tx+dx]);
      S5 += lsc[ty+dy][tx+dx];
    }
  float tv = ltg[ty+2][tx+2];
  float sc = lsc[ty+2][tx+2];
  float tb = (tv > 0.f && tv == m) ? 1.f : 0.f;
  float pc = fminf(fmaxf(sc, 1e-12f), 1.0f - 1e-12f);
  float bce = -(tb*logf(pc) + (1.f-tb)*logf(1.f-pc));
  float lap = (S5 - sc)*(1.0f/48.0f) - 0.5f*sc;
  float extra = sc*expf(-lap);
  bce = wave_sum(bce); extra = wave_sum(extra);
  int wave = threadIdx.x >> 6, lane = threadIdx.x & 63;
  if (lane == 0){ rbuf[wave][0] = bce; rbuf[wave][1] = extra; }
  __syncthreads();
  if (threadIdx.x == 0){
    int slot = (blockIdx.x + blockIdx.y*(WW/TX) + blockIdx.z*400) & (NSLOT-1);
    atomicAdd(&accs[(1*NSLOT + slot)*8], (double)(rbuf[0][0]+rbuf[1][0]+rbuf[2][0]+rbuf[3][0]));
    atomicAdd(&accs[(2*NSLOT + slot)*8], (double)(rbuf[0][1]+rbuf[1][1]+rbuf[2][1]+rbuf[3][1]));
  }
}

// ---------------- K9: fused rownorm+bf16 convert AND point projection ----------------
__global__ void k_rowproj(const float* __restrict__ desc, float* __restrict__ xx,
        unsigned short* __restrict__ dbf,
        const float* __restrict__ points, const float* __restrict__ depths,
        const float* __restrict__ poses, const float* __restrict__ Km,
        float* __restrict__ mproj, unsigned char* __restrict__ mvis){
  int t = blockIdx.x*blockDim.x + threadIdx.x;
  if (t < BB*NPTS){
    const float* dptr = desc + (size_t)t*DD;
    unsigned short* optr = dbf + (size_t)t*DD;
    float s = 0.f;
    for (int d = 0; d < DD; d += 4){
      float4 v = *(const float4*)(dptr + d);
      s += v.x*v.x + v.y*v.y + v.z*v.z + v.w*v.w;
      unsigned int u0 = __float_as_uint(v.x); optr[d+0] = (unsigned short)((u0 + 0x7fffu + ((u0>>16)&1u)) >> 16);
      unsigned int u1 = __float_as_uint(v.y); optr[d+1] = (unsigned short)((u1 + 0x7fffu + ((u1>>16)&1u)) >> 16);
      unsigned int u2 = __float_as_uint(v.z); optr[d+2] = (unsigned short)((u2 + 0x7fffu + ((u2>>16)&1u)) >> 16);
      unsigned int u3 = __float_as_uint(v.w); optr[d+3] = (unsigned short)((u3 + 0x7fffu + ((u3>>16)&1u)) >> 16);
    }
    xx[t] = s;
    return;
  }
  int t2 = t - BB*NPTS;
  if (t2 >= BB*BB*NPTS) return;
  int i = t2 / (BB*NPTS); int r = t2 - i*(BB*NPTS); int j = r / NPTS; int n = r - j*NPTS;
  float ptx = points[((size_t)j*NPTS+n)*2+0];
  float pty = points[((size_t)j*NPTS+n)*2+1];
  Proj pr = project_point(ptx, pty, j, i, depths, poses, Km);
  mproj[(size_t)t2*2+0] = (pr.u*2.0f)/(float)(WW-1) - 1.0f;
  mproj[(size_t)t2*2+1] = (pr.v*2.0f)/(float)(HH-1) - 1.0f;
  mvis[t2] = pr.vis ? 1 : 0;
}

// ---------------- K10: distinction via MFMA, ONE 64x64 tile per block ----------------
__global__ __launch_bounds__(256) void k_distinction_mfma(const unsigned short* __restrict__ dbf,
        const float* __restrict__ xx, double* __restrict__ accs){
  __shared__ float rbuf[4];
  int b = blockIdx.z;
  int tid = threadIdx.x;
  int wave = tid >> 6, lane = tid & 63;
  int wr = blockIdx.x*64 + (wave&1)*32;
  int wc = blockIdx.y*64 + (wave>>1)*32;
  int r = lane & 15, kg = lane >> 4;
  const unsigned short* descb = dbf + (size_t)b*NPTS*DD;
  const float* xb = xx + (size_t)b*NPTS;
  f32x4 c00 = {}, c01 = {}, c10 = {}, c11 = {};
  #pragma unroll
  for (int ks = 0; ks < 4; ++ks){
    int ko = ks*32 + kg*8;
    bf16x8 a0 = *(const bf16x8*)(descb + (size_t)(wr+r)*DD + ko);
    bf16x8 a1 = *(const bf16x8*)(descb + (size_t)(wr+16+r)*DD + ko);
    bf16x8 b0 = *(const bf16x8*)(descb + (size_t)(wc+r)*DD + ko);
    bf16x8 b1 = *(const bf16x8*)(descb + (size_t)(wc+16+r)*DD + ko);
    c00 = __builtin_amdgcn_mfma_f32_16x16x32_bf16(a0, b0, c00, 0, 0, 0);
    c01 = __builtin_amdgcn_mfma_f32_16x16x32_bf16(a0, b1, c01, 0, 0, 0);
    c10 = __builtin_amdgcn_mfma_f32_16x16x32_bf16(a1, b0, c10, 0, 0, 0);
    c11 = __builtin_amdgcn_mfma_f32_16x16x32_bf16(a1, b1, c11, 0, 0, 0);
  }
  float xn0 = xb[wc + r], xn1 = xb[wc + 16 + r];
  float local = 0.f;
  #pragma unroll
  for (int mi = 0; mi < 2; ++mi){
    #pragma unroll
    for (int j = 0; j < 4; ++j){
      float xm = xb[wr + mi*16 + 4*kg + j];
      float v0 = (mi ? c10[j] : c00[j]);
      float v1 = (mi ? c11[j] : c01[j]);
      local += fmaxf(v0 * rsqrtf(fmaxf(xm*xn0, 1e-16f)), 0.f);
      local += fmaxf(v1 * rsqrtf(fmaxf(xm*xn1, 1e-16f)), 0.f);
    }
  }
  local = wave_sum(local);
  if (lane == 0) rbuf[wave] = local;
  __syncthreads();
  if (tid == 0){
    int slot = (blockIdx.x + blockIdx.y*16 + blockIdx.z*32) & (NSLOT-1);
    atomicAdd(&accs[(0*NSLOT + slot)*8], (double)(rbuf[0]+rbuf[1]+rbuf[2]+rbuf[3]));
  }
}

// ---------------- K11: match via MFMA, ONE 64x64 tile per block ----------------
// grid (136 triangular tiles, 1, 36): ti -> (mt, nt) with nt >= mt
__global__ __launch_bounds__(256) void k_match_mfma(const unsigned short* __restrict__ dbf,
        const float* __restrict__ xx, const float* __restrict__ points,
        const float* __restrict__ mproj, const unsigned char* __restrict__ mvis,
        double* __restrict__ accs){
  __shared__ float rbuf[4][4];
  int ab = blockIdx.z; int a = ab / BB, b = ab - a*BB;
  int ti = blockIdx.x;
  int mt = 0;
  while (ti >= 16 - mt){ ti -= 16 - mt; ++mt; }
  int nt = mt + ti;
  int tid = threadIdx.x;
  int wave = tid >> 6, lane = tid & 63;
  int wr = mt*64 + (wave&1)*32;
  int wc = nt*64 + (wave>>1)*32;
  int r = lane & 15, kg = lane >> 4;
  const unsigned short* descA = dbf + (size_t)a*NPTS*DD;
  const unsigned short* descB = dbf + (size_t)b*NPTS*DD;
  const float* xxa = xx + (size_t)a*NPTS;
  const float* xxb = xx + (size_t)b*NPTS;
  const float* pts = points + (size_t)b*NPTS*2;
  const float* mp  = mproj + (((size_t)a*BB+b)*NPTS)*2;
  const unsigned char* mv = mvis + ((size_t)a*BB+b)*NPTS;
  f32x4 c00 = {}, c01 = {}, c10 = {}, c11 = {};
  #pragma unroll
  for (int ks = 0; ks < 4; ++ks){
    int ko = ks*32 + kg*8;
    bf16x8 a0 = *(const bf16x8*)(descA + (size_t)(wr+r)*DD + ko);
    bf16x8 a1 = *(const bf16x8*)(descA + (size_t)(wr+16+r)*DD + ko);
    bf16x8 b0 = *(const bf16x8*)(descB + (size_t)(wc+r)*DD + ko);
    bf16x8 b1 = *(const bf16x8*)(descB + (size_t)(wc+16+r)*DD + ko);
    c00 = __builtin_amdgcn_mfma_f32_16x16x32_bf16(a0, b0, c00, 0, 0, 0);
    c01 = __builtin_amdgcn_mfma_f32_16x16x32_bf16(a0, b1, c01, 0, 0, 0);
    c10 = __builtin_amdgcn_mfma_f32_16x16x32_bf16(a1, b0, c10, 0, 0, 0);
    c11 = __builtin_amdgcn_mfma_f32_16x16x32_bf16(a1, b1, c11, 0, 0, 0);
  }
  // n-side per-lane data (2 cols)
  float nxxv[2], ndx[2], ndy[2], ny2[2];
  #pragma unroll
  for (int ni = 0; ni < 2; ++ni){
    int n = wc + ni*16 + r;
    nxxv[ni] = xxb[n];
    float qx = mp[n*2+0], qy = mp[n*2+1];
    float dx = ((qx+1.f)*(float)(WW-1))*0.5f;
    float dy = ((qy+1.f)*(float)(HH-1))*0.5f;
    ndx[ni] = dx; ndy[ni] = dy;
    ny2[ni] = dx*dx + dy*dy;
  }
  float pos = 0.f, neg = 0.f, pcf = 0.f, ncf = 0.f;
  #pragma unroll
  for (int mi = 0; mi < 2; ++mi){
    #pragma unroll
    for (int j = 0; j < 4; ++j){
      int m = wr + mi*16 + 4*kg + j;
      if (!mv[m]) continue;
      float px = pts[m*2+0], py = pts[m*2+1];
      float sx = ((px+1.f)*(float)(WW-1))*0.5f;
      float sy = ((py+1.f)*(float)(HH-1))*0.5f;
      float x2 = sx*sx + sy*sy;
      float xm = xxa[m];
      #pragma unroll
      for (int ni = 0; ni < 2; ++ni){
        int n = wc + ni*16 + r;
        if (m >= n) continue;
        float dv = (mi ? (ni ? c11[j] : c10[j]) : (ni ? c01[j] : c00[j]));
        float d2 = x2 + ny2[ni] - 2.f*(sx*ndx[ni] + sy*ndy[ni]);
        float p = dv * rsqrtf(fmaxf(xm * nxxv[ni], 1e-16f));
        if (d2 <= 1.0f){ pos += p; pcf += 1.f; }
        else           { neg += p; ncf += 1.f; }
      }
    }
  }
  pos = wave_sum(pos); neg = wave_sum(neg);
  pcf = wave_sum(pcf); ncf = wave_sum(ncf);
  if (lane == 0){ rbuf[wave][0] = pos; rbuf[wave][1] = neg; rbuf[wave][2] = pcf; rbuf[wave][3] = ncf; }
  __syncthreads();
  if (tid == 0){
    int slot = (blockIdx.x + blockIdx.z*8) & (NSLOT-1);
    atomicAdd(&accs[(3*NSLOT + slot)*8], (double)(rbuf[0][0]+rbuf[1][0]+rbuf[2][0]+rbuf[3][0]));
    atomicAdd(&accs[(4*NSLOT + slot)*8], (double)(rbuf[0][1]+rbuf[1][1]+rbuf[2][1]+rbuf[3][1]));
    atomicAdd(&accs[(5*NSLOT + slot)*8], (double)(rbuf[0][2]+rbuf[1][2]+rbuf[2][2]+rbuf[3][2]));
    atomicAdd(&accs[(6*NSLOT + slot)*8], (double)(rbuf[0][3]+rbuf[1][3]+rbuf[2][3]+rbuf[3][3]));
  }
}

// ---------------- K12: finalize (64 threads, wave-reduce the slots) ----------------
__global__ void k_final(const double* __restrict__ accs, float* __restrict__ out){
  int lane = threadIdx.x;
  double tot[7];
  #pragma unroll
  for (int q = 0; q < 7; ++q)
    tot[q] = wave_sumd(accs[((size_t)q*NSLOT + lane)*8]);
  if (lane == 0){
    double distinction = tot[0] / (double)((long long)BB*NPTS*NPTS);
    double bce = tot[1] / (double)((long long)BB*HWsz);
    double extra = tot[2] / (double)((long long)BB*HWsz);
    double cornerness = bce + 10.0*extra;
    double pcd = tot[5] < 0.5 ? 1.0 : tot[5];
    double ncd = tot[6] < 0.5 ? 1.0 : tot[6];
    double pos_mean = tot[3] / pcd;
    double neg_mean = tot[4] / ncd;
    double match = 1.0 - pos_mean + neg_mean;
    out[0] = (float)(distinction + 0.5*cornerness + match);
  }
}

extern "C" void kernel_launch(void* const* d_in, const int* in_sizes, int n_in,
                              void* d_out, int out_size, void* d_ws, size_t ws_size,
                              hipStream_t stream) {
  (void)in_sizes; (void)n_in; (void)out_size; (void)ws_size;
  const float* desc   = (const float*)d_in[0];
  const float* points = (const float*)d_in[1];
  const float* scores = (const float*)d_in[2];
  const float* depths = (const float*)d_in[3];
  const float* poses  = (const float*)d_in[4];
  const float* Km     = (const float*)d_in[5];
  const float* imgs   = (const float*)d_in[6];
  float* out = (float*)d_out;

  const size_t S = (size_t)BB*HWsz;
  float* resp = (float*)d_ws;          // S
  float* gxx  = resp + S;              // S
  float* gyy  = gxx + S;               // S (→ target)
  float* gxy  = gyy + S;               // S
  unsigned long long* ckeys = (unsigned long long*)(gxy + S);      // BB*CAP*8
  unsigned int* ccnt = (unsigned int*)(ckeys + (size_t)BB*CAP);    // 8 uints
  double* accs = (double*)(ccnt + 8);                              // 7*64*8 doubles
  float* cpts  = (float*)(accs + 7*NSLOT*8);                       // BB*NC*2
  float* cvals = cpts + (size_t)BB*NC*2;                           // BB*NC
  float* xx    = cvals + (size_t)BB*NC;                            // BB*NPTS
  float* mproj = xx + (size_t)BB*NPTS;                             // BB*BB*NPTS*2
  unsigned char* mvis = (unsigned char*)(mproj + (size_t)BB*BB*NPTS*2); // BB*BB*NPTS
  unsigned short* dbf = (unsigned short*)(mvis + (size_t)BB*BB*NPTS);   // bf16 desc

  dim3 blk(256);
  dim3 gtile(WW/TX, HH/TY, BB);

  k_graysobel<<<gtile, blk, 0, stream>>>(imgs, gxx, gyy, gxy);
  k_gauss_resp<<<gtile, blk, 0, stream>>>(gxx, gyy, gxy, resp);

  // zero target (reuses gyy: AFTER k_gauss_resp) and ckeys/ccnt/accs region
  hipMemsetAsync(gyy, 0, S*sizeof(float), stream);
  hipMemsetAsync(ckeys, 0,
      (size_t)BB*CAP*sizeof(unsigned long long) + 8*sizeof(unsigned int) +
      (size_t)7*NSLOT*8*sizeof(double), stream);

  k_nmsblk<<<gtile, blk, 0, stream>>>(resp, ckeys, ccnt);
  k_top500<<<dim3(BB), dim3(1024), 0, stream>>>(ckeys, cpts, cvals);
  {
    int n = BB*BB*NC;
    k_corner_scatter<<<dim3((n+255)/256), blk, 0, stream>>>(cpts, cvals, depths, poses, Km,
                                                            (unsigned int*)gyy);
  }
  k_score_reduce<<<gtile, blk, 0, stream>>>(gyy, scores, accs);
  {
    int n = BB*NPTS + BB*BB*NPTS;
    k_rowproj<<<dim3((n+255)/256), blk, 0, stream>>>(desc, xx, dbf, points, depths, poses, Km,
                                                     mproj, mvis);
  }
  k_distinction_mfma<<<dim3(16, 16, BB), blk, 0, stream>>>(dbf, xx, accs);
  k_match_mfma<<<dim3(136, 1, BB*BB), blk, 0, stream>>>(dbf, xx, points, mproj, mvis, accs);
  k_final<<<dim3(1), dim3(64), 0, stream>>>(accs, out);
}

// Round 12
// 198.084 us; speedup vs baseline: 3.1442x; 1.0869x over previous
//
#include <hip/hip_runtime.h>
#include <stdint.h>

#define BB 6
#define NPTS 1024
#define DD 128
#define HH 320
#define WW 320
#define NC 500
#define HWsz (HH*WW)
#define CAP 2048
#define NBLK ((HH/8)*(WW/8))
#define TX 32
#define TY 8
#define NSLOT 64
// accs: 7 quantities x 64 slots, each slot on its own 64B line
// q: 0=distinction 1=bce 2=extra 3=pos 4=neg 5=pcnt 6=ncnt

typedef __attribute__((ext_vector_type(8))) short bf16x8;
typedef __attribute__((ext_vector_type(4))) float f32x4;

__device__ __forceinline__ int clampi(int v, int lo, int hi){ return v<lo?lo:(v>hi?hi:v); }
__device__ __forceinline__ int refl(int p, int L){ if(p<0)p=-p; if(p>=L)p=2*L-2-p; return p; }

__device__ __forceinline__ float wave_sum(float v){
  #pragma unroll
  for (int o = 32; o > 0; o >>= 1) v += __shfl_xor(v, o, 64);
  return v;
}
__device__ __forceinline__ double wave_sumd(double v){
  #pragma unroll
  for (int o = 32; o > 0; o >>= 1) v += __shfl_xor(v, o, 64);
  return v;
}
__device__ __forceinline__ float wave_max(float v){
  #pragma unroll
  for (int o = 32; o > 0; o >>= 1) v = fmaxf(v, __shfl_xor(v, o, 64));
  return v;
}

__device__ __constant__ float GW[7] = {
  0.0044330481f, 0.0540055850f, 0.2420362300f, 0.3990502700f,
  0.2420362300f, 0.0540055850f, 0.0044330481f };

// ---------------- projection (matches pairwise_project) ----------------
struct Proj { float u, v; int vis; };

__device__ Proj project_point(float ptx, float pty, int jsrc, int itgt,
                              const float* __restrict__ depths,
                              const float* __restrict__ poses,
                              const float* __restrict__ Km)
{
  float pxx = ((ptx + 1.0f)*(float)(WW-1))*0.5f;
  float pxy = ((pty + 1.0f)*(float)(HH-1))*0.5f;
  float rx = rintf(pxx), ry = rintf(pxy);
  rx = fminf(fmaxf(rx, 0.f), (float)(WW-1));
  ry = fminf(fmaxf(ry, 0.f), (float)(HH-1));
  int xi = (int)rx, yi = (int)ry;
  float d = depths[(size_t)jsrc*HWsz + yi*WW + xi];
  float a00=Km[0],a01=Km[1],a02=Km[2],a10=Km[3],a11=Km[4],a12=Km[5],a20=Km[6],a21=Km[7],a22=Km[8];
  float det = a00*(a11*a22 - a12*a21) - a01*(a10*a22 - a12*a20) + a02*(a10*a21 - a11*a20);
  float id_ = 1.0f/det;
  float i00 = (a11*a22 - a12*a21)*id_;
  float i01 = (a02*a21 - a01*a22)*id_;
  float i02 = (a01*a12 - a02*a11)*id_;
  float i10 = (a12*a20 - a10*a22)*id_;
  float i11 = (a00*a22 - a02*a20)*id_;
  float i12 = (a02*a10 - a00*a12)*id_;
  float i20 = (a10*a21 - a11*a20)*id_;
  float i21 = (a01*a20 - a00*a21)*id_;
  float i22 = (a00*a11 - a01*a10)*id_;
  float c0 = (i00*pxx + i01*pxy + i02)*d;
  float c1 = (i10*pxx + i11*pxy + i12)*d;
  float c2 = (i20*pxx + i21*pxy + i22)*d;
  const float* Pj = poses + (size_t)jsrc*16;
  float w0 = Pj[0]*c0 + Pj[1]*c1 + Pj[2]*c2  + Pj[3];
  float w1 = Pj[4]*c0 + Pj[5]*c1 + Pj[6]*c2  + Pj[7];
  float w2 = Pj[8]*c0 + Pj[9]*c1 + Pj[10]*c2 + Pj[11];
  const float* Pi = poses + (size_t)itgt*16;
  float dx = w0 - Pi[3], dy = w1 - Pi[7], dz = w2 - Pi[11];
  float e0 = Pi[0]*dx + Pi[4]*dy + Pi[8]*dz;
  float e1 = Pi[1]*dx + Pi[5]*dy + Pi[9]*dz;
  float e2 = Pi[2]*dx + Pi[6]*dy + Pi[10]*dz;
  float uu = a00*e0 + a01*e1 + a02*e2;
  float vv = a10*e0 + a11*e1 + a12*e2;
  float zz = a20*e0 + a21*e1 + a22*e2;
  float zs = (fabsf(zz) > 1e-6f) ? zz : 1e-6f;
  Proj r;
  r.u = uu/zs; r.v = vv/zs;
  r.vis = (zz > 0.1f) && (r.u >= 0.f) && (r.u <= (float)(WW-1)) && (r.v >= 0.f) && (r.v <= (float)(HH-1));
  return r;
}

// ---------------- K1: FUSED gray+sobel+gauss7x7+GFTT response ----------------
// gray tile halo 4 (clamp), sobel products halo 3 (reflect at product coords), 7x7 conv.
__global__ __launch_bounds__(256) void k_gftt(const float* __restrict__ imgs,
        float* __restrict__ resp){
  __shared__ float lg[TY+8][TX+8];
  __shared__ float lxx[TY+6][TX+6], lyy[TY+6][TX+6], lxy[TY+6][TX+6];
  int b = blockIdx.z;
  int x0 = blockIdx.x*TX, y0 = blockIdx.y*TY;
  const float* br = imgs + (size_t)b*3*HWsz;
  const float* bg = br + HWsz;
  const float* bbl = bg + HWsz;
  const int GW2 = TX+8, GH2 = TY+8;
  for (int i = threadIdx.x; i < GH2*GW2; i += 256){
    int ly = i / GW2, lx = i - ly*GW2;
    int gy = clampi(y0-4+ly, 0, HH-1), gx = clampi(x0-4+lx, 0, WW-1);
    size_t off = (size_t)gy*WW + gx;
    lg[ly][lx] = 0.299f*br[off] + 0.587f*bg[off] + 0.114f*bbl[off];
  }
  __syncthreads();
  const int PW2 = TX+6, PH2 = TY+6;
  for (int i = threadIdx.x; i < PH2*PW2; i += 256){
    int ly = i / PW2, lx = i - ly*PW2;
    int pcy = refl(y0-3+ly, HH), pcx = refl(x0-3+lx, WW);
    int ym = clampi(pcy-1,0,HH-1)-(y0-4), yc = pcy-(y0-4), yp = clampi(pcy+1,0,HH-1)-(y0-4);
    int xm = clampi(pcx-1,0,WW-1)-(x0-4), xc = pcx-(x0-4), xp = clampi(pcx+1,0,WW-1)-(x0-4);
    float g00=lg[ym][xm], g01=lg[ym][xc], g02=lg[ym][xp];
    float g10=lg[yc][xm],                 g12=lg[yc][xp];
    float g20=lg[yp][xm], g21=lg[yp][xc], g22=lg[yp][xp];
    float gx = 0.125f*(g02-g00)+0.25f*(g12-g10)+0.125f*(g22-g20);
    float gy = 0.125f*(g20-g00)+0.25f*(g21-g01)+0.125f*(g22-g02);
    lxx[ly][lx]=gx*gx; lyy[ly][lx]=gy*gy; lxy[ly][lx]=gx*gy;
  }
  __syncthreads();
  int tx = threadIdx.x & (TX-1), ty = threadIdx.x / TX;
  float sxx=0.f, syy=0.f, sxy=0.f;
  #pragma unroll
  for (int i=0;i<7;++i){
    float wr = GW[i];
    #pragma unroll
    for (int j=0;j<7;++j){
      float wc = wr*GW[j];
      sxx += wc*lxx[ty+i][tx+j];
      syy += wc*lyy[ty+i][tx+j];
      sxy += wc*lxy[ty+i][tx+j];
    }
  }
  float tr = sxx+syy, df = sxx-syy;
  float disc = sqrtf(fmaxf(df*df + 4.f*sxy*sxy, 0.f));
  resp[(size_t)b*HWsz + (size_t)(y0+ty)*WW + (x0+tx)] = 0.5f*(tr - disc);
}

// ---------------- K4+K5 fused: 5x5 NMS + 8x8 blockmax + slot write ----------------
__global__ __launch_bounds__(256) void k_nmsblk(const float* __restrict__ resp,
        unsigned long long* __restrict__ ckeys, unsigned int* __restrict__ ccnt){
  __shared__ float lr[TY+4][TX+4];
  __shared__ float lk[TY][TX];
  int b = blockIdx.z;
  int x0 = blockIdx.x*TX, y0 = blockIdx.y*TY;
  const float* rb = resp + (size_t)b*HWsz;
  const int W2 = TX+4, H2 = TY+4;
  for (int i = threadIdx.x; i < H2*W2; i += 256){
    int ly = i / W2, lx = i - ly*W2;
    int gy = y0 - 2 + ly, gx = x0 - 2 + lx;
    lr[ly][lx] = (gy >= 0 && gy < HH && gx >= 0 && gx < WW) ? rb[(size_t)gy*WW + gx] : -1e30f;
  }
  __syncthreads();
  int tx = threadIdx.x & (TX-1), ty = threadIdx.x / TX;
  float m = -1e30f;
  #pragma unroll
  for (int dy=0; dy<5; ++dy)
    #pragma unroll
    for (int dx=0; dx<5; ++dx) m = fmaxf(m, lr[ty+dy][tx+dx]);
  float r = lr[ty+2][tx+2];
  lk[ty][tx] = (r == m) ? r : 0.f;
  __syncthreads();
  int wave = threadIdx.x >> 6, lane = threadIdx.x & 63;
  int ly = lane >> 3, lx = wave*8 + (lane & 7);
  float v = lk[ly][lx];
  float bm = wave_max(v);
  if (!(bm > 0.f)) return;
  unsigned long long mask = __ballot(v == bm);
  if (v == bm){
    int yy = y0 + ly, xx2 = x0 + lx;
    unsigned long long key =
      ((unsigned long long)__float_as_uint(bm) << 32) |
      (unsigned long long)(0xFFFFFFFFu - (unsigned int)(yy*WW + xx2));
    int rank = __popcll(mask & ((1ull << lane) - 1ull));
    int rblk = blockIdx.y*(WW/8) + blockIdx.x*4 + wave;
    if (rank == 0){
      ckeys[(size_t)b*CAP + rblk] = key;
    } else {
      unsigned int slot = NBLK + atomicAdd(&ccnt[b], 1u);
      if (slot < CAP) ckeys[(size_t)b*CAP + slot] = key;
    }
  }
}

// ---------------- K6: bitonic top-500 per batch ----------------
__global__ __launch_bounds__(1024) void k_top500(const unsigned long long* __restrict__ ckeys,
        float* __restrict__ cpts, float* __restrict__ cvals){
  __shared__ unsigned long long sk[CAP];
  int b = blockIdx.x;
  int tid = threadIdx.x;
  for (int i = tid; i < CAP; i += 1024)
    sk[i] = ckeys[(size_t)b*CAP + i];
  __syncthreads();
  for (int k = 2; k <= CAP; k <<= 1){
    for (int j = k >> 1; j > 0; j >>= 1){
      for (int i = tid; i < CAP; i += 1024){
        int l = i ^ j;
        if (l > i){
          unsigned long long A = sk[i], Bv = sk[l];
          bool up = ((i & k) == 0);
          if ((A > Bv) == up){ sk[i] = Bv; sk[l] = A; }
        }
      }
      __syncthreads();
    }
  }
  if (tid < NC){
    unsigned long long key = sk[CAP-1-tid];
    float val = __uint_as_float((unsigned int)(key >> 32));
    size_t o = (size_t)b*NC + tid;
    if (val > 0.f){
      unsigned int idx = 0xFFFFFFFFu - (unsigned int)(key & 0xFFFFFFFFull);
      float fx = (float)(idx % WW), fy = (float)(idx / WW);
      cpts[o*2+0] = (fx*2.0f)/(float)(WW-1) - 1.0f;
      cpts[o*2+1] = (fy*2.0f)/(float)(HH-1) - 1.0f;
      cvals[o] = val;
    } else {
      cpts[o*2+0] = __int_as_float(0x7fc00000);
      cpts[o*2+1] = __int_as_float(0x7fc00000);
      cvals[o] = 0.f;
    }
  }
}

// ---------------- K7: corner projection + scatter-max ----------------
__global__ void k_corner_scatter(const float* __restrict__ cpts, const float* __restrict__ cvals,
        const float* __restrict__ depths, const float* __restrict__ poses,
        const float* __restrict__ Km, unsigned int* __restrict__ target){
  int t = blockIdx.x*blockDim.x + threadIdx.x;
  if (t >= BB*BB*NC) return;
  int i = t / (BB*NC); int r = t - i*(BB*NC); int j = r / NC; int n = r - j*NC;
  float val = cvals[(size_t)i*NC + n];
  float ptx = cpts[((size_t)j*NC+n)*2+0];
  float pty = cpts[((size_t)j*NC+n)*2+1];
  if (!(val > 0.f) || ptx != ptx) return;
  Proj pr = project_point(ptx, pty, j, i, depths, poses, Km);
  if (!pr.vis) return;
  float nu = (pr.u*2.0f)/(float)(WW-1) - 1.0f;
  float nv = (pr.v*2.0f)/(float)(HH-1) - 1.0f;
  float px2 = ((nu+1.0f)*(float)(WW-1))*0.5f;
  float py2 = ((nv+1.0f)*(float)(HH-1))*0.5f;
  float rx = rintf(px2), ry = rintf(py2);
  if (!(rx >= 0.f && ry >= 0.f && rx <= (float)(WW-1) && ry <= (float)(HH-1))) return;
  int wf = (int)rx, hf = (int)ry;
  atomicMax(&target[(size_t)j*HWsz + hf*WW + wf], __float_as_uint(val));
}

// ---------------- K8: target NMS + BCE + laplacian, LDS-tiled + slot atomics ----------------
__global__ __launch_bounds__(256) void k_score_reduce(const float* __restrict__ target,
        const float* __restrict__ scores, double* __restrict__ accs){
  __shared__ float ltg[TY+4][TX+4], lsc[TY+4][TX+4];
  __shared__ float rbuf[4][2];
  int b = blockIdx.z;
  int x0 = blockIdx.x*TX, y0 = blockIdx.y*TY;
  const float* tg = target + (size_t)b*HWsz;
  const float* sb = scores + (size_t)b*HWsz;
  const int W2 = TX+4, H2 = TY+4;
  for (int i = threadIdx.x; i < H2*W2; i += 256){
    int ly = i / W2, lx = i - ly*W2;
    int gy = y0 - 2 + ly, gx = x0 - 2 + lx;
    ltg[ly][lx] = (gy >= 0 && gy < HH && gx >= 0 && gx < WW) ? tg[(size_t)gy*WW + gx] : -1e30f;
    lsc[ly][lx] = sb[(size_t)refl(gy,HH)*WW + refl(gx,WW)];
  }
  __syncthreads();
  int tx = threadIdx.x & (TX-1), ty = threadIdx.x / TX;
  float m = -1e30f, S5 = 0.f;
  #pragma unroll
  for (int dy=0; dy<5; ++dy)
    #pragma unroll
    for (int dx=0; dx<5; ++dx){
      m = fmaxf(m, ltg[ty+dy][tx+dx]);
      S5 += lsc[ty+dy][tx+dx];
    }
  float tv = ltg[ty+2][tx+2];
  float sc = lsc[ty+2][tx+2];
  float tb = (tv > 0.f && tv == m) ? 1.f : 0.f;
  float pc = fminf(fmaxf(sc, 1e-12f), 1.0f - 1e-12f);
  float bce = -(tb*logf(pc) + (1.f-tb)*logf(1.f-pc));
  float lap = (S5 - sc)*(1.0f/48.0f) - 0.5f*sc;
  float extra = sc*expf(-lap);
  bce = wave_sum(bce); extra = wave_sum(extra);
  int wave = threadIdx.x >> 6, lane = threadIdx.x & 63;
  if (lane == 0){ rbuf[wave][0] = bce; rbuf[wave][1] = extra; }
  __syncthreads();
  if (threadIdx.x == 0){
    int slot = (blockIdx.x + blockIdx.y*(WW/TX) + blockIdx.z*400) & (NSLOT-1);
    atomicAdd(&accs[(1*NSLOT + slot)*8], (double)(rbuf[0][0]+rbuf[1][0]+rbuf[2][0]+rbuf[3][0]));
    atomicAdd(&accs[(2*NSLOT + slot)*8], (double)(rbuf[0][1]+rbuf[1][1]+rbuf[2][1]+rbuf[3][1]));
  }
}

// ---------------- K9: fused rownorm+bf16 convert AND point projection ----------------
__global__ void k_rowproj(const float* __restrict__ desc, float* __restrict__ xx,
        unsigned short* __restrict__ dbf,
        const float* __restrict__ points, const float* __restrict__ depths,
        const float* __restrict__ poses, const float* __restrict__ Km,
        float* __restrict__ mproj, unsigned char* __restrict__ mvis){
  int t = blockIdx.x*blockDim.x + threadIdx.x;
  if (t < BB*NPTS){
    const float* dptr = desc + (size_t)t*DD;
    unsigned short* optr = dbf + (size_t)t*DD;
    float s = 0.f;
    for (int d = 0; d < DD; d += 4){
      float4 v = *(const float4*)(dptr + d);
      s += v.x*v.x + v.y*v.y + v.z*v.z + v.w*v.w;
      unsigned int u0 = __float_as_uint(v.x); optr[d+0] = (unsigned short)((u0 + 0x7fffu + ((u0>>16)&1u)) >> 16);
      unsigned int u1 = __float_as_uint(v.y); optr[d+1] = (unsigned short)((u1 + 0x7fffu + ((u1>>16)&1u)) >> 16);
      unsigned int u2 = __float_as_uint(v.z); optr[d+2] = (unsigned short)((u2 + 0x7fffu + ((u2>>16)&1u)) >> 16);
      unsigned int u3 = __float_as_uint(v.w); optr[d+3] = (unsigned short)((u3 + 0x7fffu + ((u3>>16)&1u)) >> 16);
    }
    xx[t] = s;
    return;
  }
  int t2 = t - BB*NPTS;
  if (t2 >= BB*BB*NPTS) return;
  int i = t2 / (BB*NPTS); int r = t2 - i*(BB*NPTS); int j = r / NPTS; int n = r - j*NPTS;
  float ptx = points[((size_t)j*NPTS+n)*2+0];
  float pty = points[((size_t)j*NPTS+n)*2+1];
  Proj pr = project_point(ptx, pty, j, i, depths, poses, Km);
  mproj[(size_t)t2*2+0] = (pr.u*2.0f)/(float)(WW-1) - 1.0f;
  mproj[(size_t)t2*2+1] = (pr.v*2.0f)/(float)(HH-1) - 1.0f;
  mvis[t2] = pr.vis ? 1 : 0;
}

// ---------------- K10+K11 merged: match tile (all blocks) + distinction tile (first 1536) ----------------
// grid (136, 1, 36). match: ti -> (mt,nt) triangular. distinction: flat = bx + 136*bz < 1536.
__global__ __launch_bounds__(256) void k_grams(const unsigned short* __restrict__ dbf,
        const float* __restrict__ xx, const float* __restrict__ points,
        const float* __restrict__ mproj, const unsigned char* __restrict__ mvis,
        double* __restrict__ accs){
  __shared__ float rbuf[4][4];
  int ab = blockIdx.z; int a = ab / BB, b = ab - a*BB;
  int ti = blockIdx.x;
  int mt = 0;
  while (ti >= 16 - mt){ ti -= 16 - mt; ++mt; }
  int nt = mt + ti;
  int tid = threadIdx.x;
  int wave = tid >> 6, lane = tid & 63;
  int wr = mt*64 + (wave&1)*32;
  int wc = nt*64 + (wave>>1)*32;
  int r = lane & 15, kg = lane >> 4;
  const unsigned short* descA = dbf + (size_t)a*NPTS*DD;
  const unsigned short* descB = dbf + (size_t)b*NPTS*DD;
  const float* xxa = xx + (size_t)a*NPTS;
  const float* xxb = xx + (size_t)b*NPTS;
  const float* pts = points + (size_t)b*NPTS*2;
  const float* mp  = mproj + (((size_t)a*BB+b)*NPTS)*2;
  const unsigned char* mv = mvis + ((size_t)a*BB+b)*NPTS;
  // ---- prefetch epilogue operands (independent of MFMA) ----
  float nxxv[2], ndx[2], ndy[2], ny2[2];
  #pragma unroll
  for (int ni = 0; ni < 2; ++ni){
    int n = wc + ni*16 + r;
    nxxv[ni] = xxb[n];
    float qx = mp[n*2+0], qy = mp[n*2+1];
    float dx = ((qx+1.f)*(float)(WW-1))*0.5f;
    float dy = ((qy+1.f)*(float)(HH-1))*0.5f;
    ndx[ni] = dx; ndy[ni] = dy;
    ny2[ni] = dx*dx + dy*dy;
  }
  bool  mok[2][4];
  float msx[2][4], msy[2][4], mx2[2][4], mxv[2][4];
  #pragma unroll
  for (int mi = 0; mi < 2; ++mi){
    #pragma unroll
    for (int j = 0; j < 4; ++j){
      int m = wr + mi*16 + 4*kg + j;
      mok[mi][j] = (mv[m] != 0);
      float px = pts[m*2+0], py = pts[m*2+1];
      float sx = ((px+1.f)*(float)(WW-1))*0.5f;
      float sy = ((py+1.f)*(float)(HH-1))*0.5f;
      msx[mi][j] = sx; msy[mi][j] = sy;
      mx2[mi][j] = sx*sx + sy*sy;
      mxv[mi][j] = xxa[m];
    }
  }
  // ---- MFMA ----
  f32x4 c00 = {}, c01 = {}, c10 = {}, c11 = {};
  #pragma unroll
  for (int ks = 0; ks < 4; ++ks){
    int ko = ks*32 + kg*8;
    bf16x8 a0 = *(const bf16x8*)(descA + (size_t)(wr+r)*DD + ko);
    bf16x8 a1 = *(const bf16x8*)(descA + (size_t)(wr+16+r)*DD + ko);
    bf16x8 b0 = *(const bf16x8*)(descB + (size_t)(wc+r)*DD + ko);
    bf16x8 b1 = *(const bf16x8*)(descB + (size_t)(wc+16+r)*DD + ko);
    c00 = __builtin_amdgcn_mfma_f32_16x16x32_bf16(a0, b0, c00, 0, 0, 0);
    c01 = __builtin_amdgcn_mfma_f32_16x16x32_bf16(a0, b1, c01, 0, 0, 0);
    c10 = __builtin_amdgcn_mfma_f32_16x16x32_bf16(a1, b0, c10, 0, 0, 0);
    c11 = __builtin_amdgcn_mfma_f32_16x16x32_bf16(a1, b1, c11, 0, 0, 0);
  }
  // ---- epilogue (registers only) ----
  float pos = 0.f, neg = 0.f, pcf = 0.f, ncf = 0.f;
  #pragma unroll
  for (int mi = 0; mi < 2; ++mi){
    #pragma unroll
    for (int j = 0; j < 4; ++j){
      int m = wr + mi*16 + 4*kg + j;
      if (!mok[mi][j]) continue;
      float sx = msx[mi][j], sy = msy[mi][j];
      float x2 = mx2[mi][j], xm = mxv[mi][j];
      #pragma unroll
      for (int ni = 0; ni < 2; ++ni){
        int n = wc + ni*16 + r;
        if (m >= n) continue;
        float dv = (mi ? (ni ? c11[j] : c10[j]) : (ni ? c01[j] : c00[j]));
        float d2 = x2 + ny2[ni] - 2.f*(sx*ndx[ni] + sy*ndy[ni]);
        float p = dv * rsqrtf(fmaxf(xm * nxxv[ni], 1e-16f));
        if (d2 <= 1.0f){ pos += p; pcf += 1.f; }
        else           { neg += p; ncf += 1.f; }
      }
    }
  }
  pos = wave_sum(pos); neg = wave_sum(neg);
  pcf = wave_sum(pcf); ncf = wave_sum(ncf);
  if (lane == 0){ rbuf[wave][0] = pos; rbuf[wave][1] = neg; rbuf[wave][2] = pcf; rbuf[wave][3] = ncf; }
  __syncthreads();
  if (tid == 0){
    int slot = (blockIdx.x + blockIdx.z*8) & (NSLOT-1);
    atomicAdd(&accs[(3*NSLOT + slot)*8], (double)(rbuf[0][0]+rbuf[1][0]+rbuf[2][0]+rbuf[3][0]));
    atomicAdd(&accs[(4*NSLOT + slot)*8], (double)(rbuf[0][1]+rbuf[1][1]+rbuf[2][1]+rbuf[3][1]));
    atomicAdd(&accs[(5*NSLOT + slot)*8], (double)(rbuf[0][2]+rbuf[1][2]+rbuf[2][2]+rbuf[3][2]));
    atomicAdd(&accs[(6*NSLOT + slot)*8], (double)(rbuf[0][3]+rbuf[1][3]+rbuf[2][3]+rbuf[3][3]));
  }
  // ---- distinction tile (first 1536 flat blocks) ----
  int flat = blockIdx.x + 136*blockIdx.z;
  if (flat >= 1536) return;
  int db = flat >> 8;
  int dt = flat & 255;
  int wr2 = (dt >> 4)*64 + (wave&1)*32;
  int wc2 = (dt & 15)*64 + (wave>>1)*32;
  const unsigned short* descb = dbf + (size_t)db*NPTS*DD;
  const float* xb = xx + (size_t)db*NPTS;
  f32x4 e00 = {}, e01 = {}, e10 = {}, e11 = {};
  #pragma unroll
  for (int ks = 0; ks < 4; ++ks){
    int ko = ks*32 + kg*8;
    bf16x8 a0 = *(const bf16x8*)(descb + (size_t)(wr2+r)*DD + ko);
    bf16x8 a1 = *(const bf16x8*)(descb + (size_t)(wr2+16+r)*DD + ko);
    bf16x8 b0 = *(const bf16x8*)(descb + (size_t)(wc2+r)*DD + ko);
    bf16x8 b1 = *(const bf16x8*)(descb + (size_t)(wc2+16+r)*DD + ko);
    e00 = __builtin_amdgcn_mfma_f32_16x16x32_bf16(a0, b0, e00, 0, 0, 0);
    e01 = __builtin_amdgcn_mfma_f32_16x16x32_bf16(a0, b1, e01, 0, 0, 0);
    e10 = __builtin_amdgcn_mfma_f32_16x16x32_bf16(a1, b0, e10, 0, 0, 0);
    e11 = __builtin_amdgcn_mfma_f32_16x16x32_bf16(a1, b1, e11, 0, 0, 0);
  }
  float xn0 = xb[wc2 + r], xn1 = xb[wc2 + 16 + r];
  float local = 0.f;
  #pragma unroll
  for (int mi = 0; mi < 2; ++mi){
    #pragma unroll
    for (int j = 0; j < 4; ++j){
      float xm = xb[wr2 + mi*16 + 4*kg + j];
      float v0 = (mi ? e10[j] : e00[j]);
      float v1 = (mi ? e11[j] : e01[j]);
      local += fmaxf(v0 * rsqrtf(fmaxf(xm*xn0, 1e-16f)), 0.f);
      local += fmaxf(v1 * rsqrtf(fmaxf(xm*xn1, 1e-16f)), 0.f);
    }
  }
  local = wave_sum(local);
  __syncthreads();            // rbuf reuse
  if (lane == 0) rbuf[wave][0] = local;
  __syncthreads();
  if (tid == 0){
    int slot = flat & (NSLOT-1);
    atomicAdd(&accs[(0*NSLOT + slot)*8], (double)(rbuf[0][0]+rbuf[1][0]+rbuf[2][0]+rbuf[3][0]));
  }
}

// ---------------- K12: finalize (64 threads, wave-reduce the slots) ----------------
__global__ void k_final(const double* __restrict__ accs, float* __restrict__ out){
  int lane = threadIdx.x;
  double tot[7];
  #pragma unroll
  for (int q = 0; q < 7; ++q)
    tot[q] = wave_sumd(accs[((size_t)q*NSLOT + lane)*8]);
  if (lane == 0){
    double distinction = tot[0] / (double)((long long)BB*NPTS*NPTS);
    double bce = tot[1] / (double)((long long)BB*HWsz);
    double extra = tot[2] / (double)((long long)BB*HWsz);
    double cornerness = bce + 10.0*extra;
    double pcd = tot[5] < 0.5 ? 1.0 : tot[5];
    double ncd = tot[6] < 0.5 ? 1.0 : tot[6];
    double pos_mean = tot[3] / pcd;
    double neg_mean = tot[4] / ncd;
    double match = 1.0 - pos_mean + neg_mean;
    out[0] = (float)(distinction + 0.5*cornerness + match);
  }
}

extern "C" void kernel_launch(void* const* d_in, const int* in_sizes, int n_in,
                              void* d_out, int out_size, void* d_ws, size_t ws_size,
                              hipStream_t stream) {
  (void)in_sizes; (void)n_in; (void)out_size; (void)ws_size;
  const float* desc   = (const float*)d_in[0];
  const float* points = (const float*)d_in[1];
  const float* scores = (const float*)d_in[2];
  const float* depths = (const float*)d_in[3];
  const float* poses  = (const float*)d_in[4];
  const float* Km     = (const float*)d_in[5];
  const float* imgs   = (const float*)d_in[6];
  float* out = (float*)d_out;

  const size_t S = (size_t)BB*HWsz;
  float* resp   = (float*)d_ws;                                    // S
  float* target = resp + S;                                        // S
  unsigned long long* ckeys = (unsigned long long*)(target + S);   // BB*CAP*8
  unsigned int* ccnt = (unsigned int*)(ckeys + (size_t)BB*CAP);    // 8 uints
  double* accs = (double*)(ccnt + 8);                              // 7*64*8 doubles
  float* cpts  = (float*)(accs + 7*NSLOT*8);                       // BB*NC*2
  float* cvals = cpts + (size_t)BB*NC*2;                           // BB*NC
  float* xx    = cvals + (size_t)BB*NC;                            // BB*NPTS
  float* mproj = xx + (size_t)BB*NPTS;                             // BB*BB*NPTS*2
  unsigned char* mvis = (unsigned char*)(mproj + (size_t)BB*BB*NPTS*2); // BB*BB*NPTS
  unsigned short* dbf = (unsigned short*)(mvis + (size_t)BB*BB*NPTS);   // bf16 desc

  dim3 blk(256);
  dim3 gtile(WW/TX, HH/TY, BB);

  // zero target + ckeys/ccnt/accs up front (contiguous region from target to accs end)
  hipMemsetAsync(target, 0,
      S*sizeof(float) +
      (size_t)BB*CAP*sizeof(unsigned long long) + 8*sizeof(unsigned int) +
      (size_t)7*NSLOT*8*sizeof(double), stream);

  k_gftt<<<gtile, blk, 0, stream>>>(imgs, resp);
  k_nmsblk<<<gtile, blk, 0, stream>>>(resp, ckeys, ccnt);
  k_top500<<<dim3(BB), dim3(1024), 0, stream>>>(ckeys, cpts, cvals);
  {
    int n = BB*BB*NC;
    k_corner_scatter<<<dim3((n+255)/256), blk, 0, stream>>>(cpts, cvals, depths, poses, Km,
                                                            (unsigned int*)target);
  }
  k_score_reduce<<<gtile, blk, 0, stream>>>(target, scores, accs);
  {
    int n = BB*NPTS + BB*BB*NPTS;
    k_rowproj<<<dim3((n+255)/256), blk, 0, stream>>>(desc, xx, dbf, points, depths, poses, Km,
                                                     mproj, mvis);
  }
  k_grams<<<dim3(136, 1, BB*BB), blk, 0, stream>>>(dbf, xx, points, mproj, mvis, accs);
  k_final<<<dim3(1), dim3(64), 0, stream>>>(accs, out);
}

// Round 13
// 193.003 us; speedup vs baseline: 3.2270x; 1.0263x over previous
//
#include <hip/hip_runtime.h>
#include <stdint.h>

#define BB 6
#define NPTS 1024
#define DD 128
#define HH 320
#define WW 320
#define NC 500
#define HWsz (HH*WW)
#define CAP 2048
#define NBLK ((HH/8)*(WW/8))
#define TX 32
#define TY 8
#define NSLOT 64
// accs: 7 quantities x 64 slots, each slot on its own 64B line
// q: 0=distinction 1=bce 2=extra 3=pos 4=neg 5=pcnt 6=ncnt

typedef __attribute__((ext_vector_type(8))) short bf16x8;
typedef __attribute__((ext_vector_type(4))) float f32x4;

__device__ __forceinline__ int clampi(int v, int lo, int hi){ return v<lo?lo:(v>hi?hi:v); }
__device__ __forceinline__ int refl(int p, int L){ if(p<0)p=-p; if(p>=L)p=2*L-2-p; return p; }

__device__ __forceinline__ float wave_sum(float v){
  #pragma unroll
  for (int o = 32; o > 0; o >>= 1) v += __shfl_xor(v, o, 64);
  return v;
}
__device__ __forceinline__ double wave_sumd(double v){
  #pragma unroll
  for (int o = 32; o > 0; o >>= 1) v += __shfl_xor(v, o, 64);
  return v;
}
__device__ __forceinline__ float wave_max(float v){
  #pragma unroll
  for (int o = 32; o > 0; o >>= 1) v = fmaxf(v, __shfl_xor(v, o, 64));
  return v;
}

__device__ __constant__ float GW[7] = {
  0.0044330481f, 0.0540055850f, 0.2420362300f, 0.3990502700f,
  0.2420362300f, 0.0540055850f, 0.0044330481f };

// ---------------- projection (matches pairwise_project) ----------------
struct Proj { float u, v; int vis; };

__device__ Proj project_point(float ptx, float pty, int jsrc, int itgt,
                              const float* __restrict__ depths,
                              const float* __restrict__ poses,
                              const float* __restrict__ Km)
{
  float pxx = ((ptx + 1.0f)*(float)(WW-1))*0.5f;
  float pxy = ((pty + 1.0f)*(float)(HH-1))*0.5f;
  float rx = rintf(pxx), ry = rintf(pxy);
  rx = fminf(fmaxf(rx, 0.f), (float)(WW-1));
  ry = fminf(fmaxf(ry, 0.f), (float)(HH-1));
  int xi = (int)rx, yi = (int)ry;
  float d = depths[(size_t)jsrc*HWsz + yi*WW + xi];
  float a00=Km[0],a01=Km[1],a02=Km[2],a10=Km[3],a11=Km[4],a12=Km[5],a20=Km[6],a21=Km[7],a22=Km[8];
  float det = a00*(a11*a22 - a12*a21) - a01*(a10*a22 - a12*a20) + a02*(a10*a21 - a11*a20);
  float id_ = 1.0f/det;
  float i00 = (a11*a22 - a12*a21)*id_;
  float i01 = (a02*a21 - a01*a22)*id_;
  float i02 = (a01*a12 - a02*a11)*id_;
  float i10 = (a12*a20 - a10*a22)*id_;
  float i11 = (a00*a22 - a02*a20)*id_;
  float i12 = (a02*a10 - a00*a12)*id_;
  float i20 = (a10*a21 - a11*a20)*id_;
  float i21 = (a01*a20 - a00*a21)*id_;
  float i22 = (a00*a11 - a01*a10)*id_;
  float c0 = (i00*pxx + i01*pxy + i02)*d;
  float c1 = (i10*pxx + i11*pxy + i12)*d;
  float c2 = (i20*pxx + i21*pxy + i22)*d;
  const float* Pj = poses + (size_t)jsrc*16;
  float w0 = Pj[0]*c0 + Pj[1]*c1 + Pj[2]*c2  + Pj[3];
  float w1 = Pj[4]*c0 + Pj[5]*c1 + Pj[6]*c2  + Pj[7];
  float w2 = Pj[8]*c0 + Pj[9]*c1 + Pj[10]*c2 + Pj[11];
  const float* Pi = poses + (size_t)itgt*16;
  float dx = w0 - Pi[3], dy = w1 - Pi[7], dz = w2 - Pi[11];
  float e0 = Pi[0]*dx + Pi[4]*dy + Pi[8]*dz;
  float e1 = Pi[1]*dx + Pi[5]*dy + Pi[9]*dz;
  float e2 = Pi[2]*dx + Pi[6]*dy + Pi[10]*dz;
  float uu = a00*e0 + a01*e1 + a02*e2;
  float vv = a10*e0 + a11*e1 + a12*e2;
  float zz = a20*e0 + a21*e1 + a22*e2;
  float zs = (fabsf(zz) > 1e-6f) ? zz : 1e-6f;
  Proj r;
  r.u = uu/zs; r.v = vv/zs;
  r.vis = (zz > 0.1f) && (r.u >= 0.f) && (r.u <= (float)(WW-1)) && (r.v >= 0.f) && (r.v <= (float)(HH-1));
  return r;
}

// ---------------- K1: FUSED gray+sobel+gauss7x7+GFTT response ----------------
__global__ __launch_bounds__(256) void k_gftt(const float* __restrict__ imgs,
        float* __restrict__ resp){
  __shared__ float lg[TY+8][TX+8];
  __shared__ float lxx[TY+6][TX+6], lyy[TY+6][TX+6], lxy[TY+6][TX+6];
  int b = blockIdx.z;
  int x0 = blockIdx.x*TX, y0 = blockIdx.y*TY;
  const float* br = imgs + (size_t)b*3*HWsz;
  const float* bg = br + HWsz;
  const float* bbl = bg + HWsz;
  const int GW2 = TX+8, GH2 = TY+8;
  for (int i = threadIdx.x; i < GH2*GW2; i += 256){
    int ly = i / GW2, lx = i - ly*GW2;
    int gy = clampi(y0-4+ly, 0, HH-1), gx = clampi(x0-4+lx, 0, WW-1);
    size_t off = (size_t)gy*WW + gx;
    lg[ly][lx] = 0.299f*br[off] + 0.587f*bg[off] + 0.114f*bbl[off];
  }
  __syncthreads();
  const int PW2 = TX+6, PH2 = TY+6;
  for (int i = threadIdx.x; i < PH2*PW2; i += 256){
    int ly = i / PW2, lx = i - ly*PW2;
    int pcy = refl(y0-3+ly, HH), pcx = refl(x0-3+lx, WW);
    int ym = clampi(pcy-1,0,HH-1)-(y0-4), yc = pcy-(y0-4), yp = clampi(pcy+1,0,HH-1)-(y0-4);
    int xm = clampi(pcx-1,0,WW-1)-(x0-4), xc = pcx-(x0-4), xp = clampi(pcx+1,0,WW-1)-(x0-4);
    float g00=lg[ym][xm], g01=lg[ym][xc], g02=lg[ym][xp];
    float g10=lg[yc][xm],                 g12=lg[yc][xp];
    float g20=lg[yp][xm], g21=lg[yp][xc], g22=lg[yp][xp];
    float gx = 0.125f*(g02-g00)+0.25f*(g12-g10)+0.125f*(g22-g20);
    float gy = 0.125f*(g20-g00)+0.25f*(g21-g01)+0.125f*(g22-g02);
    lxx[ly][lx]=gx*gx; lyy[ly][lx]=gy*gy; lxy[ly][lx]=gx*gy;
  }
  __syncthreads();
  int tx = threadIdx.x & (TX-1), ty = threadIdx.x / TX;
  float sxx=0.f, syy=0.f, sxy=0.f;
  #pragma unroll
  for (int i=0;i<7;++i){
    float wr = GW[i];
    #pragma unroll
    for (int j=0;j<7;++j){
      float wc = wr*GW[j];
      sxx += wc*lxx[ty+i][tx+j];
      syy += wc*lyy[ty+i][tx+j];
      sxy += wc*lxy[ty+i][tx+j];
    }
  }
  float tr = sxx+syy, df = sxx-syy;
  float disc = sqrtf(fmaxf(df*df + 4.f*sxy*sxy, 0.f));
  resp[(size_t)b*HWsz + (size_t)(y0+ty)*WW + (x0+tx)] = 0.5f*(tr - disc);
}

// ---------------- K4+K5 fused: 5x5 NMS + 8x8 blockmax + slot write ----------------
__global__ __launch_bounds__(256) void k_nmsblk(const float* __restrict__ resp,
        unsigned long long* __restrict__ ckeys, unsigned int* __restrict__ ccnt){
  __shared__ float lr[TY+4][TX+4];
  __shared__ float lk[TY][TX];
  int b = blockIdx.z;
  int x0 = blockIdx.x*TX, y0 = blockIdx.y*TY;
  const float* rb = resp + (size_t)b*HWsz;
  const int W2 = TX+4, H2 = TY+4;
  for (int i = threadIdx.x; i < H2*W2; i += 256){
    int ly = i / W2, lx = i - ly*W2;
    int gy = y0 - 2 + ly, gx = x0 - 2 + lx;
    lr[ly][lx] = (gy >= 0 && gy < HH && gx >= 0 && gx < WW) ? rb[(size_t)gy*WW + gx] : -1e30f;
  }
  __syncthreads();
  int tx = threadIdx.x & (TX-1), ty = threadIdx.x / TX;
  float m = -1e30f;
  #pragma unroll
  for (int dy=0; dy<5; ++dy)
    #pragma unroll
    for (int dx=0; dx<5; ++dx) m = fmaxf(m, lr[ty+dy][tx+dx]);
  float r = lr[ty+2][tx+2];
  lk[ty][tx] = (r == m) ? r : 0.f;
  __syncthreads();
  int wave = threadIdx.x >> 6, lane = threadIdx.x & 63;
  int ly = lane >> 3, lx = wave*8 + (lane & 7);
  float v = lk[ly][lx];
  float bm = wave_max(v);
  if (!(bm > 0.f)) return;
  unsigned long long mask = __ballot(v == bm);
  if (v == bm){
    int yy = y0 + ly, xx2 = x0 + lx;
    unsigned long long key =
      ((unsigned long long)__float_as_uint(bm) << 32) |
      (unsigned long long)(0xFFFFFFFFu - (unsigned int)(yy*WW + xx2));
    int rank = __popcll(mask & ((1ull << lane) - 1ull));
    int rblk = blockIdx.y*(WW/8) + blockIdx.x*4 + wave;
    if (rank == 0){
      ckeys[(size_t)b*CAP + rblk] = key;
    } else {
      unsigned int slot = NBLK + atomicAdd(&ccnt[b], 1u);
      if (slot < CAP) ckeys[(size_t)b*CAP + slot] = key;
    }
  }
}

// ---------------- K6: bitonic top-500 per batch ----------------
__global__ __launch_bounds__(1024) void k_top500(const unsigned long long* __restrict__ ckeys,
        float* __restrict__ cpts, float* __restrict__ cvals){
  __shared__ unsigned long long sk[CAP];
  int b = blockIdx.x;
  int tid = threadIdx.x;
  for (int i = tid; i < CAP; i += 1024)
    sk[i] = ckeys[(size_t)b*CAP + i];
  __syncthreads();
  for (int k = 2; k <= CAP; k <<= 1){
    for (int j = k >> 1; j > 0; j >>= 1){
      for (int i = tid; i < CAP; i += 1024){
        int l = i ^ j;
        if (l > i){
          unsigned long long A = sk[i], Bv = sk[l];
          bool up = ((i & k) == 0);
          if ((A > Bv) == up){ sk[i] = Bv; sk[l] = A; }
        }
      }
      __syncthreads();
    }
  }
  if (tid < NC){
    unsigned long long key = sk[CAP-1-tid];
    float val = __uint_as_float((unsigned int)(key >> 32));
    size_t o = (size_t)b*NC + tid;
    if (val > 0.f){
      unsigned int idx = 0xFFFFFFFFu - (unsigned int)(key & 0xFFFFFFFFull);
      float fx = (float)(idx % WW), fy = (float)(idx / WW);
      cpts[o*2+0] = (fx*2.0f)/(float)(WW-1) - 1.0f;
      cpts[o*2+1] = (fy*2.0f)/(float)(HH-1) - 1.0f;
      cvals[o] = val;
    } else {
      cpts[o*2+0] = __int_as_float(0x7fc00000);
      cpts[o*2+1] = __int_as_float(0x7fc00000);
      cvals[o] = 0.f;
    }
  }
}

// ---------------- K7: corner projection + scatter-max ----------------
__global__ void k_corner_scatter(const float* __restrict__ cpts, const float* __restrict__ cvals,
        const float* __restrict__ depths, const float* __restrict__ poses,
        const float* __restrict__ Km, unsigned int* __restrict__ target){
  int t = blockIdx.x*blockDim.x + threadIdx.x;
  if (t >= BB*BB*NC) return;
  int i = t / (BB*NC); int r = t - i*(BB*NC); int j = r / NC; int n = r - j*NC;
  float val = cvals[(size_t)i*NC + n];
  float ptx = cpts[((size_t)j*NC+n)*2+0];
  float pty = cpts[((size_t)j*NC+n)*2+1];
  if (!(val > 0.f) || ptx != ptx) return;
  Proj pr = project_point(ptx, pty, j, i, depths, poses, Km);
  if (!pr.vis) return;
  float nu = (pr.u*2.0f)/(float)(WW-1) - 1.0f;
  float nv = (pr.v*2.0f)/(float)(HH-1) - 1.0f;
  float px2 = ((nu+1.0f)*(float)(WW-1))*0.5f;
  float py2 = ((nv+1.0f)*(float)(HH-1))*0.5f;
  float rx = rintf(px2), ry = rintf(py2);
  if (!(rx >= 0.f && ry >= 0.f && rx <= (float)(WW-1) && ry <= (float)(HH-1))) return;
  int wf = (int)rx, hf = (int)ry;
  atomicMax(&target[(size_t)j*HWsz + hf*WW + wf], __float_as_uint(val));
}

// ---------------- K8: target NMS + BCE + laplacian, LDS-tiled + slot atomics ----------------
__global__ __launch_bounds__(256) void k_score_reduce(const float* __restrict__ target,
        const float* __restrict__ scores, double* __restrict__ accs){
  __shared__ float ltg[TY+4][TX+4], lsc[TY+4][TX+4];
  __shared__ float rbuf[4][2];
  int b = blockIdx.z;
  int x0 = blockIdx.x*TX, y0 = blockIdx.y*TY;
  const float* tg = target + (size_t)b*HWsz;
  const float* sb = scores + (size_t)b*HWsz;
  const int W2 = TX+4, H2 = TY+4;
  for (int i = threadIdx.x; i < H2*W2; i += 256){
    int ly = i / W2, lx = i - ly*W2;
    int gy = y0 - 2 + ly, gx = x0 - 2 + lx;
    ltg[ly][lx] = (gy >= 0 && gy < HH && gx >= 0 && gx < WW) ? tg[(size_t)gy*WW + gx] : -1e30f;
    lsc[ly][lx] = sb[(size_t)refl(gy,HH)*WW + refl(gx,WW)];
  }
  __syncthreads();
  int tx = threadIdx.x & (TX-1), ty = threadIdx.x / TX;
  float m = -1e30f, S5 = 0.f;
  #pragma unroll
  for (int dy=0; dy<5; ++dy)
    #pragma unroll
    for (int dx=0; dx<5; ++dx){
      m = fmaxf(m, ltg[ty+dy][tx+dx]);
      S5 += lsc[ty+dy][tx+dx];
    }
  float tv = ltg[ty+2][tx+2];
  float sc = lsc[ty+2][tx+2];
  float tb = (tv > 0.f && tv == m) ? 1.f : 0.f;
  float pc = fminf(fmaxf(sc, 1e-12f), 1.0f - 1e-12f);
  float bce = -(tb*logf(pc) + (1.f-tb)*logf(1.f-pc));
  float lap = (S5 - sc)*(1.0f/48.0f) - 0.5f*sc;
  float extra = sc*expf(-lap);
  bce = wave_sum(bce); extra = wave_sum(extra);
  int wave = threadIdx.x >> 6, lane = threadIdx.x & 63;
  if (lane == 0){ rbuf[wave][0] = bce; rbuf[wave][1] = extra; }
  __syncthreads();
  if (threadIdx.x == 0){
    int slot = (blockIdx.x + blockIdx.y*(WW/TX) + blockIdx.z*400) & (NSLOT-1);
    atomicAdd(&accs[(1*NSLOT + slot)*8], (double)(rbuf[0][0]+rbuf[1][0]+rbuf[2][0]+rbuf[3][0]));
    atomicAdd(&accs[(2*NSLOT + slot)*8], (double)(rbuf[0][1]+rbuf[1][1]+rbuf[2][1]+rbuf[3][1]));
  }
}

// ---------------- K9: fused rownorm+bf16 convert AND point projection ----------------
__global__ void k_rowproj(const float* __restrict__ desc, float* __restrict__ xx,
        unsigned short* __restrict__ dbf,
        const float* __restrict__ points, const float* __restrict__ depths,
        const float* __restrict__ poses, const float* __restrict__ Km,
        float* __restrict__ mproj, unsigned char* __restrict__ mvis){
  int t = blockIdx.x*blockDim.x + threadIdx.x;
  if (t < BB*NPTS){
    const float* dptr = desc + (size_t)t*DD;
    unsigned short* optr = dbf + (size_t)t*DD;
    float s = 0.f;
    for (int d = 0; d < DD; d += 4){
      float4 v = *(const float4*)(dptr + d);
      s += v.x*v.x + v.y*v.y + v.z*v.z + v.w*v.w;
      unsigned int u0 = __float_as_uint(v.x); optr[d+0] = (unsigned short)((u0 + 0x7fffu + ((u0>>16)&1u)) >> 16);
      unsigned int u1 = __float_as_uint(v.y); optr[d+1] = (unsigned short)((u1 + 0x7fffu + ((u1>>16)&1u)) >> 16);
      unsigned int u2 = __float_as_uint(v.z); optr[d+2] = (unsigned short)((u2 + 0x7fffu + ((u2>>16)&1u)) >> 16);
      unsigned int u3 = __float_as_uint(v.w); optr[d+3] = (unsigned short)((u3 + 0x7fffu + ((u3>>16)&1u)) >> 16);
    }
    xx[t] = s;
    return;
  }
  int t2 = t - BB*NPTS;
  if (t2 >= BB*BB*NPTS) return;
  int i = t2 / (BB*NPTS); int r = t2 - i*(BB*NPTS); int j = r / NPTS; int n = r - j*NPTS;
  float ptx = points[((size_t)j*NPTS+n)*2+0];
  float pty = points[((size_t)j*NPTS+n)*2+1];
  Proj pr = project_point(ptx, pty, j, i, depths, poses, Km);
  mproj[(size_t)t2*2+0] = (pr.u*2.0f)/(float)(WW-1) - 1.0f;
  mproj[(size_t)t2*2+1] = (pr.v*2.0f)/(float)(HH-1) - 1.0f;
  mvis[t2] = pr.vis ? 1 : 0;
}

// ---------------- K10+K11 merged, 128x128 block tiles ----------------
// grid (36, 1, 36). match: ti -> (mt,nt) triangular over 8 tiles of 128.
// distinction: flat = bx + 36*bz < 384 -> batch flat/64, tile (dt>>3, dt&7) of 128.
__global__ __launch_bounds__(256) void k_grams(const unsigned short* __restrict__ dbf,
        const float* __restrict__ xx, const float* __restrict__ points,
        const float* __restrict__ mproj, const unsigned char* __restrict__ mvis,
        double* __restrict__ accs){
  __shared__ float rbuf[4][4];
  int ab = blockIdx.z; int a = ab / BB, b = ab - a*BB;
  int ti = blockIdx.x;
  int mt = 0;
  while (ti >= 8 - mt){ ti -= 8 - mt; ++mt; }
  int nt = mt + ti;
  int tid = threadIdx.x;
  int wave = tid >> 6, lane = tid & 63;
  int wr = mt*128 + (wave&1)*64;
  int wc = nt*128 + (wave>>1)*64;
  int r = lane & 15, kg = lane >> 4;
  const unsigned short* descA = dbf + (size_t)a*NPTS*DD;
  const unsigned short* descB = dbf + (size_t)b*NPTS*DD;
  const float* xxa = xx + (size_t)a*NPTS;
  const float* xxb = xx + (size_t)b*NPTS;
  const float* pts = points + (size_t)b*NPTS*2;
  const float* mp  = mproj + (((size_t)a*BB+b)*NPTS)*2;
  const unsigned char* mv = mvis + ((size_t)a*BB+b)*NPTS;
  // ---- MFMA: 4x4 fragments, K=128 ----
  f32x4 acc[4][4] = {};
  #pragma unroll
  for (int ks = 0; ks < 4; ++ks){
    int ko = ks*32 + kg*8;
    bf16x8 af[4], bf[4];
    #pragma unroll
    for (int q = 0; q < 4; ++q){
      af[q] = *(const bf16x8*)(descA + (size_t)(wr+q*16+r)*DD + ko);
      bf[q] = *(const bf16x8*)(descB + (size_t)(wc+q*16+r)*DD + ko);
    }
    #pragma unroll
    for (int mi = 0; mi < 4; ++mi)
      #pragma unroll
      for (int ni = 0; ni < 4; ++ni)
        acc[mi][ni] = __builtin_amdgcn_mfma_f32_16x16x32_bf16(af[mi], bf[ni], acc[mi][ni], 0, 0, 0);
  }
  // ---- n-side prefetch (4 cols per lane) ----
  float nxxv[4], ndx[4], ndy[4], ny2[4];
  #pragma unroll
  for (int ni = 0; ni < 4; ++ni){
    int n = wc + ni*16 + r;
    nxxv[ni] = xxb[n];
    float qx = mp[n*2+0], qy = mp[n*2+1];
    float dx = ((qx+1.f)*(float)(WW-1))*0.5f;
    float dy = ((qy+1.f)*(float)(HH-1))*0.5f;
    ndx[ni] = dx; ndy[ni] = dy;
    ny2[ni] = dx*dx + dy*dy;
  }
  float pos = 0.f, neg = 0.f, pcf = 0.f, ncf = 0.f;
  #pragma unroll
  for (int mi = 0; mi < 4; ++mi){
    #pragma unroll
    for (int j = 0; j < 4; ++j){
      int m = wr + mi*16 + 4*kg + j;
      if (!mv[m]) continue;
      float px = pts[m*2+0], py = pts[m*2+1];
      float sx = ((px+1.f)*(float)(WW-1))*0.5f;
      float sy = ((py+1.f)*(float)(HH-1))*0.5f;
      float x2 = sx*sx + sy*sy;
      float xm = xxa[m];
      #pragma unroll
      for (int ni = 0; ni < 4; ++ni){
        int n = wc + ni*16 + r;
        if (m >= n) continue;
        float dv = acc[mi][ni][j];
        float d2 = x2 + ny2[ni] - 2.f*(sx*ndx[ni] + sy*ndy[ni]);
        float p = dv * rsqrtf(fmaxf(xm * nxxv[ni], 1e-16f));
        if (d2 <= 1.0f){ pos += p; pcf += 1.f; }
        else           { neg += p; ncf += 1.f; }
      }
    }
  }
  pos = wave_sum(pos); neg = wave_sum(neg);
  pcf = wave_sum(pcf); ncf = wave_sum(ncf);
  if (lane == 0){ rbuf[wave][0] = pos; rbuf[wave][1] = neg; rbuf[wave][2] = pcf; rbuf[wave][3] = ncf; }
  __syncthreads();
  if (tid == 0){
    int slot = (blockIdx.x + blockIdx.z*8) & (NSLOT-1);
    atomicAdd(&accs[(3*NSLOT + slot)*8], (double)(rbuf[0][0]+rbuf[1][0]+rbuf[2][0]+rbuf[3][0]));
    atomicAdd(&accs[(4*NSLOT + slot)*8], (double)(rbuf[0][1]+rbuf[1][1]+rbuf[2][1]+rbuf[3][1]));
    atomicAdd(&accs[(5*NSLOT + slot)*8], (double)(rbuf[0][2]+rbuf[1][2]+rbuf[2][2]+rbuf[3][2]));
    atomicAdd(&accs[(6*NSLOT + slot)*8], (double)(rbuf[0][3]+rbuf[1][3]+rbuf[2][3]+rbuf[3][3]));
  }
  // ---- distinction tile (first 384 flat blocks), 128x128 ----
  int flat = blockIdx.x + 36*blockIdx.z;
  if (flat >= 384) return;
  int db = flat >> 6;
  int dt = flat & 63;
  int wr2 = (dt >> 3)*128 + (wave&1)*64;
  int wc2 = (dt & 7)*128 + (wave>>1)*64;
  const unsigned short* descb = dbf + (size_t)db*NPTS*DD;
  const float* xb = xx + (size_t)db*NPTS;
  f32x4 ec[4][4] = {};
  #pragma unroll
  for (int ks = 0; ks < 4; ++ks){
    int ko = ks*32 + kg*8;
    bf16x8 af[4], bf[4];
    #pragma unroll
    for (int q = 0; q < 4; ++q){
      af[q] = *(const bf16x8*)(descb + (size_t)(wr2+q*16+r)*DD + ko);
      bf[q] = *(const bf16x8*)(descb + (size_t)(wc2+q*16+r)*DD + ko);
    }
    #pragma unroll
    for (int mi = 0; mi < 4; ++mi)
      #pragma unroll
      for (int ni = 0; ni < 4; ++ni)
        ec[mi][ni] = __builtin_amdgcn_mfma_f32_16x16x32_bf16(af[mi], bf[ni], ec[mi][ni], 0, 0, 0);
  }
  float xn[4];
  #pragma unroll
  for (int ni = 0; ni < 4; ++ni) xn[ni] = xb[wc2 + ni*16 + r];
  float local = 0.f;
  #pragma unroll
  for (int mi = 0; mi < 4; ++mi){
    #pragma unroll
    for (int j = 0; j < 4; ++j){
      float xm = xb[wr2 + mi*16 + 4*kg + j];
      #pragma unroll
      for (int ni = 0; ni < 4; ++ni)
        local += fmaxf(ec[mi][ni][j] * rsqrtf(fmaxf(xm*xn[ni], 1e-16f)), 0.f);
    }
  }
  local = wave_sum(local);
  __syncthreads();            // rbuf reuse
  if (lane == 0) rbuf[wave][0] = local;
  __syncthreads();
  if (tid == 0){
    int slot = flat & (NSLOT-1);
    atomicAdd(&accs[(0*NSLOT + slot)*8], (double)(rbuf[0][0]+rbuf[1][0]+rbuf[2][0]+rbuf[3][0]));
  }
}

// ---------------- K12: finalize (64 threads, wave-reduce the slots) ----------------
__global__ void k_final(const double* __restrict__ accs, float* __restrict__ out){
  int lane = threadIdx.x;
  double tot[7];
  #pragma unroll
  for (int q = 0; q < 7; ++q)
    tot[q] = wave_sumd(accs[((size_t)q*NSLOT + lane)*8]);
  if (lane == 0){
    double distinction = tot[0] / (double)((long long)BB*NPTS*NPTS);
    double bce = tot[1] / (double)((long long)BB*HWsz);
    double extra = tot[2] / (double)((long long)BB*HWsz);
    double cornerness = bce + 10.0*extra;
    double pcd = tot[5] < 0.5 ? 1.0 : tot[5];
    double ncd = tot[6] < 0.5 ? 1.0 : tot[6];
    double pos_mean = tot[3] / pcd;
    double neg_mean = tot[4] / ncd;
    double match = 1.0 - pos_mean + neg_mean;
    out[0] = (float)(distinction + 0.5*cornerness + match);
  }
}

extern "C" void kernel_launch(void* const* d_in, const int* in_sizes, int n_in,
                              void* d_out, int out_size, void* d_ws, size_t ws_size,
                              hipStream_t stream) {
  (void)in_sizes; (void)n_in; (void)out_size; (void)ws_size;
  const float* desc   = (const float*)d_in[0];
  const float* points = (const float*)d_in[1];
  const float* scores = (const float*)d_in[2];
  const float* depths = (const float*)d_in[3];
  const float* poses  = (const float*)d_in[4];
  const float* Km     = (const float*)d_in[5];
  const float* imgs   = (const float*)d_in[6];
  float* out = (float*)d_out;

  const size_t S = (size_t)BB*HWsz;
  float* resp   = (float*)d_ws;                                    // S
  float* target = resp + S;                                        // S
  unsigned long long* ckeys = (unsigned long long*)(target + S);   // BB*CAP*8
  unsigned int* ccnt = (unsigned int*)(ckeys + (size_t)BB*CAP);    // 8 uints
  double* accs = (double*)(ccnt + 8);                              // 7*64*8 doubles
  float* cpts  = (float*)(accs + 7*NSLOT*8);                       // BB*NC*2
  float* cvals = cpts + (size_t)BB*NC*2;                           // BB*NC
  float* xx    = cvals + (size_t)BB*NC;                            // BB*NPTS
  float* mproj = xx + (size_t)BB*NPTS;                             // BB*BB*NPTS*2
  unsigned char* mvis = (unsigned char*)(mproj + (size_t)BB*BB*NPTS*2); // BB*BB*NPTS
  unsigned short* dbf = (unsigned short*)(mvis + (size_t)BB*BB*NPTS);   // bf16 desc

  dim3 blk(256);
  dim3 gtile(WW/TX, HH/TY, BB);

  hipMemsetAsync(target, 0,
      S*sizeof(float) +
      (size_t)BB*CAP*sizeof(unsigned long long) + 8*sizeof(unsigned int) +
      (size_t)7*NSLOT*8*sizeof(double), stream);

  k_gftt<<<gtile, blk, 0, stream>>>(imgs, resp);
  k_nmsblk<<<gtile, blk, 0, stream>>>(resp, ckeys, ccnt);
  k_top500<<<dim3(BB), dim3(1024), 0, stream>>>(ckeys, cpts, cvals);
  {
    int n = BB*BB*NC;
    k_corner_scatter<<<dim3((n+255)/256), blk, 0, stream>>>(cpts, cvals, depths, poses, Km,
                                                            (unsigned int*)target);
  }
  k_score_reduce<<<gtile, blk, 0, stream>>>(target, scores, accs);
  {
    int n = BB*NPTS + BB*BB*NPTS;
    k_rowproj<<<dim3((n+255)/256), blk, 0, stream>>>(desc, xx, dbf, points, depths, poses, Km,
                                                     mproj, mvis);
  }
  k_grams<<<dim3(36, 1, BB*BB), blk, 0, stream>>>(dbf, xx, points, mproj, mvis, accs);
  k_final<<<dim3(1), dim3(64), 0, stream>>>(accs, out);
}